// Round 1
// baseline (7336.311 us; speedup 1.0000x reference)
//
#include <hip/hip_runtime.h>
#include <math.h>

#define DEVFN __device__ __forceinline__

constexpr float BN_INV = 0.99999500003749971f; // 1/sqrt(1+1e-5)

DEVFN float sigm(float x) { return 1.0f / (1.0f + expf(-x)); }

// ---------------- precompute kernels (run every call; ws is re-poisoned) ----------------

// Combined LSTM weight, transposed to k-major: WgT[k*512+t], k<64 from Wih, else Whh. bg = bih+bhh.
__global__ void pre_lstm(const float* __restrict__ Wih, const float* __restrict__ Whh,
                         const float* __restrict__ bih, const float* __restrict__ bhh,
                         float* __restrict__ WgT, float* __restrict__ bg) {
    int idx = blockIdx.x * blockDim.x + threadIdx.x;   // 192*512
    int k = idx >> 9, t = idx & 511;
    WgT[idx] = (k < 64) ? Wih[t * 64 + k] : Whh[t * 128 + (k - 64)];
    if (idx < 512) bg[idx] = bih[idx] + bhh[idx];
}

// pp1 h-part, transposed + BN scale folded: Wh1T[h*512+k] = pp1_W[k,64+h]*BN_INV*pp1_g[k]
__global__ void pre_wh1(const float* __restrict__ pp1W, const float* __restrict__ pp1g,
                        float* __restrict__ Wh1T) {
    int idx = blockIdx.x * blockDim.x + threadIdx.x;   // 128*512
    int h = idx >> 9, k = idx & 511;
    Wh1T[idx] = pp1W[k * 192 + 64 + h] * (BN_INV * pp1g[k]);
}

// Mp[d*512+k] = (sp_W[:,d] . pp1_W[k,:64]) * s1;  c1[k] = ((sp_b . pp1_W[k,:64]) + pp1_b)*s1 + pp1_be
__global__ void pre_mp(const float* __restrict__ spW, const float* __restrict__ spb,
                       const float* __restrict__ pp1W, const float* __restrict__ pp1b,
                       const float* __restrict__ pp1g, const float* __restrict__ pp1be,
                       float* __restrict__ Mp, float* __restrict__ c1) {
    int k = blockIdx.x * blockDim.x + threadIdx.x;     // 512
    float m0 = 0.f, m1 = 0.f, c0 = 0.f;
    for (int e = 0; e < 64; e++) {
        float w = pp1W[k * 192 + e];
        m0 += spW[e * 2] * w; m1 += spW[e * 2 + 1] * w; c0 += spb[e] * w;
    }
    float s = BN_INV * pp1g[k];
    Mp[k] = m0 * s; Mp[512 + k] = m1 * s;
    c1[k] = (c0 + pp1b[k]) * s + pp1be[k];
}

// Generic: Wt[ki*KO+ko] = W[ko*KI+ki]*BN_INV*g[ko]; cv[ko]=b*s+be.  KO is a power of two.
__global__ void pre_scaleT(const float* __restrict__ W, const float* __restrict__ b,
                           const float* __restrict__ g, const float* __restrict__ be,
                           float* __restrict__ Wt, float* __restrict__ cv,
                           int KI, int koShift) {
    int idx = blockIdx.x * blockDim.x + threadIdx.x;
    int KO = 1 << koShift;
    if (idx >= KI * KO) return;
    int ki = idx >> koShift, ko = idx & (KO - 1);
    float s = BN_INV * g[ko];
    Wt[idx] = W[ko * KI + ki] * s;
    if (idx < KO) cv[idx] = b[idx] * s + be[idx];
}

// State init: h=h0, c=c0, curr=last_pos, din0 = last_pos_rel @ emb_W.T + emb_b
__global__ void pre_init(const float* __restrict__ lp, const float* __restrict__ lpr,
                         const float* __restrict__ h0, const float* __restrict__ c0,
                         const float* __restrict__ embW, const float* __restrict__ embb,
                         float* __restrict__ h_st, float* __restrict__ c_st,
                         float* __restrict__ curr, float* __restrict__ din) {
    int idx = blockIdx.x * blockDim.x + threadIdx.x;   // 1024*128
    h_st[idx] = h0[idx];
    c_st[idx] = c0[idx];
    if (idx < 1024 * 2) curr[idx] = lp[idx];
    if (idx < 1024 * 64) {
        int n = idx >> 6, e = idx & 63;
        din[idx] = fmaf(lpr[n * 2], embW[e * 2], fmaf(lpr[n * 2 + 1], embW[e * 2 + 1], embb[e]));
    }
}

// ---------------- per-step kernels ----------------

// Fused: LSTM cell + rel_pos + curr update + din2 + preds write.  1 block per pedestrian.
__global__ __launch_bounds__(512) void k_lstm(
    const float* __restrict__ WgT, const float* __restrict__ bg,
    float* __restrict__ h_st, float* __restrict__ c_st,
    float* __restrict__ din, float* __restrict__ curr, float* __restrict__ h2buf,
    const float* __restrict__ posW, const float* __restrict__ posb,
    const float* __restrict__ embW, const float* __restrict__ embb,
    float* __restrict__ preds) {
    int n = blockIdx.x, t = threadIdx.x;
    __shared__ float x[192];
    __shared__ float gates[512];
    __shared__ float h2s[128];
    __shared__ float rp[2];
    if (t < 64) x[t] = din[n * 64 + t];
    else if (t < 192) x[t] = h_st[n * 128 + (t - 64)];
    __syncthreads();
    float acc = bg[t];
#pragma unroll 8
    for (int k = 0; k < 192; k++) acc = fmaf(x[k], WgT[(k << 9) + t], acc);
    gates[t] = acc;
    __syncthreads();
    if (t < 128) {
        float ig = sigm(gates[t]);
        float fg = sigm(gates[128 + t]);
        float gg = tanhf(gates[256 + t]);
        float og = sigm(gates[384 + t]);
        float c2 = fmaf(fg, c_st[n * 128 + t], ig * gg);
        float h2 = og * tanhf(c2);
        c_st[n * 128 + t] = c2;
        h2buf[n * 128 + t] = h2;
        h2s[t] = h2;
    }
    __syncthreads();
    if (t < 64) {
        float p0 = fmaf(h2s[t], posW[t], h2s[t + 64] * posW[t + 64]);
        float p1 = fmaf(h2s[t], posW[128 + t], h2s[t + 64] * posW[192 + t]);
#pragma unroll
        for (int off = 32; off > 0; off >>= 1) {
            p0 += __shfl_down(p0, off, 64);
            p1 += __shfl_down(p1, off, 64);
        }
        if (t == 0) { rp[0] = p0 + posb[0]; rp[1] = p1 + posb[1]; }
    }
    __syncthreads();
    float r0 = rp[0], r1 = rp[1];
    if (t == 0) {
        preds[n * 2] = r0; preds[n * 2 + 1] = r1;
        curr[n * 2] += r0; curr[n * 2 + 1] += r1;
    }
    if (t < 64) din[n * 64 + t] = fmaf(r0, embW[t * 2], fmaf(r1, embW[t * 2 + 1], embb[t]));
}

// Hp[j,k] = (h2[j,:] @ pp1_W[:,64:].T)[k] * s1[k]   (bias/affine folded into c1, added later)
__global__ __launch_bounds__(512) void k_hpp1(const float* __restrict__ h2buf,
                                              const float* __restrict__ Wh1T,
                                              float* __restrict__ Hp) {
    int n = blockIdx.x, t = threadIdx.x;
    __shared__ float hs[128];
    if (t < 128) hs[t] = h2buf[n * 128 + t];
    __syncthreads();
    float acc = 0.f;
#pragma unroll 8
    for (int h = 0; h < 128; h++) acc = fmaf(hs[h], Wh1T[(h << 9) + t], acc);
    Hp[(n << 9) + t] = acc;
}

// pp2 GEMM + max-over-j pool. Block = one (s,i) x 256-wide ko chunk; 32 j rows, K=512.
// x1[j,k] = relu(Hp[j,k] + rx[j]*Mp[0,k] + ry[j]*Mp[1,k] + c1[k]) built on the fly in LDS.
__global__ __launch_bounds__(256) void k_pool(
    const float* __restrict__ Hp, const float* __restrict__ Mp,
    const float* __restrict__ c1, const float* __restrict__ W2t,
    const float* __restrict__ c2v, const float* __restrict__ curr,
    float* __restrict__ pool) {
    int si = blockIdx.y;              // s*32 + i
    int s = si >> 5;
    int koBase = blockIdx.x << 8;
    int t = threadIdx.x;
    int lane = t & 63, wv = t >> 6;
    int j0 = wv << 3;                 // 8 j-rows per wave
    int ko = koBase + (lane << 2);    // 4 ko per thread
    __shared__ float rx[32], ry[32];
    __shared__ float xs[64][36];      // [k][j], pad 36 keeps float4 alignment
    __shared__ float red[1024];
    if (t < 32) {
        float pix = curr[si * 2], piy = curr[si * 2 + 1];
        int jg = (s << 5) + t;
        float dx = curr[jg * 2] - pix, dy = curr[jg * 2 + 1] - piy;
        float den = fmaxf(sqrtf(dx * dx + dy * dy), 1e-12f);
        rx[t] = dx / den; ry[t] = dy / den;
    }
    __syncthreads();
    float acc[8][4];
#pragma unroll
    for (int a = 0; a < 8; a++)
#pragma unroll
        for (int b = 0; b < 4; b++) acc[a][b] = 0.f;

    for (int kt = 0; kt < 512; kt += 64) {
#pragma unroll
        for (int u = 0; u < 8; u++) {
            int lin = t + (u << 8);
            int j = lin >> 6, kk = lin & 63;
            int kg = kt + kk;
            float v = Hp[((s << 5) + j) * 512 + kg] + rx[j] * Mp[kg] + ry[j] * Mp[512 + kg] + c1[kg];
            xs[kk][j] = fmaxf(v, 0.f);
        }
        __syncthreads();
#pragma unroll 4
        for (int kk = 0; kk < 64; kk++) {
            float4 w = *(const float4*)(W2t + (kt + kk) * 1024 + ko);
            float4 xa = *(const float4*)(&xs[kk][j0]);
            float4 xb = *(const float4*)(&xs[kk][j0 + 4]);
            float xv[8] = {xa.x, xa.y, xa.z, xa.w, xb.x, xb.y, xb.z, xb.w};
#pragma unroll
            for (int a = 0; a < 8; a++) {
                acc[a][0] = fmaf(xv[a], w.x, acc[a][0]);
                acc[a][1] = fmaf(xv[a], w.y, acc[a][1]);
                acc[a][2] = fmaf(xv[a], w.z, acc[a][2]);
                acc[a][3] = fmaf(xv[a], w.w, acc[a][3]);
            }
        }
        __syncthreads();
    }
    // relu + max over this wave's 8 j (relu>=0 so init 0 is exact)
    float4 cc = *(const float4*)(c2v + ko);
    float m0 = 0.f, m1 = 0.f, m2 = 0.f, m3 = 0.f;
#pragma unroll
    for (int a = 0; a < 8; a++) {
        m0 = fmaxf(m0, acc[a][0] + cc.x);
        m1 = fmaxf(m1, acc[a][1] + cc.y);
        m2 = fmaxf(m2, acc[a][2] + cc.z);
        m3 = fmaxf(m3, acc[a][3] + cc.w);
    }
    *(float4*)(&red[(wv << 8) + (lane << 2)]) = make_float4(m0, m1, m2, m3);
    __syncthreads();
    float r = fmaxf(fmaxf(red[t], red[256 + t]), fmaxf(red[512 + t], red[768 + t]));
    pool[si * 1024 + koBase + t] = r;
}

// m1: dh1 = relu(bn(concat(h2,pool) @ m1_W.T + b)).  Block = 16 rows x 256 ko, K=1152.
__global__ __launch_bounds__(256) void k_m1(
    const float* __restrict__ h2buf, const float* __restrict__ pool,
    const float* __restrict__ M1t, const float* __restrict__ cm1,
    float* __restrict__ dh1) {
    int rowBase = blockIdx.y << 4;
    int koBase = blockIdx.x << 8;
    int t = threadIdx.x;
    int lane = t & 63, wv = t >> 6;
    int j0 = wv << 2;                 // 4 rows per wave
    int ko = koBase + (lane << 2);
    __shared__ float xs[64][20];
    float acc[4][4];
#pragma unroll
    for (int a = 0; a < 4; a++)
#pragma unroll
        for (int b = 0; b < 4; b++) acc[a][b] = 0.f;

    for (int kt = 0; kt < 1152; kt += 64) {
#pragma unroll
        for (int u = 0; u < 4; u++) {
            int lin = t + (u << 8);   // 64 kk x 16 rows
            int j = lin >> 6, kk = lin & 63;
            int jg = rowBase + j, kg = kt + kk;
            xs[kk][j] = (kg < 128) ? h2buf[jg * 128 + kg] : pool[jg * 1024 + (kg - 128)];
        }
        __syncthreads();
#pragma unroll 4
        for (int kk = 0; kk < 64; kk++) {
            float4 w = *(const float4*)(M1t + (kt + kk) * 1024 + ko);
            float4 xa = *(const float4*)(&xs[kk][j0]);
            float xv[4] = {xa.x, xa.y, xa.z, xa.w};
#pragma unroll
            for (int a = 0; a < 4; a++) {
                acc[a][0] = fmaf(xv[a], w.x, acc[a][0]);
                acc[a][1] = fmaf(xv[a], w.y, acc[a][1]);
                acc[a][2] = fmaf(xv[a], w.z, acc[a][2]);
                acc[a][3] = fmaf(xv[a], w.w, acc[a][3]);
            }
        }
        __syncthreads();
    }
    float4 cc = *(const float4*)(cm1 + ko);
#pragma unroll
    for (int a = 0; a < 4; a++) {
        int jg = rowBase + j0 + a;
        float4 o = make_float4(fmaxf(acc[a][0] + cc.x, 0.f), fmaxf(acc[a][1] + cc.y, 0.f),
                               fmaxf(acc[a][2] + cc.z, 0.f), fmaxf(acc[a][3] + cc.w, 0.f));
        *(float4*)(dh1 + jg * 1024 + ko) = o;
    }
}

// m2: h_next = relu(bn(dh1 @ m2_W.T + b)).  Block = 8 rows x 128 ko, K=1024.
__global__ __launch_bounds__(256) void k_m2(
    const float* __restrict__ dh1, const float* __restrict__ M2t,
    const float* __restrict__ cm2, float* __restrict__ h_st) {
    int rowBase = blockIdx.x << 3;
    int t = threadIdx.x;
    int ko = t & 127, rg = t >> 7;    // rg 0..1 -> rows rg*4..rg*4+3
    __shared__ float xs[8][1024];
#pragma unroll
    for (int u = 0; u < 32; u++) {
        int lin = t + (u << 8);
        int r = lin >> 10, ki = lin & 1023;
        xs[r][ki] = dh1[(rowBase + r) * 1024 + ki];
    }
    __syncthreads();
    float acc[4] = {0.f, 0.f, 0.f, 0.f};
    for (int ki = 0; ki < 1024; ki += 4) {
        float w0 = M2t[(ki + 0) * 128 + ko];
        float w1 = M2t[(ki + 1) * 128 + ko];
        float w2 = M2t[(ki + 2) * 128 + ko];
        float w3 = M2t[(ki + 3) * 128 + ko];
#pragma unroll
        for (int q = 0; q < 4; q++) {
            float4 xv = *(const float4*)(&xs[rg * 4 + q][ki]);
            acc[q] = fmaf(xv.x, w0, fmaf(xv.y, w1, fmaf(xv.z, w2, fmaf(xv.w, w3, acc[q]))));
        }
    }
    float c = cm2[ko];
#pragma unroll
    for (int q = 0; q < 4; q++)
        h_st[(rowBase + rg * 4 + q) * 128 + ko] = fmaxf(acc[q] + c, 0.f);
}

// ---------------- launch ----------------

extern "C" void kernel_launch(void* const* d_in, const int* in_sizes, int n_in,
                              void* d_out, int out_size, void* d_ws, size_t ws_size,
                              hipStream_t stream) {
    const float* last_pos     = (const float*)d_in[0];
    const float* last_pos_rel = (const float*)d_in[1];
    const float* h0   = (const float*)d_in[2];
    const float* c0   = (const float*)d_in[3];
    const float* emb_W = (const float*)d_in[5];
    const float* emb_b = (const float*)d_in[6];
    const float* lstm_Wih = (const float*)d_in[7];
    const float* lstm_Whh = (const float*)d_in[8];
    const float* lstm_bih = (const float*)d_in[9];
    const float* lstm_bhh = (const float*)d_in[10];
    const float* pos_W = (const float*)d_in[11];
    const float* pos_b = (const float*)d_in[12];
    const float* sp_W  = (const float*)d_in[13];
    const float* sp_b  = (const float*)d_in[14];
    const float* pp1_W = (const float*)d_in[15];
    const float* pp1_b = (const float*)d_in[16];
    const float* pp1_g = (const float*)d_in[17];
    const float* pp1_be= (const float*)d_in[18];
    const float* pp2_W = (const float*)d_in[19];
    const float* pp2_b = (const float*)d_in[20];
    const float* pp2_g = (const float*)d_in[21];
    const float* pp2_be= (const float*)d_in[22];
    const float* m1_W  = (const float*)d_in[23];
    const float* m1_b  = (const float*)d_in[24];
    const float* m1_g  = (const float*)d_in[25];
    const float* m1_be = (const float*)d_in[26];
    const float* m2_W  = (const float*)d_in[27];
    const float* m2_b  = (const float*)d_in[28];
    const float* m2_g  = (const float*)d_in[29];
    const float* m2_be = (const float*)d_in[30];
    float* out = (float*)d_out;

    float* p = (float*)d_ws;
    float* WgT  = p; p += 192 * 512;
    float* bg   = p; p += 512;
    float* Wh1T = p; p += 128 * 512;
    float* Mp   = p; p += 2 * 512;
    float* c1   = p; p += 512;
    float* W2t  = p; p += 512 * 1024;
    float* c2v  = p; p += 1024;
    float* M1t  = p; p += 1152 * 1024;
    float* cm1  = p; p += 1024;
    float* M2t  = p; p += 1024 * 128;
    float* cm2  = p; p += 128;
    float* h_st = p; p += 1024 * 128;
    float* c_st = p; p += 1024 * 128;
    float* h2b  = p; p += 1024 * 128;
    float* curr = p; p += 1024 * 2;
    float* din  = p; p += 1024 * 64;
    float* Hp   = p; p += 1024 * 512;
    float* pool = p; p += 1024 * 1024;
    float* dh1  = p; p += 1024 * 1024;

    pre_lstm<<<384, 256, 0, stream>>>(lstm_Wih, lstm_Whh, lstm_bih, lstm_bhh, WgT, bg);
    pre_wh1<<<256, 256, 0, stream>>>(pp1_W, pp1_g, Wh1T);
    pre_mp<<<2, 256, 0, stream>>>(sp_W, sp_b, pp1_W, pp1_b, pp1_g, pp1_be, Mp, c1);
    pre_scaleT<<<2048, 256, 0, stream>>>(pp2_W, pp2_b, pp2_g, pp2_be, W2t, c2v, 512, 10);
    pre_scaleT<<<4608, 256, 0, stream>>>(m1_W, m1_b, m1_g, m1_be, M1t, cm1, 1152, 10);
    pre_scaleT<<<512, 256, 0, stream>>>(m2_W, m2_b, m2_g, m2_be, M2t, cm2, 1024, 7);
    pre_init<<<512, 256, 0, stream>>>(last_pos, last_pos_rel, h0, c0, emb_W, emb_b,
                                      h_st, c_st, curr, din);

    for (int t = 0; t < 12; t++) {
        k_lstm<<<1024, 512, 0, stream>>>(WgT, bg, h_st, c_st, din, curr, h2b,
                                         pos_W, pos_b, emb_W, emb_b, out + t * 2048);
        if (t == 11) break;  // last step only needs rel_pos
        k_hpp1<<<1024, 512, 0, stream>>>(h2b, Wh1T, Hp);
        k_pool<<<dim3(4, 1024), 256, 0, stream>>>(Hp, Mp, c1, W2t, c2v, curr, pool);
        k_m1<<<dim3(4, 64), 256, 0, stream>>>(h2b, pool, M1t, cm1, dh1);
        k_m2<<<128, 256, 0, stream>>>(dh1, M2t, cm2, h_st);
    }
}

// Round 2
// 2872.812 us; speedup vs baseline: 2.5537x; 2.5537x over previous
//
#include <hip/hip_runtime.h>
#include <hip/hip_bf16.h>
#include <math.h>

#define DEVFN __device__ __forceinline__

constexpr float BN_INV = 0.99999500003749971f; // 1/sqrt(1+1e-5)

DEVFN float sigm(float x) { return 1.0f / (1.0f + expf(-x)); }

DEVFN unsigned short f2bf(float f) {
    __hip_bfloat16 b = __float2bfloat16(f);
    return *reinterpret_cast<unsigned short*>(&b);
}

typedef __attribute__((ext_vector_type(8))) short short8;  // 8 bf16 = 4 VGPRs
typedef __attribute__((ext_vector_type(4))) float f32x4;

// ---------------- precompute kernels (run every call; ws is re-poisoned) ----------------

// Combined LSTM weight, transposed to k-major: WgT[k*512+t], k<64 from Wih, else Whh. bg = bih+bhh.
__global__ void pre_lstm(const float* __restrict__ Wih, const float* __restrict__ Whh,
                         const float* __restrict__ bih, const float* __restrict__ bhh,
                         float* __restrict__ WgT, float* __restrict__ bg) {
    int idx = blockIdx.x * blockDim.x + threadIdx.x;   // 192*512
    int k = idx >> 9, t = idx & 511;
    WgT[idx] = (k < 64) ? Wih[t * 64 + k] : Whh[t * 128 + (k - 64)];
    if (idx < 512) bg[idx] = bih[idx] + bhh[idx];
}

// pp1 h-part, transposed + BN scale folded: Wh1T[h*512+k] = pp1_W[k,64+h]*BN_INV*pp1_g[k]
__global__ void pre_wh1(const float* __restrict__ pp1W, const float* __restrict__ pp1g,
                        float* __restrict__ Wh1T) {
    int idx = blockIdx.x * blockDim.x + threadIdx.x;   // 128*512
    int h = idx >> 9, k = idx & 511;
    Wh1T[idx] = pp1W[k * 192 + 64 + h] * (BN_INV * pp1g[k]);
}

// Mp[d*512+k] = (sp_W[:,d] . pp1_W[k,:64]) * s1;  c1[k] = ((sp_b . pp1_W[k,:64]) + pp1_b)*s1 + pp1_be
__global__ void pre_mp(const float* __restrict__ spW, const float* __restrict__ spb,
                       const float* __restrict__ pp1W, const float* __restrict__ pp1b,
                       const float* __restrict__ pp1g, const float* __restrict__ pp1be,
                       float* __restrict__ Mp, float* __restrict__ c1) {
    int k = blockIdx.x * blockDim.x + threadIdx.x;     // 512
    float m0 = 0.f, m1 = 0.f, c0 = 0.f;
    for (int e = 0; e < 64; e++) {
        float w = pp1W[k * 192 + e];
        m0 += spW[e * 2] * w; m1 += spW[e * 2 + 1] * w; c0 += spb[e] * w;
    }
    float s = BN_INV * pp1g[k];
    Mp[k] = m0 * s; Mp[512 + k] = m1 * s;
    c1[k] = (c0 + pp1b[k]) * s + pp1be[k];
}

// pp2 weights: scale+convert to bf16 (layout already [ko][ki], ko-major, ki contiguous).
__global__ void pre_w2bf(const float* __restrict__ W, const float* __restrict__ b,
                         const float* __restrict__ g, const float* __restrict__ be,
                         unsigned short* __restrict__ Wbf, float* __restrict__ cv) {
    int idx = blockIdx.x * blockDim.x + threadIdx.x;   // 1024*512
    int ko = idx >> 9;
    float s = BN_INV * g[ko];
    Wbf[idx] = f2bf(W[idx] * s);
    if (idx < 1024) cv[idx] = b[idx] * s + be[idx];
}

// Generic: Wt[ki*KO+ko] = W[ko*KI+ki]*BN_INV*g[ko]; cv[ko]=b*s+be.  KO is a power of two.
__global__ void pre_scaleT(const float* __restrict__ W, const float* __restrict__ b,
                           const float* __restrict__ g, const float* __restrict__ be,
                           float* __restrict__ Wt, float* __restrict__ cv,
                           int KI, int koShift) {
    int idx = blockIdx.x * blockDim.x + threadIdx.x;
    int KO = 1 << koShift;
    if (idx >= KI * KO) return;
    int ki = idx >> koShift, ko = idx & (KO - 1);
    float s = BN_INV * g[ko];
    Wt[idx] = W[ko * KI + ki] * s;
    if (idx < KO) cv[idx] = b[idx] * s + be[idx];
}

// State init: h=h0, c=c0, curr=last_pos, din0 = last_pos_rel @ emb_W.T + emb_b
__global__ void pre_init(const float* __restrict__ lp, const float* __restrict__ lpr,
                         const float* __restrict__ h0, const float* __restrict__ c0,
                         const float* __restrict__ embW, const float* __restrict__ embb,
                         float* __restrict__ h_st, float* __restrict__ c_st,
                         float* __restrict__ curr, float* __restrict__ din) {
    int idx = blockIdx.x * blockDim.x + threadIdx.x;   // 1024*128
    h_st[idx] = h0[idx];
    c_st[idx] = c0[idx];
    if (idx < 1024 * 2) curr[idx] = lp[idx];
    if (idx < 1024 * 64) {
        int n = idx >> 6, e = idx & 63;
        din[idx] = fmaf(lpr[n * 2], embW[e * 2], fmaf(lpr[n * 2 + 1], embW[e * 2 + 1], embb[e]));
    }
}

// ---------------- per-step kernels ----------------

// Fused: LSTM cell + rel_pos + curr update + din2 + preds write.  1 block per pedestrian.
__global__ __launch_bounds__(512) void k_lstm(
    const float* __restrict__ WgT, const float* __restrict__ bg,
    float* __restrict__ h_st, float* __restrict__ c_st,
    float* __restrict__ din, float* __restrict__ curr, float* __restrict__ h2buf,
    const float* __restrict__ posW, const float* __restrict__ posb,
    const float* __restrict__ embW, const float* __restrict__ embb,
    float* __restrict__ preds) {
    int n = blockIdx.x, t = threadIdx.x;
    __shared__ float x[192];
    __shared__ float gates[512];
    __shared__ float h2s[128];
    __shared__ float rp[2];
    if (t < 64) x[t] = din[n * 64 + t];
    else if (t < 192) x[t] = h_st[n * 128 + (t - 64)];
    __syncthreads();
    float acc = bg[t];
#pragma unroll 8
    for (int k = 0; k < 192; k++) acc = fmaf(x[k], WgT[(k << 9) + t], acc);
    gates[t] = acc;
    __syncthreads();
    if (t < 128) {
        float ig = sigm(gates[t]);
        float fg = sigm(gates[128 + t]);
        float gg = tanhf(gates[256 + t]);
        float og = sigm(gates[384 + t]);
        float c2 = fmaf(fg, c_st[n * 128 + t], ig * gg);
        float h2 = og * tanhf(c2);
        c_st[n * 128 + t] = c2;
        h2buf[n * 128 + t] = h2;
        h2s[t] = h2;
    }
    __syncthreads();
    if (t < 64) {
        float p0 = fmaf(h2s[t], posW[t], h2s[t + 64] * posW[t + 64]);
        float p1 = fmaf(h2s[t], posW[128 + t], h2s[t + 64] * posW[192 + t]);
#pragma unroll
        for (int off = 32; off > 0; off >>= 1) {
            p0 += __shfl_down(p0, off, 64);
            p1 += __shfl_down(p1, off, 64);
        }
        if (t == 0) { rp[0] = p0 + posb[0]; rp[1] = p1 + posb[1]; }
    }
    __syncthreads();
    float r0 = rp[0], r1 = rp[1];
    if (t == 0) {
        preds[n * 2] = r0; preds[n * 2 + 1] = r1;
        curr[n * 2] += r0; curr[n * 2 + 1] += r1;
    }
    if (t < 64) din[n * 64 + t] = fmaf(r0, embW[t * 2], fmaf(r1, embW[t * 2 + 1], embb[t]));
}

// Hp[j,k] = (h2[j,:] @ pp1_W[:,64:].T)[k] * s1[k]   (bias/affine folded into c1, added later)
__global__ __launch_bounds__(512) void k_hpp1(const float* __restrict__ h2buf,
                                              const float* __restrict__ Wh1T,
                                              float* __restrict__ Hp) {
    int n = blockIdx.x, t = threadIdx.x;
    __shared__ float hs[128];
    if (t < 128) hs[t] = h2buf[n * 128 + t];
    __syncthreads();
    float acc = 0.f;
#pragma unroll 8
    for (int h = 0; h < 128; h++) acc = fmaf(hs[h], Wh1T[(h << 9) + t], acc);
    Hp[(n << 9) + t] = acc;
}

// pp2 GEMM + max-pool via bf16 MFMA.
// Per-scene GEMM: D[(i,j)][ko] = x1[(i,j)][k] * W2bf[k][ko], K=512.
// Block tile: 128 rows (4 i x 32 j) x 128 ko. 4 waves, each a 64x64 quadrant of
// 16x16x32 MFMAs. x1 built on the fly into LDS (bf16). Max over j completes
// in-block: in-register max + shfl_xor(16/32). No atomics, no LDS epilogue.
__global__ __launch_bounds__(256) void k_pool_mfma(
    const float* __restrict__ Hp, const float* __restrict__ Mp,
    const float* __restrict__ c1, const unsigned short* __restrict__ W2bf,
    const float* __restrict__ c2v, const float* __restrict__ curr,
    float* __restrict__ pool) {
    int s = blockIdx.z;
    int rb = blockIdx.y;               // i-group: global i = rb*4 .. rb*4+3
    int koBase = blockIdx.x << 7;
    int t = threadIdx.x;
    int lane = t & 63, wv = t >> 6;
    int quad = lane >> 4, l15 = lane & 15;
    int qrow = (wv >> 1) << 6;         // 0 or 64
    int qcol = (wv & 1) << 6;          // 0 or 64

    __shared__ unsigned short As[128 * 40];  // x1 tile [row][k], pad 40 (16B-aligned rows)
    __shared__ unsigned short Bs[128 * 40];  // W2 tile  [ko ][k]
    __shared__ float rx[128], ry[128];       // per (iLocal*32+j)

    // rx/ry: normalized rel positions for this block's 4 i's x 32 j's
    if (t < 128) {
        int iL = t >> 5, j = t & 31;
        int ig = (s << 5) + (rb << 2) + iL;
        int jg = (s << 5) + j;
        float dx = curr[jg * 2] - curr[ig * 2];
        float dy = curr[jg * 2 + 1] - curr[ig * 2 + 1];
        float den = fmaxf(sqrtf(dx * dx + dy * dy), 1e-12f);
        rx[t] = dx / den; ry[t] = dy / den;
    }
    __syncthreads();

    f32x4 acc[4][4];
#pragma unroll
    for (int a = 0; a < 4; a++)
#pragma unroll
        for (int b = 0; b < 4; b++) acc[a][b] = (f32x4){0.f, 0.f, 0.f, 0.f};

    int r0 = t >> 3, c4 = (t & 7) << 2;     // A-build: 32 rows/pass, 4 k each
    int bn = t >> 1, bk = (t & 1) << 4;     // B-stage: row, 16-k half

    for (int kt = 0; kt < 512; kt += 32) {
        // build A tile: x1[r][kk] = relu(Hp[s,j,kg] + rx*Mp0 + ry*Mp1 + c1) -> bf16
#pragma unroll
        for (int p = 0; p < 4; p++) {
            int rr = r0 + (p << 5);
            int j = rr & 31;
            int kg = kt + c4;
            float4 hv = *(const float4*)(Hp + (((s << 5) + j) << 9) + kg);
            float4 m0 = *(const float4*)(Mp + kg);
            float4 m1 = *(const float4*)(Mp + 512 + kg);
            float4 cc = *(const float4*)(c1 + kg);
            float rxv = rx[rr], ryv = ry[rr];
            float v0 = fmaxf(hv.x + rxv * m0.x + ryv * m1.x + cc.x, 0.f);
            float v1 = fmaxf(hv.y + rxv * m0.y + ryv * m1.y + cc.y, 0.f);
            float v2 = fmaxf(hv.z + rxv * m0.z + ryv * m1.z + cc.z, 0.f);
            float v3 = fmaxf(hv.w + rxv * m0.w + ryv * m1.w + cc.w, 0.f);
            unsigned int u0 = (unsigned int)f2bf(v0) | ((unsigned int)f2bf(v1) << 16);
            unsigned int u1 = (unsigned int)f2bf(v2) | ((unsigned int)f2bf(v3) << 16);
            *(uint2*)(&As[rr * 40 + c4]) = make_uint2(u0, u1);
        }
        // stage B tile: Bs[n][kk] = W2bf[koBase+n][kt+kk]  (16 bf16 = 32B per thread)
        {
            const unsigned short* src = W2bf + (((koBase + bn) << 9) + kt + bk);
            uint4 w0 = *(const uint4*)src;
            uint4 w1 = *(const uint4*)(src + 8);
            *(uint4*)(&Bs[bn * 40 + bk]) = w0;
            *(uint4*)(&Bs[bn * 40 + bk + 8]) = w1;
        }
        __syncthreads();
#pragma unroll
        for (int a = 0; a < 4; a++) {
            short8 aF = *(const short8*)(&As[(qrow + (a << 4) + l15) * 40 + (quad << 3)]);
#pragma unroll
            for (int b = 0; b < 4; b++) {
                short8 bF = *(const short8*)(&Bs[(qcol + (b << 4) + l15) * 40 + (quad << 3)]);
                acc[a][b] = __builtin_amdgcn_mfma_f32_16x16x32_bf16(aF, bF, acc[a][b], 0, 0, 0);
            }
        }
        __syncthreads();
    }

    // epilogue: max over j (rows), then +bias, relu, write.
    // tile a, lane: row m = qrow + a*16 + quad*4 + reg; a in {0,1} -> iL0, {2,3} -> iL0+1
    float mx0[4], mx1[4];
#pragma unroll
    for (int b = 0; b < 4; b++) {
        float m = 0.f;  // relu floor: max >= 0 pre-bias is NOT valid; do true max
        m = acc[0][b].x;
#pragma unroll
        for (int a = 0; a < 2; a++) {
            m = fmaxf(m, acc[a][b].x); m = fmaxf(m, acc[a][b].y);
            m = fmaxf(m, acc[a][b].z); m = fmaxf(m, acc[a][b].w);
        }
        m = fmaxf(m, __shfl_xor(m, 16));
        m = fmaxf(m, __shfl_xor(m, 32));
        mx0[b] = m;
        float n = acc[2][b].x;
#pragma unroll
        for (int a = 2; a < 4; a++) {
            n = fmaxf(n, acc[a][b].x); n = fmaxf(n, acc[a][b].y);
            n = fmaxf(n, acc[a][b].z); n = fmaxf(n, acc[a][b].w);
        }
        n = fmaxf(n, __shfl_xor(n, 16));
        n = fmaxf(n, __shfl_xor(n, 32));
        mx1[b] = n;
    }
    // quad q writes col-tile b=q; col = koBase + qcol + q*16 + l15
    float v0 = (quad == 0) ? mx0[0] : (quad == 1) ? mx0[1] : (quad == 2) ? mx0[2] : mx0[3];
    float v1 = (quad == 0) ? mx1[0] : (quad == 1) ? mx1[1] : (quad == 2) ? mx1[2] : mx1[3];
    int col = koBase + qcol + (quad << 4) + l15;
    int i0 = (rb << 2) + ((wv >> 1) << 1);
    int si0 = (s << 5) + i0;
    float bias = c2v[col];
    pool[si0 * 1024 + col] = fmaxf(v0 + bias, 0.f);
    pool[(si0 + 1) * 1024 + col] = fmaxf(v1 + bias, 0.f);
}

// m1: dh1 = relu(bn(concat(h2,pool) @ m1_W.T + b)).  Block = 16 rows x 256 ko, K=1152.
__global__ __launch_bounds__(256) void k_m1(
    const float* __restrict__ h2buf, const float* __restrict__ pool,
    const float* __restrict__ M1t, const float* __restrict__ cm1,
    float* __restrict__ dh1) {
    int rowBase = blockIdx.y << 4;
    int koBase = blockIdx.x << 8;
    int t = threadIdx.x;
    int lane = t & 63, wv = t >> 6;
    int j0 = wv << 2;                 // 4 rows per wave
    int ko = koBase + (lane << 2);
    __shared__ float xs[64][20];
    float acc[4][4];
#pragma unroll
    for (int a = 0; a < 4; a++)
#pragma unroll
        for (int b = 0; b < 4; b++) acc[a][b] = 0.f;

    for (int kt = 0; kt < 1152; kt += 64) {
#pragma unroll
        for (int u = 0; u < 4; u++) {
            int lin = t + (u << 8);   // 64 kk x 16 rows
            int j = lin >> 6, kk = lin & 63;
            int jg = rowBase + j, kg = kt + kk;
            xs[kk][j] = (kg < 128) ? h2buf[jg * 128 + kg] : pool[jg * 1024 + (kg - 128)];
        }
        __syncthreads();
#pragma unroll 4
        for (int kk = 0; kk < 64; kk++) {
            float4 w = *(const float4*)(M1t + (kt + kk) * 1024 + ko);
            float4 xa = *(const float4*)(&xs[kk][j0]);
            float xv[4] = {xa.x, xa.y, xa.z, xa.w};
#pragma unroll
            for (int a = 0; a < 4; a++) {
                acc[a][0] = fmaf(xv[a], w.x, acc[a][0]);
                acc[a][1] = fmaf(xv[a], w.y, acc[a][1]);
                acc[a][2] = fmaf(xv[a], w.z, acc[a][2]);
                acc[a][3] = fmaf(xv[a], w.w, acc[a][3]);
            }
        }
        __syncthreads();
    }
    float4 cc = *(const float4*)(cm1 + ko);
#pragma unroll
    for (int a = 0; a < 4; a++) {
        int jg = rowBase + j0 + a;
        float4 o = make_float4(fmaxf(acc[a][0] + cc.x, 0.f), fmaxf(acc[a][1] + cc.y, 0.f),
                               fmaxf(acc[a][2] + cc.z, 0.f), fmaxf(acc[a][3] + cc.w, 0.f));
        *(float4*)(dh1 + jg * 1024 + ko) = o;
    }
}

// m2: h_next = relu(bn(dh1 @ m2_W.T + b)).  Block = 8 rows x 128 ko, K=1024.
__global__ __launch_bounds__(256) void k_m2(
    const float* __restrict__ dh1, const float* __restrict__ M2t,
    const float* __restrict__ cm2, float* __restrict__ h_st) {
    int rowBase = blockIdx.x << 3;
    int t = threadIdx.x;
    int ko = t & 127, rg = t >> 7;    // rg 0..1 -> rows rg*4..rg*4+3
    __shared__ float xs[8][1024];
#pragma unroll
    for (int u = 0; u < 32; u++) {
        int lin = t + (u << 8);
        int r = lin >> 10, ki = lin & 1023;
        xs[r][ki] = dh1[(rowBase + r) * 1024 + ki];
    }
    __syncthreads();
    float acc[4] = {0.f, 0.f, 0.f, 0.f};
    for (int ki = 0; ki < 1024; ki += 4) {
        float w0 = M2t[(ki + 0) * 128 + ko];
        float w1 = M2t[(ki + 1) * 128 + ko];
        float w2 = M2t[(ki + 2) * 128 + ko];
        float w3 = M2t[(ki + 3) * 128 + ko];
#pragma unroll
        for (int q = 0; q < 4; q++) {
            float4 xv = *(const float4*)(&xs[rg * 4 + q][ki]);
            acc[q] = fmaf(xv.x, w0, fmaf(xv.y, w1, fmaf(xv.z, w2, fmaf(xv.w, w3, acc[q]))));
        }
    }
    float c = cm2[ko];
#pragma unroll
    for (int q = 0; q < 4; q++)
        h_st[(rowBase + rg * 4 + q) * 128 + ko] = fmaxf(acc[q] + c, 0.f);
}

// ---------------- launch ----------------

extern "C" void kernel_launch(void* const* d_in, const int* in_sizes, int n_in,
                              void* d_out, int out_size, void* d_ws, size_t ws_size,
                              hipStream_t stream) {
    const float* last_pos     = (const float*)d_in[0];
    const float* last_pos_rel = (const float*)d_in[1];
    const float* h0   = (const float*)d_in[2];
    const float* c0   = (const float*)d_in[3];
    const float* emb_W = (const float*)d_in[5];
    const float* emb_b = (const float*)d_in[6];
    const float* lstm_Wih = (const float*)d_in[7];
    const float* lstm_Whh = (const float*)d_in[8];
    const float* lstm_bih = (const float*)d_in[9];
    const float* lstm_bhh = (const float*)d_in[10];
    const float* pos_W = (const float*)d_in[11];
    const float* pos_b = (const float*)d_in[12];
    const float* sp_W  = (const float*)d_in[13];
    const float* sp_b  = (const float*)d_in[14];
    const float* pp1_W = (const float*)d_in[15];
    const float* pp1_b = (const float*)d_in[16];
    const float* pp1_g = (const float*)d_in[17];
    const float* pp1_be= (const float*)d_in[18];
    const float* pp2_W = (const float*)d_in[19];
    const float* pp2_b = (const float*)d_in[20];
    const float* pp2_g = (const float*)d_in[21];
    const float* pp2_be= (const float*)d_in[22];
    const float* m1_W  = (const float*)d_in[23];
    const float* m1_b  = (const float*)d_in[24];
    const float* m1_g  = (const float*)d_in[25];
    const float* m1_be = (const float*)d_in[26];
    const float* m2_W  = (const float*)d_in[27];
    const float* m2_b  = (const float*)d_in[28];
    const float* m2_g  = (const float*)d_in[29];
    const float* m2_be = (const float*)d_in[30];
    float* out = (float*)d_out;

    float* p = (float*)d_ws;
    float* WgT  = p; p += 192 * 512;
    float* bg   = p; p += 512;
    float* Wh1T = p; p += 128 * 512;
    float* Mp   = p; p += 2 * 512;
    float* c1   = p; p += 512;
    unsigned short* W2bf = (unsigned short*)p; p += 512 * 1024 / 2;
    float* c2v  = p; p += 1024;
    float* M1t  = p; p += 1152 * 1024;
    float* cm1  = p; p += 1024;
    float* M2t  = p; p += 1024 * 128;
    float* cm2  = p; p += 128;
    float* h_st = p; p += 1024 * 128;
    float* c_st = p; p += 1024 * 128;
    float* h2b  = p; p += 1024 * 128;
    float* curr = p; p += 1024 * 2;
    float* din  = p; p += 1024 * 64;
    float* Hp   = p; p += 1024 * 512;
    float* pool = p; p += 1024 * 1024;
    float* dh1  = p; p += 1024 * 1024;

    pre_lstm<<<384, 256, 0, stream>>>(lstm_Wih, lstm_Whh, lstm_bih, lstm_bhh, WgT, bg);
    pre_wh1<<<256, 256, 0, stream>>>(pp1_W, pp1_g, Wh1T);
    pre_mp<<<2, 256, 0, stream>>>(sp_W, sp_b, pp1_W, pp1_b, pp1_g, pp1_be, Mp, c1);
    pre_w2bf<<<2048, 256, 0, stream>>>(pp2_W, pp2_b, pp2_g, pp2_be, W2bf, c2v);
    pre_scaleT<<<4608, 256, 0, stream>>>(m1_W, m1_b, m1_g, m1_be, M1t, cm1, 1152, 10);
    pre_scaleT<<<512, 256, 0, stream>>>(m2_W, m2_b, m2_g, m2_be, M2t, cm2, 1024, 7);
    pre_init<<<512, 256, 0, stream>>>(last_pos, last_pos_rel, h0, c0, emb_W, emb_b,
                                      h_st, c_st, curr, din);

    for (int t = 0; t < 12; t++) {
        k_lstm<<<1024, 512, 0, stream>>>(WgT, bg, h_st, c_st, din, curr, h2b,
                                         pos_W, pos_b, emb_W, emb_b, out + t * 2048);
        if (t == 11) break;  // last step only needs rel_pos
        k_hpp1<<<1024, 512, 0, stream>>>(h2b, Wh1T, Hp);
        k_pool_mfma<<<dim3(8, 8, 32), 256, 0, stream>>>(Hp, Mp, c1, W2bf, c2v, curr, pool);
        k_m1<<<dim3(4, 64), 256, 0, stream>>>(h2b, pool, M1t, cm1, dh1);
        k_m2<<<128, 256, 0, stream>>>(dh1, M2t, cm2, h_st);
    }
}

// Round 3
// 1788.103 us; speedup vs baseline: 4.1028x; 1.6066x over previous
//
#include <hip/hip_runtime.h>
#include <hip/hip_bf16.h>
#include <math.h>

#define DEVFN __device__ __forceinline__

constexpr float BN_INV = 0.99999500003749971f; // 1/sqrt(1+1e-5)

DEVFN float sigm(float x) { return 1.0f / (1.0f + expf(-x)); }

DEVFN unsigned short f2bf(float f) {
    __hip_bfloat16 b = __float2bfloat16(f);
    return *reinterpret_cast<unsigned short*>(&b);
}
DEVFN float bf2f(unsigned short u) {
    unsigned int x = ((unsigned int)u) << 16;
    return *reinterpret_cast<float*>(&x);
}
DEVFN void splitf(float v, unsigned short& h, unsigned short& l) {
    h = f2bf(v);
    l = f2bf(v - bf2f(h));
}
DEVFN unsigned int pack2(unsigned short a, unsigned short b) {
    return (unsigned int)a | ((unsigned int)b << 16);
}

typedef __attribute__((ext_vector_type(8))) short short8;  // 8 bf16 = 4 VGPRs
typedef __attribute__((ext_vector_type(4))) float f32x4;

// ---------------- precompute kernels (run every call; ws is re-poisoned) ----------------

__global__ void pre_lstm(const float* __restrict__ Wih, const float* __restrict__ Whh,
                         const float* __restrict__ bih, const float* __restrict__ bhh,
                         float* __restrict__ WgT, float* __restrict__ bg) {
    int idx = blockIdx.x * blockDim.x + threadIdx.x;   // 192*512
    int k = idx >> 9, t = idx & 511;
    WgT[idx] = (k < 64) ? Wih[t * 64 + k] : Whh[t * 128 + (k - 64)];
    if (idx < 512) bg[idx] = bih[idx] + bhh[idx];
}

// pp1 h-part, transposed + BN scale folded: Wh1T[h*512+k] = pp1_W[k,64+h]*BN_INV*pp1_g[k]
__global__ void pre_wh1(const float* __restrict__ pp1W, const float* __restrict__ pp1g,
                        float* __restrict__ Wh1T) {
    int idx = blockIdx.x * blockDim.x + threadIdx.x;   // 128*512
    int h = idx >> 9, k = idx & 511;
    Wh1T[idx] = pp1W[k * 192 + 64 + h] * (BN_INV * pp1g[k]);
}

// Mp[d*512+k] = (sp_W[:,d] . pp1_W[k,:64]) * s1;  c1[k] = ((sp_b . pp1_W[k,:64]) + pp1_b)*s1 + pp1_be
__global__ void pre_mp(const float* __restrict__ spW, const float* __restrict__ spb,
                       const float* __restrict__ pp1W, const float* __restrict__ pp1b,
                       const float* __restrict__ pp1g, const float* __restrict__ pp1be,
                       float* __restrict__ Mp, float* __restrict__ c1) {
    int k = blockIdx.x * blockDim.x + threadIdx.x;     // 512
    float m0 = 0.f, m1 = 0.f, c0 = 0.f;
    for (int e = 0; e < 64; e++) {
        float w = pp1W[k * 192 + e];
        m0 += spW[e * 2] * w; m1 += spW[e * 2 + 1] * w; c0 += spb[e] * w;
    }
    float s = BN_INV * pp1g[k];
    Mp[k] = m0 * s; Mp[512 + k] = m1 * s;
    c1[k] = (c0 + pp1b[k]) * s + pp1be[k];
}

// pp2 weights: scale+convert to bf16 (layout already [ko][ki], ki contiguous).
__global__ void pre_w2bf(const float* __restrict__ W, const float* __restrict__ b,
                         const float* __restrict__ g, const float* __restrict__ be,
                         unsigned short* __restrict__ Wbf, float* __restrict__ cv) {
    int idx = blockIdx.x * blockDim.x + threadIdx.x;   // 1024*512
    int ko = idx >> 9;
    float s = BN_INV * g[ko];
    Wbf[idx] = f2bf(W[idx] * s);
    if (idx < 1024) cv[idx] = b[idx] * s + be[idx];
}

// m1 weights split hi/lo bf16, BN folded. Layout [ko][1152] native.
__global__ void pre_w1split(const float* __restrict__ W, const float* __restrict__ b,
                            const float* __restrict__ g, const float* __restrict__ be,
                            unsigned short* __restrict__ Wh, unsigned short* __restrict__ Wl,
                            float* __restrict__ cv) {
    int idx = blockIdx.x * blockDim.x + threadIdx.x;   // 1024*1152
    int ko = idx / 1152;
    float s = BN_INV * g[ko];
    unsigned short h, l;
    splitf(W[idx] * s, h, l);
    Wh[idx] = h; Wl[idx] = l;
    if (idx < 1024) {
        float s2 = BN_INV * g[idx];
        cv[idx] = b[idx] * s2 + be[idx];
    }
}

// m2 weights split hi/lo bf16. Layout [128][1024] native.
__global__ void pre_w2split(const float* __restrict__ W, const float* __restrict__ b,
                            const float* __restrict__ g, const float* __restrict__ be,
                            unsigned short* __restrict__ Wh, unsigned short* __restrict__ Wl,
                            float* __restrict__ cv) {
    int idx = blockIdx.x * blockDim.x + threadIdx.x;   // 128*1024
    int ko = idx >> 10;
    float s = BN_INV * g[ko];
    unsigned short h, l;
    splitf(W[idx] * s, h, l);
    Wh[idx] = h; Wl[idx] = l;
    if (idx < 128) {
        float s2 = BN_INV * g[idx];
        cv[idx] = b[idx] * s2 + be[idx];
    }
}

__global__ void pre_init(const float* __restrict__ lp, const float* __restrict__ lpr,
                         const float* __restrict__ h0, const float* __restrict__ c0,
                         const float* __restrict__ embW, const float* __restrict__ embb,
                         float* __restrict__ h_st, float* __restrict__ c_st,
                         float* __restrict__ curr, float* __restrict__ din) {
    int idx = blockIdx.x * blockDim.x + threadIdx.x;   // 1024*128
    h_st[idx] = h0[idx];
    c_st[idx] = c0[idx];
    if (idx < 1024 * 2) curr[idx] = lp[idx];
    if (idx < 1024 * 64) {
        int n = idx >> 6, e = idx & 63;
        din[idx] = fmaf(lpr[n * 2], embW[e * 2], fmaf(lpr[n * 2 + 1], embW[e * 2 + 1], embb[e]));
    }
}

// ---------------- per-step kernels ----------------

// Fused: LSTM cell (4 peds/block) + rel_pos + curr + din2 + preds + Hp (=h2@Wh1T).
// h2 stored pre-split (hi/lo bf16) for the m1 MFMA consumer.
__global__ __launch_bounds__(512) void k_lstm(
    const float* __restrict__ WgT, const float* __restrict__ bg,
    float* __restrict__ h_st, float* __restrict__ c_st,
    float* __restrict__ din, float* __restrict__ curr,
    unsigned short* __restrict__ h2h, unsigned short* __restrict__ h2l,
    const float* __restrict__ posW, const float* __restrict__ posb,
    const float* __restrict__ embW, const float* __restrict__ embb,
    const float* __restrict__ Wh1T, float* __restrict__ Hp, int doHp,
    float* __restrict__ preds) {
    int n0 = blockIdx.x << 2;
    int t = threadIdx.x;
    __shared__ float xs[4][256];
    __shared__ float gates[4][512];
    __shared__ float h2s[4][128];
    __shared__ float rp[4][2];
#pragma unroll
    for (int u = 0; u < 2; u++) {
        int lin = t + (u << 9);
        int r = lin >> 8, k = lin & 255;
        float v = 0.f;
        if (k < 64) v = din[(n0 + r) * 64 + k];
        else if (k < 192) v = h_st[(n0 + r) * 128 + (k - 64)];
        xs[r][k] = v;
    }
    __syncthreads();
    float a0 = bg[t], a1 = a0, a2 = a0, a3 = a0;
#pragma unroll 4
    for (int k = 0; k < 192; k++) {
        float w = WgT[(k << 9) + t];
        a0 = fmaf(xs[0][k], w, a0);
        a1 = fmaf(xs[1][k], w, a1);
        a2 = fmaf(xs[2][k], w, a2);
        a3 = fmaf(xs[3][k], w, a3);
    }
    gates[0][t] = a0; gates[1][t] = a1; gates[2][t] = a2; gates[3][t] = a3;
    __syncthreads();
    {
        int r = t >> 7, hx = t & 127;
        float ig = sigm(gates[r][hx]);
        float fg = sigm(gates[r][128 + hx]);
        float gg = tanhf(gates[r][256 + hx]);
        float og = sigm(gates[r][384 + hx]);
        float c2 = fmaf(fg, c_st[(n0 + r) * 128 + hx], ig * gg);
        float h2 = og * tanhf(c2);
        c_st[(n0 + r) * 128 + hx] = c2;
        unsigned short sh, sl;
        splitf(h2, sh, sl);
        h2h[(n0 + r) * 128 + hx] = sh;
        h2l[(n0 + r) * 128 + hx] = sl;
        h2s[r][hx] = h2;
    }
    __syncthreads();
    int wv = t >> 6, l = t & 63;
    if (wv < 4) {
        float p0 = fmaf(h2s[wv][l], posW[l], h2s[wv][l + 64] * posW[l + 64]);
        float p1 = fmaf(h2s[wv][l], posW[128 + l], h2s[wv][l + 64] * posW[192 + l]);
#pragma unroll
        for (int off = 32; off > 0; off >>= 1) {
            p0 += __shfl_down(p0, off, 64);
            p1 += __shfl_down(p1, off, 64);
        }
        if (l == 0) { rp[wv][0] = p0 + posb[0]; rp[wv][1] = p1 + posb[1]; }
    }
    __syncthreads();
    if (t < 256) {
        int r = t >> 6, e = t & 63;
        float r0 = rp[r][0], r1 = rp[r][1];
        din[(n0 + r) * 64 + e] = fmaf(r0, embW[e * 2], fmaf(r1, embW[e * 2 + 1], embb[e]));
        if (e == 0) {
            preds[(n0 + r) * 2] = r0; preds[(n0 + r) * 2 + 1] = r1;
            curr[(n0 + r) * 2] += r0; curr[(n0 + r) * 2 + 1] += r1;
        }
    }
    if (doHp) {
        float q0 = 0.f, q1 = 0.f, q2 = 0.f, q3 = 0.f;
#pragma unroll 4
        for (int h = 0; h < 128; h++) {
            float w = Wh1T[(h << 9) + t];
            q0 = fmaf(h2s[0][h], w, q0);
            q1 = fmaf(h2s[1][h], w, q1);
            q2 = fmaf(h2s[2][h], w, q2);
            q3 = fmaf(h2s[3][h], w, q3);
        }
        Hp[((n0 + 0) << 9) + t] = q0;
        Hp[((n0 + 1) << 9) + t] = q1;
        Hp[((n0 + 2) << 9) + t] = q2;
        Hp[((n0 + 3) << 9) + t] = q3;
    }
}

// pp2 GEMM + max-pool via bf16 MFMA (unchanged math; pool now stored split hi/lo).
__global__ __launch_bounds__(256) void k_pool_mfma(
    const float* __restrict__ Hp, const float* __restrict__ Mp,
    const float* __restrict__ c1, const unsigned short* __restrict__ W2bf,
    const float* __restrict__ c2v, const float* __restrict__ curr,
    unsigned short* __restrict__ poolh, unsigned short* __restrict__ pooll) {
    int s = blockIdx.z;
    int rb = blockIdx.y;               // i-group: global i = rb*4 .. rb*4+3
    int koBase = blockIdx.x << 7;
    int t = threadIdx.x;
    int lane = t & 63, wv = t >> 6;
    int quad = lane >> 4, l15 = lane & 15;
    int qrow = (wv >> 1) << 6;
    int qcol = (wv & 1) << 6;

    __shared__ unsigned short As[128 * 40];
    __shared__ unsigned short Bs[128 * 40];
    __shared__ float rx[128], ry[128];

    if (t < 128) {
        int iL = t >> 5, j = t & 31;
        int ig = (s << 5) + (rb << 2) + iL;
        int jg = (s << 5) + j;
        float dx = curr[jg * 2] - curr[ig * 2];
        float dy = curr[jg * 2 + 1] - curr[ig * 2 + 1];
        float den = fmaxf(sqrtf(dx * dx + dy * dy), 1e-12f);
        rx[t] = dx / den; ry[t] = dy / den;
    }
    __syncthreads();

    f32x4 acc[4][4];
#pragma unroll
    for (int a = 0; a < 4; a++)
#pragma unroll
        for (int b = 0; b < 4; b++) acc[a][b] = (f32x4){0.f, 0.f, 0.f, 0.f};

    int r0 = t >> 3, c4 = (t & 7) << 2;
    int bn = t >> 1, bk = (t & 1) << 4;

    for (int kt = 0; kt < 512; kt += 32) {
#pragma unroll
        for (int p = 0; p < 4; p++) {
            int rr = r0 + (p << 5);
            int j = rr & 31;
            int kg = kt + c4;
            float4 hv = *(const float4*)(Hp + (((s << 5) + j) << 9) + kg);
            float4 m0 = *(const float4*)(Mp + kg);
            float4 m1 = *(const float4*)(Mp + 512 + kg);
            float4 cc = *(const float4*)(c1 + kg);
            float rxv = rx[rr], ryv = ry[rr];
            float v0 = fmaxf(hv.x + rxv * m0.x + ryv * m1.x + cc.x, 0.f);
            float v1 = fmaxf(hv.y + rxv * m0.y + ryv * m1.y + cc.y, 0.f);
            float v2 = fmaxf(hv.z + rxv * m0.z + ryv * m1.z + cc.z, 0.f);
            float v3 = fmaxf(hv.w + rxv * m0.w + ryv * m1.w + cc.w, 0.f);
            unsigned int u0 = pack2(f2bf(v0), f2bf(v1));
            unsigned int u1 = pack2(f2bf(v2), f2bf(v3));
            *(uint2*)(&As[rr * 40 + c4]) = make_uint2(u0, u1);
        }
        {
            const unsigned short* src = W2bf + (((koBase + bn) << 9) + kt + bk);
            uint4 w0 = *(const uint4*)src;
            uint4 w1 = *(const uint4*)(src + 8);
            *(uint4*)(&Bs[bn * 40 + bk]) = w0;
            *(uint4*)(&Bs[bn * 40 + bk + 8]) = w1;
        }
        __syncthreads();
#pragma unroll
        for (int a = 0; a < 4; a++) {
            short8 aF = *(const short8*)(&As[(qrow + (a << 4) + l15) * 40 + (quad << 3)]);
#pragma unroll
            for (int b = 0; b < 4; b++) {
                short8 bF = *(const short8*)(&Bs[(qcol + (b << 4) + l15) * 40 + (quad << 3)]);
                acc[a][b] = __builtin_amdgcn_mfma_f32_16x16x32_bf16(aF, bF, acc[a][b], 0, 0, 0);
            }
        }
        __syncthreads();
    }

    float mx0[4], mx1[4];
#pragma unroll
    for (int b = 0; b < 4; b++) {
        float m = acc[0][b].x;
#pragma unroll
        for (int a = 0; a < 2; a++) {
            m = fmaxf(m, acc[a][b].x); m = fmaxf(m, acc[a][b].y);
            m = fmaxf(m, acc[a][b].z); m = fmaxf(m, acc[a][b].w);
        }
        m = fmaxf(m, __shfl_xor(m, 16));
        m = fmaxf(m, __shfl_xor(m, 32));
        mx0[b] = m;
        float n = acc[2][b].x;
#pragma unroll
        for (int a = 2; a < 4; a++) {
            n = fmaxf(n, acc[a][b].x); n = fmaxf(n, acc[a][b].y);
            n = fmaxf(n, acc[a][b].z); n = fmaxf(n, acc[a][b].w);
        }
        n = fmaxf(n, __shfl_xor(n, 16));
        n = fmaxf(n, __shfl_xor(n, 32));
        mx1[b] = n;
    }
    float v0 = (quad == 0) ? mx0[0] : (quad == 1) ? mx0[1] : (quad == 2) ? mx0[2] : mx0[3];
    float v1 = (quad == 0) ? mx1[0] : (quad == 1) ? mx1[1] : (quad == 2) ? mx1[2] : mx1[3];
    int col = koBase + qcol + (quad << 4) + l15;
    int i0 = (rb << 2) + ((wv >> 1) << 1);
    int si0 = (s << 5) + i0;
    float bias = c2v[col];
    float w0 = fmaxf(v0 + bias, 0.f);
    float w1 = fmaxf(v1 + bias, 0.f);
    unsigned short h0, l0, h1, l1;
    splitf(w0, h0, l0); splitf(w1, h1, l1);
    poolh[si0 * 1024 + col] = h0; pooll[si0 * 1024 + col] = l0;
    poolh[(si0 + 1) * 1024 + col] = h1; pooll[(si0 + 1) * 1024 + col] = l1;
}

// m1 via bf16x3 MFMA (fp32-grade): D = X(hi+lo) . W(hi+lo), drop lo*lo.
// X = concat(h2, pool) pre-split. Block: 64 rows x 64 ko, K=1152. Grid 16x16.
__global__ __launch_bounds__(256) void k_m1_mfma(
    const unsigned short* __restrict__ h2h, const unsigned short* __restrict__ h2l,
    const unsigned short* __restrict__ poolh, const unsigned short* __restrict__ pooll,
    const unsigned short* __restrict__ M1h, const unsigned short* __restrict__ M1l,
    const float* __restrict__ cm1,
    unsigned short* __restrict__ dh1h, unsigned short* __restrict__ dh1l) {
    int rowBase = blockIdx.y << 6;
    int koBase = blockIdx.x << 6;
    int t = threadIdx.x;
    int lane = t & 63, wv = t >> 6;
    int quad = lane >> 4, l15 = lane & 15;
    int qrow = (wv >> 1) << 5, qcol = (wv & 1) << 5;
    __shared__ unsigned short Ah[64 * 40], Al[64 * 40], Bh[64 * 40], Bl[64 * 40];
    f32x4 acc[2][2];
#pragma unroll
    for (int a = 0; a < 2; a++)
#pragma unroll
        for (int b = 0; b < 2; b++) acc[a][b] = (f32x4){0.f, 0.f, 0.f, 0.f};

    int ar = t >> 2, ak = (t & 3) << 3;   // 64 rows x 32 k, 8 elems/thread

    for (int kt = 0; kt < 1152; kt += 32) {
        {
            const unsigned short* sH;
            const unsigned short* sL;
            int off;
            if (kt < 128) {
                off = (rowBase + ar) * 128 + kt + ak;
                sH = h2h; sL = h2l;
            } else {
                off = (rowBase + ar) * 1024 + (kt - 128) + ak;
                sH = poolh; sL = pooll;
            }
            *(uint4*)&Ah[ar * 40 + ak] = *(const uint4*)(sH + off);
            *(uint4*)&Al[ar * 40 + ak] = *(const uint4*)(sL + off);
        }
        {
            int boff = (koBase + ar) * 1152 + kt + ak;
            *(uint4*)&Bh[ar * 40 + ak] = *(const uint4*)(M1h + boff);
            *(uint4*)&Bl[ar * 40 + ak] = *(const uint4*)(M1l + boff);
        }
        __syncthreads();
#pragma unroll
        for (int a = 0; a < 2; a++) {
            int aoff = (qrow + (a << 4) + l15) * 40 + (quad << 3);
            short8 aH = *(const short8*)(&Ah[aoff]);
            short8 aL = *(const short8*)(&Al[aoff]);
#pragma unroll
            for (int b = 0; b < 2; b++) {
                int boff = (qcol + (b << 4) + l15) * 40 + (quad << 3);
                short8 bH = *(const short8*)(&Bh[boff]);
                short8 bL = *(const short8*)(&Bl[boff]);
                acc[a][b] = __builtin_amdgcn_mfma_f32_16x16x32_bf16(aH, bH, acc[a][b], 0, 0, 0);
                acc[a][b] = __builtin_amdgcn_mfma_f32_16x16x32_bf16(aH, bL, acc[a][b], 0, 0, 0);
                acc[a][b] = __builtin_amdgcn_mfma_f32_16x16x32_bf16(aL, bH, acc[a][b], 0, 0, 0);
            }
        }
        __syncthreads();
    }
#pragma unroll
    for (int b = 0; b < 2; b++) {
        int col = koBase + qcol + (b << 4) + l15;
        float bias = cm1[col];
#pragma unroll
        for (int a = 0; a < 2; a++) {
#pragma unroll
            for (int rg = 0; rg < 4; rg++) {
                int row = rowBase + qrow + (a << 4) + (quad << 2) + rg;
                float v = fmaxf(acc[a][b][rg] + bias, 0.f);
                unsigned short sh, sl;
                splitf(v, sh, sl);
                dh1h[row * 1024 + col] = sh;
                dh1l[row * 1024 + col] = sl;
            }
        }
    }
}

// m2 via bf16x3 MFMA: D[1024 x 128] = dh1 . W, K=1024. Block: 64 rows x 128 ko. Grid 16.
__global__ __launch_bounds__(256) void k_m2_mfma(
    const unsigned short* __restrict__ dh1h, const unsigned short* __restrict__ dh1l,
    const unsigned short* __restrict__ M2h, const unsigned short* __restrict__ M2l,
    const float* __restrict__ cm2, float* __restrict__ h_st) {
    int rowBase = blockIdx.x << 6;
    int t = threadIdx.x;
    int lane = t & 63, wv = t >> 6;
    int quad = lane >> 4, l15 = lane & 15;
    int qrow = (wv >> 1) << 5;   // 0 or 32
    int qcol = (wv & 1) << 6;    // 0 or 64
    __shared__ unsigned short Ah[64 * 40], Al[64 * 40], Bh[128 * 40], Bl[128 * 40];
    f32x4 acc[2][4];
#pragma unroll
    for (int a = 0; a < 2; a++)
#pragma unroll
        for (int b = 0; b < 4; b++) acc[a][b] = (f32x4){0.f, 0.f, 0.f, 0.f};

    int ar = t >> 2, ak = (t & 3) << 3;   // A: 64 rows x 32 k
    int br = t >> 1, bk = (t & 1) << 4;   // B: 128 ko x 32 k (16 elems/thread)

    for (int kt = 0; kt < 1024; kt += 32) {
        {
            int off = (rowBase + ar) * 1024 + kt + ak;
            *(uint4*)&Ah[ar * 40 + ak] = *(const uint4*)(dh1h + off);
            *(uint4*)&Al[ar * 40 + ak] = *(const uint4*)(dh1l + off);
        }
        {
            int off = br * 1024 + kt + bk;
            *(uint4*)&Bh[br * 40 + bk] = *(const uint4*)(M2h + off);
            *(uint4*)&Bh[br * 40 + bk + 8] = *(const uint4*)(M2h + off + 8);
            *(uint4*)&Bl[br * 40 + bk] = *(const uint4*)(M2l + off);
            *(uint4*)&Bl[br * 40 + bk + 8] = *(const uint4*)(M2l + off + 8);
        }
        __syncthreads();
#pragma unroll
        for (int a = 0; a < 2; a++) {
            int aoff = (qrow + (a << 4) + l15) * 40 + (quad << 3);
            short8 aH = *(const short8*)(&Ah[aoff]);
            short8 aL = *(const short8*)(&Al[aoff]);
#pragma unroll
            for (int b = 0; b < 4; b++) {
                int boff = (qcol + (b << 4) + l15) * 40 + (quad << 3);
                short8 bH = *(const short8*)(&Bh[boff]);
                short8 bL = *(const short8*)(&Bl[boff]);
                acc[a][b] = __builtin_amdgcn_mfma_f32_16x16x32_bf16(aH, bH, acc[a][b], 0, 0, 0);
                acc[a][b] = __builtin_amdgcn_mfma_f32_16x16x32_bf16(aH, bL, acc[a][b], 0, 0, 0);
                acc[a][b] = __builtin_amdgcn_mfma_f32_16x16x32_bf16(aL, bH, acc[a][b], 0, 0, 0);
            }
        }
        __syncthreads();
    }
#pragma unroll
    for (int b = 0; b < 4; b++) {
        int col = qcol + (b << 4) + l15;       // 0..127
        float bias = cm2[col];
#pragma unroll
        for (int a = 0; a < 2; a++) {
#pragma unroll
            for (int rg = 0; rg < 4; rg++) {
                int row = rowBase + qrow + (a << 4) + (quad << 2) + rg;
                h_st[row * 128 + col] = fmaxf(acc[a][b][rg] + bias, 0.f);
            }
        }
    }
}

// ---------------- launch ----------------

extern "C" void kernel_launch(void* const* d_in, const int* in_sizes, int n_in,
                              void* d_out, int out_size, void* d_ws, size_t ws_size,
                              hipStream_t stream) {
    const float* last_pos     = (const float*)d_in[0];
    const float* last_pos_rel = (const float*)d_in[1];
    const float* h0   = (const float*)d_in[2];
    const float* c0   = (const float*)d_in[3];
    const float* emb_W = (const float*)d_in[5];
    const float* emb_b = (const float*)d_in[6];
    const float* lstm_Wih = (const float*)d_in[7];
    const float* lstm_Whh = (const float*)d_in[8];
    const float* lstm_bih = (const float*)d_in[9];
    const float* lstm_bhh = (const float*)d_in[10];
    const float* pos_W = (const float*)d_in[11];
    const float* pos_b = (const float*)d_in[12];
    const float* sp_W  = (const float*)d_in[13];
    const float* sp_b  = (const float*)d_in[14];
    const float* pp1_W = (const float*)d_in[15];
    const float* pp1_b = (const float*)d_in[16];
    const float* pp1_g = (const float*)d_in[17];
    const float* pp1_be= (const float*)d_in[18];
    const float* pp2_W = (const float*)d_in[19];
    const float* pp2_b = (const float*)d_in[20];
    const float* pp2_g = (const float*)d_in[21];
    const float* pp2_be= (const float*)d_in[22];
    const float* m1_W  = (const float*)d_in[23];
    const float* m1_b  = (const float*)d_in[24];
    const float* m1_g  = (const float*)d_in[25];
    const float* m1_be = (const float*)d_in[26];
    const float* m2_W  = (const float*)d_in[27];
    const float* m2_b  = (const float*)d_in[28];
    const float* m2_g  = (const float*)d_in[29];
    const float* m2_be = (const float*)d_in[30];
    float* out = (float*)d_out;

    float* p = (float*)d_ws;
    float* WgT  = p; p += 192 * 512;
    float* bg   = p; p += 512;
    float* Wh1T = p; p += 128 * 512;
    float* Mp   = p; p += 2 * 512;
    float* c1   = p; p += 512;
    unsigned short* W2bf = (unsigned short*)p; p += 512 * 1024 / 2;
    float* c2v  = p; p += 1024;
    unsigned short* M1h = (unsigned short*)p; p += 1024 * 1152 / 2;
    unsigned short* M1l = (unsigned short*)p; p += 1024 * 1152 / 2;
    float* cm1  = p; p += 1024;
    unsigned short* M2h = (unsigned short*)p; p += 128 * 1024 / 2;
    unsigned short* M2l = (unsigned short*)p; p += 128 * 1024 / 2;
    float* cm2  = p; p += 128;
    float* h_st = p; p += 1024 * 128;
    float* c_st = p; p += 1024 * 128;
    unsigned short* h2h = (unsigned short*)p; p += 1024 * 128 / 2;
    unsigned short* h2l = (unsigned short*)p; p += 1024 * 128 / 2;
    float* curr = p; p += 1024 * 2;
    float* din  = p; p += 1024 * 64;
    float* Hp   = p; p += 1024 * 512;
    unsigned short* poolh = (unsigned short*)p; p += 1024 * 1024 / 2;
    unsigned short* pooll = (unsigned short*)p; p += 1024 * 1024 / 2;
    unsigned short* dh1h = (unsigned short*)p; p += 1024 * 1024 / 2;
    unsigned short* dh1l = (unsigned short*)p; p += 1024 * 1024 / 2;

    pre_lstm<<<384, 256, 0, stream>>>(lstm_Wih, lstm_Whh, lstm_bih, lstm_bhh, WgT, bg);
    pre_wh1<<<256, 256, 0, stream>>>(pp1_W, pp1_g, Wh1T);
    pre_mp<<<2, 256, 0, stream>>>(sp_W, sp_b, pp1_W, pp1_b, pp1_g, pp1_be, Mp, c1);
    pre_w2bf<<<2048, 256, 0, stream>>>(pp2_W, pp2_b, pp2_g, pp2_be, W2bf, c2v);
    pre_w1split<<<4608, 256, 0, stream>>>(m1_W, m1_b, m1_g, m1_be, M1h, M1l, cm1);
    pre_w2split<<<512, 256, 0, stream>>>(m2_W, m2_b, m2_g, m2_be, M2h, M2l, cm2);
    pre_init<<<512, 256, 0, stream>>>(last_pos, last_pos_rel, h0, c0, emb_W, emb_b,
                                      h_st, c_st, curr, din);

    for (int t = 0; t < 12; t++) {
        k_lstm<<<256, 512, 0, stream>>>(WgT, bg, h_st, c_st, din, curr, h2h, h2l,
                                        pos_W, pos_b, emb_W, emb_b,
                                        Wh1T, Hp, (t < 11) ? 1 : 0, out + t * 2048);
        if (t == 11) break;
        k_pool_mfma<<<dim3(8, 8, 32), 256, 0, stream>>>(Hp, Mp, c1, W2bf, c2v, curr,
                                                        poolh, pooll);
        k_m1_mfma<<<dim3(16, 16), 256, 0, stream>>>(h2h, h2l, poolh, pooll,
                                                    M1h, M1l, cm1, dh1h, dh1l);
        k_m2_mfma<<<16, 256, 0, stream>>>(dh1h, dh1l, M2h, M2l, cm2, h_st);
    }
}

// Round 4
// 1683.212 us; speedup vs baseline: 4.3585x; 1.0623x over previous
//
#include <hip/hip_runtime.h>
#include <hip/hip_bf16.h>
#include <math.h>

#define DEVFN __device__ __forceinline__

constexpr float BN_INV = 0.99999500003749971f; // 1/sqrt(1+1e-5)

DEVFN float sigm(float x) { return 1.0f / (1.0f + expf(-x)); }

DEVFN unsigned short f2bf(float f) {
    __hip_bfloat16 b = __float2bfloat16(f);
    return *reinterpret_cast<unsigned short*>(&b);
}
DEVFN float bf2f(unsigned short u) {
    unsigned int x = ((unsigned int)u) << 16;
    return *reinterpret_cast<float*>(&x);
}
DEVFN void splitf(float v, unsigned short& h, unsigned short& l) {
    h = f2bf(v);
    l = f2bf(v - bf2f(h));
}
DEVFN unsigned int pack2(unsigned short a, unsigned short b) {
    return (unsigned int)a | ((unsigned int)b << 16);
}

typedef __attribute__((ext_vector_type(8))) short short8;  // 8 bf16 = 4 VGPRs
typedef __attribute__((ext_vector_type(4))) float f32x4;

// async global->LDS, 16B per lane; ldst must be wave-uniform (HW adds lane*16)
#define ASYNC_COPY16(gsrc, ldst)                                                            \
    __builtin_amdgcn_global_load_lds((const __attribute__((address_space(1))) unsigned int*)(gsrc), \
                                     (__attribute__((address_space(3))) unsigned int*)(ldst), 16, 0, 0)

// ---------------- precompute kernels (run every call; ws is re-poisoned) ----------------

__global__ void pre_lstm(const float* __restrict__ Wih, const float* __restrict__ Whh,
                         const float* __restrict__ bih, const float* __restrict__ bhh,
                         float* __restrict__ WgT, float* __restrict__ bg) {
    int idx = blockIdx.x * blockDim.x + threadIdx.x;   // 192*512
    int k = idx >> 9, t = idx & 511;
    WgT[idx] = (k < 64) ? Wih[t * 64 + k] : Whh[t * 128 + (k - 64)];
    if (idx < 512) bg[idx] = bih[idx] + bhh[idx];
}

__global__ void pre_wh1(const float* __restrict__ pp1W, const float* __restrict__ pp1g,
                        float* __restrict__ Wh1T) {
    int idx = blockIdx.x * blockDim.x + threadIdx.x;   // 128*512
    int h = idx >> 9, k = idx & 511;
    Wh1T[idx] = pp1W[k * 192 + 64 + h] * (BN_INV * pp1g[k]);
}

__global__ void pre_mp(const float* __restrict__ spW, const float* __restrict__ spb,
                       const float* __restrict__ pp1W, const float* __restrict__ pp1b,
                       const float* __restrict__ pp1g, const float* __restrict__ pp1be,
                       float* __restrict__ Mp, float* __restrict__ c1) {
    int k = blockIdx.x * blockDim.x + threadIdx.x;     // 512
    float m0 = 0.f, m1 = 0.f, c0 = 0.f;
    for (int e = 0; e < 64; e++) {
        float w = pp1W[k * 192 + e];
        m0 += spW[e * 2] * w; m1 += spW[e * 2 + 1] * w; c0 += spb[e] * w;
    }
    float s = BN_INV * pp1g[k];
    Mp[k] = m0 * s; Mp[512 + k] = m1 * s;
    c1[k] = (c0 + pp1b[k]) * s + pp1be[k];
}

// pp2 weights -> bf16, optionally XOR-swizzled (chunk c of each 64-k tile stored at c^(ko&7))
__global__ void pre_w2bf(const float* __restrict__ W, const float* __restrict__ b,
                         const float* __restrict__ g, const float* __restrict__ be,
                         unsigned short* __restrict__ Wbf, float* __restrict__ cv, int swz) {
    int idx = blockIdx.x * blockDim.x + threadIdx.x;   // 1024*512
    int ko = idx >> 9, k = idx & 511;
    float s = BN_INV * g[ko];
    int outk = swz ? ((k & ~63) | ((((k >> 3) & 7) ^ (ko & 7)) << 3) | (k & 7)) : k;
    Wbf[(ko << 9) + outk] = f2bf(W[idx] * s);
    if (idx < 1024) cv[idx] = b[idx] * s + be[idx];
}

__global__ void pre_w1split(const float* __restrict__ W, const float* __restrict__ b,
                            const float* __restrict__ g, const float* __restrict__ be,
                            unsigned short* __restrict__ Wh, unsigned short* __restrict__ Wl,
                            float* __restrict__ cv) {
    int idx = blockIdx.x * blockDim.x + threadIdx.x;   // 1024*1152
    int ko = idx / 1152;
    float s = BN_INV * g[ko];
    unsigned short h, l;
    splitf(W[idx] * s, h, l);
    Wh[idx] = h; Wl[idx] = l;
    if (idx < 1024) {
        float s2 = BN_INV * g[idx];
        cv[idx] = b[idx] * s2 + be[idx];
    }
}

__global__ void pre_w2split(const float* __restrict__ W, const float* __restrict__ b,
                            const float* __restrict__ g, const float* __restrict__ be,
                            unsigned short* __restrict__ Wh, unsigned short* __restrict__ Wl,
                            float* __restrict__ cv) {
    int idx = blockIdx.x * blockDim.x + threadIdx.x;   // 128*1024
    int ko = idx >> 10;
    float s = BN_INV * g[ko];
    unsigned short h, l;
    splitf(W[idx] * s, h, l);
    Wh[idx] = h; Wl[idx] = l;
    if (idx < 128) {
        float s2 = BN_INV * g[idx];
        cv[idx] = b[idx] * s2 + be[idx];
    }
}

__global__ void pre_init(const float* __restrict__ lp, const float* __restrict__ lpr,
                         const float* __restrict__ h0, const float* __restrict__ c0,
                         const float* __restrict__ embW, const float* __restrict__ embb,
                         float* __restrict__ h_st, float* __restrict__ c_st,
                         float* __restrict__ curr, float* __restrict__ din) {
    int idx = blockIdx.x * blockDim.x + threadIdx.x;   // 1024*128
    h_st[idx] = h0[idx];
    c_st[idx] = c0[idx];
    if (idx < 1024 * 2) curr[idx] = lp[idx];
    if (idx < 1024 * 64) {
        int n = idx >> 6, e = idx & 63;
        din[idx] = fmaf(lpr[n * 2], embW[e * 2], fmaf(lpr[n * 2 + 1], embW[e * 2 + 1], embb[e]));
    }
}

// ---------------- per-step kernels ----------------

// Fused: LSTM cell (4 peds/block) + rel_pos + curr + din2 + preds + Hp (=h2@Wh1T + c1).
__global__ __launch_bounds__(512) void k_lstm(
    const float* __restrict__ WgT, const float* __restrict__ bg,
    float* __restrict__ h_st, float* __restrict__ c_st,
    float* __restrict__ din, float* __restrict__ curr,
    unsigned short* __restrict__ h2h, unsigned short* __restrict__ h2l,
    const float* __restrict__ posW, const float* __restrict__ posb,
    const float* __restrict__ embW, const float* __restrict__ embb,
    const float* __restrict__ Wh1T, const float* __restrict__ c1,
    float* __restrict__ Hp, int doHp,
    float* __restrict__ preds) {
    int n0 = blockIdx.x << 2;
    int t = threadIdx.x;
    __shared__ float xs[4][256];
    __shared__ float gates[4][512];
    __shared__ float h2s[4][128];
    __shared__ float rp[4][2];
#pragma unroll
    for (int u = 0; u < 2; u++) {
        int lin = t + (u << 9);
        int r = lin >> 8, k = lin & 255;
        float v = 0.f;
        if (k < 64) v = din[(n0 + r) * 64 + k];
        else if (k < 192) v = h_st[(n0 + r) * 128 + (k - 64)];
        xs[r][k] = v;
    }
    __syncthreads();
    float a0 = bg[t], a1 = a0, a2 = a0, a3 = a0;
#pragma unroll 4
    for (int k = 0; k < 192; k++) {
        float w = WgT[(k << 9) + t];
        a0 = fmaf(xs[0][k], w, a0);
        a1 = fmaf(xs[1][k], w, a1);
        a2 = fmaf(xs[2][k], w, a2);
        a3 = fmaf(xs[3][k], w, a3);
    }
    gates[0][t] = a0; gates[1][t] = a1; gates[2][t] = a2; gates[3][t] = a3;
    __syncthreads();
    {
        int r = t >> 7, hx = t & 127;
        float ig = sigm(gates[r][hx]);
        float fg = sigm(gates[r][128 + hx]);
        float gg = tanhf(gates[r][256 + hx]);
        float og = sigm(gates[r][384 + hx]);
        float c2 = fmaf(fg, c_st[(n0 + r) * 128 + hx], ig * gg);
        float h2 = og * tanhf(c2);
        c_st[(n0 + r) * 128 + hx] = c2;
        unsigned short sh, sl;
        splitf(h2, sh, sl);
        h2h[(n0 + r) * 128 + hx] = sh;
        h2l[(n0 + r) * 128 + hx] = sl;
        h2s[r][hx] = h2;
    }
    __syncthreads();
    int wv = t >> 6, l = t & 63;
    if (wv < 4) {
        float p0 = fmaf(h2s[wv][l], posW[l], h2s[wv][l + 64] * posW[l + 64]);
        float p1 = fmaf(h2s[wv][l], posW[128 + l], h2s[wv][l + 64] * posW[192 + l]);
#pragma unroll
        for (int off = 32; off > 0; off >>= 1) {
            p0 += __shfl_down(p0, off, 64);
            p1 += __shfl_down(p1, off, 64);
        }
        if (l == 0) { rp[wv][0] = p0 + posb[0]; rp[wv][1] = p1 + posb[1]; }
    }
    __syncthreads();
    if (t < 256) {
        int r = t >> 6, e = t & 63;
        float r0 = rp[r][0], r1 = rp[r][1];
        din[(n0 + r) * 64 + e] = fmaf(r0, embW[e * 2], fmaf(r1, embW[e * 2 + 1], embb[e]));
        if (e == 0) {
            preds[(n0 + r) * 2] = r0; preds[(n0 + r) * 2 + 1] = r1;
            curr[(n0 + r) * 2] += r0; curr[(n0 + r) * 2 + 1] += r1;
        }
    }
    if (doHp) {
        float cc = c1[t];
        float q0 = cc, q1 = cc, q2 = cc, q3 = cc;
#pragma unroll 4
        for (int h = 0; h < 128; h++) {
            float w = Wh1T[(h << 9) + t];
            q0 = fmaf(h2s[0][h], w, q0);
            q1 = fmaf(h2s[1][h], w, q1);
            q2 = fmaf(h2s[2][h], w, q2);
            q3 = fmaf(h2s[3][h], w, q3);
        }
        Hp[((n0 + 0) << 9) + t] = q0;
        Hp[((n0 + 1) << 9) + t] = q1;
        Hp[((n0 + 2) << 9) + t] = q2;
        Hp[((n0 + 3) << 9) + t] = q3;
    }
}

// Build x1 bf16 once per step, XOR-swizzled within each 64-k tile (chunk c at c^(j&7)).
// Block = one (s,i): 32 j rows x 512 k. x1[(s,i,j),k] = relu(Hp[j,k] + rx*Mp0[k] + ry*Mp1[k]).
__global__ __launch_bounds__(256) void k_x1(
    const float* __restrict__ Hp, const float* __restrict__ Mp,
    const float* __restrict__ curr, unsigned short* __restrict__ x1g) {
    int si = blockIdx.x;           // s*32 + i
    int s = si >> 5;
    int t = threadIdx.x;
    __shared__ float rx[32], ry[32];
    __shared__ float m0s[512], m1s[512];
    for (int u = t; u < 512; u += 256) { m0s[u] = Mp[u]; m1s[u] = Mp[512 + u]; }
    if (t < 32) {
        int jg = (s << 5) + t;
        float dx = curr[jg * 2] - curr[si * 2];
        float dy = curr[jg * 2 + 1] - curr[si * 2 + 1];
        float den = fmaxf(sqrtf(dx * dx + dy * dy), 1e-12f);
        rx[t] = dx / den; ry[t] = dy / den;
    }
    __syncthreads();
    int j = t >> 3, c8 = t & 7;
    float rxv = rx[j], ryv = ry[j];
    const float* hp = Hp + (((s << 5) + j) << 9);
    unsigned short* op = x1g + ((size_t)((si << 5) + j) << 9);
    int swz = (c8 ^ (j & 7)) << 3;
#pragma unroll
    for (int kt = 0; kt < 512; kt += 64) {
        int k = kt + (c8 << 3);
        float4 ha = *(const float4*)(hp + k);
        float4 hb = *(const float4*)(hp + k + 4);
        uint4 o;
        o.x = pack2(f2bf(fmaxf(fmaf(rxv, m0s[k + 0], fmaf(ryv, m1s[k + 0], ha.x)), 0.f)),
                    f2bf(fmaxf(fmaf(rxv, m0s[k + 1], fmaf(ryv, m1s[k + 1], ha.y)), 0.f)));
        o.y = pack2(f2bf(fmaxf(fmaf(rxv, m0s[k + 2], fmaf(ryv, m1s[k + 2], ha.z)), 0.f)),
                    f2bf(fmaxf(fmaf(rxv, m0s[k + 3], fmaf(ryv, m1s[k + 3], ha.w)), 0.f)));
        o.z = pack2(f2bf(fmaxf(fmaf(rxv, m0s[k + 4], fmaf(ryv, m1s[k + 4], hb.x)), 0.f)),
                    f2bf(fmaxf(fmaf(rxv, m0s[k + 5], fmaf(ryv, m1s[k + 5], hb.y)), 0.f)));
        o.w = pack2(f2bf(fmaxf(fmaf(rxv, m0s[k + 6], fmaf(ryv, m1s[k + 6], hb.z)), 0.f)),
                    f2bf(fmaxf(fmaf(rxv, m0s[k + 7], fmaf(ryv, m1s[k + 7], hb.w)), 0.f)));
        *(uint4*)(op + kt + swz) = o;
    }
}

// Pure GEMM + max-pool: D[(i,j)][ko] = x1 . W2, K=512, both staged via global_load_lds
// from pre-swizzled global. 128 rows (4i x 32j) x 128 ko per block, BK=64, 4 waves.
__global__ __launch_bounds__(256) void k_pool_g(
    const unsigned short* __restrict__ x1g, const unsigned short* __restrict__ W2bf,
    const float* __restrict__ c2v,
    unsigned short* __restrict__ poolh, unsigned short* __restrict__ pooll) {
    int s = blockIdx.z;
    int rb = blockIdx.y;
    int koBase = blockIdx.x << 7;
    int t = threadIdx.x;
    int lane = t & 63, wv = t >> 6;
    int quad = lane >> 4, l15 = lane & 15;
    int qrow = (wv >> 1) << 6, qcol = (wv & 1) << 6;
    __shared__ unsigned short As[128 * 64];
    __shared__ unsigned short Bs[128 * 64];
    f32x4 acc[4][4];
#pragma unroll
    for (int a = 0; a < 4; a++)
#pragma unroll
        for (int b = 0; b < 4; b++) acc[a][b] = (f32x4){0.f, 0.f, 0.f, 0.f};

    int rowG0 = (s << 10) + (rb << 7);
    int rlane = lane >> 3;            // 0..7 (row within 8-row group)
    int clane = (lane & 7) << 3;      // k-chunk offset (shorts)

    for (int kt = 0; kt < 512; kt += 64) {
#pragma unroll
        for (int u = 0; u < 4; u++) {
            int r = (wv << 5) + (u << 3);
            ASYNC_COPY16(x1g + (size_t)(rowG0 + r + rlane) * 512 + kt + clane, &As[r << 6]);
            ASYNC_COPY16(W2bf + (size_t)(koBase + r + rlane) * 512 + kt + clane, &Bs[r << 6]);
        }
        __syncthreads();
#pragma unroll
        for (int kt2 = 0; kt2 < 2; kt2++) {
            short8 aF[4], bF[4];
#pragma unroll
            for (int a = 0; a < 4; a++) {
                int r = qrow + (a << 4) + l15;
                int pos = ((kt2 << 2) + quad) ^ (r & 7);
                aF[a] = *(const short8*)(&As[(r << 6) + (pos << 3)]);
            }
#pragma unroll
            for (int b = 0; b < 4; b++) {
                int r = qcol + (b << 4) + l15;
                int pos = ((kt2 << 2) + quad) ^ (r & 7);
                bF[b] = *(const short8*)(&Bs[(r << 6) + (pos << 3)]);
            }
#pragma unroll
            for (int a = 0; a < 4; a++)
#pragma unroll
                for (int b = 0; b < 4; b++)
                    acc[a][b] = __builtin_amdgcn_mfma_f32_16x16x32_bf16(aF[a], bF[b], acc[a][b], 0, 0, 0);
        }
        __syncthreads();
    }

    float mx0[4], mx1[4];
#pragma unroll
    for (int b = 0; b < 4; b++) {
        float m = acc[0][b].x;
#pragma unroll
        for (int a = 0; a < 2; a++) {
            m = fmaxf(m, acc[a][b].x); m = fmaxf(m, acc[a][b].y);
            m = fmaxf(m, acc[a][b].z); m = fmaxf(m, acc[a][b].w);
        }
        m = fmaxf(m, __shfl_xor(m, 16));
        m = fmaxf(m, __shfl_xor(m, 32));
        mx0[b] = m;
        float n = acc[2][b].x;
#pragma unroll
        for (int a = 2; a < 4; a++) {
            n = fmaxf(n, acc[a][b].x); n = fmaxf(n, acc[a][b].y);
            n = fmaxf(n, acc[a][b].z); n = fmaxf(n, acc[a][b].w);
        }
        n = fmaxf(n, __shfl_xor(n, 16));
        n = fmaxf(n, __shfl_xor(n, 32));
        mx1[b] = n;
    }
    float v0 = (quad == 0) ? mx0[0] : (quad == 1) ? mx0[1] : (quad == 2) ? mx0[2] : mx0[3];
    float v1 = (quad == 0) ? mx1[0] : (quad == 1) ? mx1[1] : (quad == 2) ? mx1[2] : mx1[3];
    int col = koBase + qcol + (quad << 4) + l15;
    int i0 = (rb << 2) + ((wv >> 1) << 1);
    int si0 = (s << 5) + i0;
    float bias = c2v[col];
    float w0 = fmaxf(v0 + bias, 0.f);
    float w1 = fmaxf(v1 + bias, 0.f);
    unsigned short h0, l0, h1, l1;
    splitf(w0, h0, l0); splitf(w1, h1, l1);
    poolh[si0 * 1024 + col] = h0; pooll[si0 * 1024 + col] = l0;
    poolh[(si0 + 1) * 1024 + col] = h1; pooll[(si0 + 1) * 1024 + col] = l1;
}

// Fallback (small ws): fused build + GEMM + pool (R3 structure, c1 pre-folded into Hp,
// B-fragments hoisted). W2bf must be UNswizzled for this path.
__global__ __launch_bounds__(256) void k_pool_mfma(
    const float* __restrict__ Hp, const float* __restrict__ Mp,
    const unsigned short* __restrict__ W2bf,
    const float* __restrict__ c2v, const float* __restrict__ curr,
    unsigned short* __restrict__ poolh, unsigned short* __restrict__ pooll) {
    int s = blockIdx.z;
    int rb = blockIdx.y;
    int koBase = blockIdx.x << 7;
    int t = threadIdx.x;
    int lane = t & 63, wv = t >> 6;
    int quad = lane >> 4, l15 = lane & 15;
    int qrow = (wv >> 1) << 6;
    int qcol = (wv & 1) << 6;

    __shared__ unsigned short As[128 * 40];
    __shared__ unsigned short Bs[128 * 40];
    __shared__ float rx[128], ry[128];

    if (t < 128) {
        int iL = t >> 5, j = t & 31;
        int ig = (s << 5) + (rb << 2) + iL;
        int jg = (s << 5) + j;
        float dx = curr[jg * 2] - curr[ig * 2];
        float dy = curr[jg * 2 + 1] - curr[ig * 2 + 1];
        float den = fmaxf(sqrtf(dx * dx + dy * dy), 1e-12f);
        rx[t] = dx / den; ry[t] = dy / den;
    }
    __syncthreads();

    f32x4 acc[4][4];
#pragma unroll
    for (int a = 0; a < 4; a++)
#pragma unroll
        for (int b = 0; b < 4; b++) acc[a][b] = (f32x4){0.f, 0.f, 0.f, 0.f};

    int r0 = t >> 3, c4 = (t & 7) << 2;
    int bn = t >> 1, bk = (t & 1) << 4;

    for (int kt = 0; kt < 512; kt += 32) {
#pragma unroll
        for (int p = 0; p < 4; p++) {
            int rr = r0 + (p << 5);
            int j = rr & 31;
            int kg = kt + c4;
            float4 hv = *(const float4*)(Hp + (((s << 5) + j) << 9) + kg);
            float4 m0 = *(const float4*)(Mp + kg);
            float4 m1 = *(const float4*)(Mp + 512 + kg);
            float rxv = rx[rr], ryv = ry[rr];
            float v0 = fmaxf(fmaf(rxv, m0.x, fmaf(ryv, m1.x, hv.x)), 0.f);
            float v1 = fmaxf(fmaf(rxv, m0.y, fmaf(ryv, m1.y, hv.y)), 0.f);
            float v2 = fmaxf(fmaf(rxv, m0.z, fmaf(ryv, m1.z, hv.z)), 0.f);
            float v3 = fmaxf(fmaf(rxv, m0.w, fmaf(ryv, m1.w, hv.w)), 0.f);
            unsigned int u0 = pack2(f2bf(v0), f2bf(v1));
            unsigned int u1 = pack2(f2bf(v2), f2bf(v3));
            *(uint2*)(&As[rr * 40 + c4]) = make_uint2(u0, u1);
        }
        {
            const unsigned short* src = W2bf + (((koBase + bn) << 9) + kt + bk);
            uint4 w0 = *(const uint4*)src;
            uint4 w1 = *(const uint4*)(src + 8);
            *(uint4*)(&Bs[bn * 40 + bk]) = w0;
            *(uint4*)(&Bs[bn * 40 + bk + 8]) = w1;
        }
        __syncthreads();
        short8 bF[4];
#pragma unroll
        for (int b = 0; b < 4; b++)
            bF[b] = *(const short8*)(&Bs[(qcol + (b << 4) + l15) * 40 + (quad << 3)]);
#pragma unroll
        for (int a = 0; a < 4; a++) {
            short8 aF = *(const short8*)(&As[(qrow + (a << 4) + l15) * 40 + (quad << 3)]);
#pragma unroll
            for (int b = 0; b < 4; b++)
                acc[a][b] = __builtin_amdgcn_mfma_f32_16x16x32_bf16(aF, bF[b], acc[a][b], 0, 0, 0);
        }
        __syncthreads();
    }

    float mx0[4], mx1[4];
#pragma unroll
    for (int b = 0; b < 4; b++) {
        float m = acc[0][b].x;
#pragma unroll
        for (int a = 0; a < 2; a++) {
            m = fmaxf(m, acc[a][b].x); m = fmaxf(m, acc[a][b].y);
            m = fmaxf(m, acc[a][b].z); m = fmaxf(m, acc[a][b].w);
        }
        m = fmaxf(m, __shfl_xor(m, 16));
        m = fmaxf(m, __shfl_xor(m, 32));
        mx0[b] = m;
        float n = acc[2][b].x;
#pragma unroll
        for (int a = 2; a < 4; a++) {
            n = fmaxf(n, acc[a][b].x); n = fmaxf(n, acc[a][b].y);
            n = fmaxf(n, acc[a][b].z); n = fmaxf(n, acc[a][b].w);
        }
        n = fmaxf(n, __shfl_xor(n, 16));
        n = fmaxf(n, __shfl_xor(n, 32));
        mx1[b] = n;
    }
    float v0 = (quad == 0) ? mx0[0] : (quad == 1) ? mx0[1] : (quad == 2) ? mx0[2] : mx0[3];
    float v1 = (quad == 0) ? mx1[0] : (quad == 1) ? mx1[1] : (quad == 2) ? mx1[2] : mx1[3];
    int col = koBase + qcol + (quad << 4) + l15;
    int i0 = (rb << 2) + ((wv >> 1) << 1);
    int si0 = (s << 5) + i0;
    float bias = c2v[col];
    float w0 = fmaxf(v0 + bias, 0.f);
    float w1 = fmaxf(v1 + bias, 0.f);
    unsigned short h0, l0, h1, l1;
    splitf(w0, h0, l0); splitf(w1, h1, l1);
    poolh[si0 * 1024 + col] = h0; pooll[si0 * 1024 + col] = l0;
    poolh[(si0 + 1) * 1024 + col] = h1; pooll[(si0 + 1) * 1024 + col] = l1;
}

// m1 via bf16x3 MFMA. Block: 64 rows x 64 ko, K=1152, B-frags hoisted.
__global__ __launch_bounds__(256) void k_m1_mfma(
    const unsigned short* __restrict__ h2h, const unsigned short* __restrict__ h2l,
    const unsigned short* __restrict__ poolh, const unsigned short* __restrict__ pooll,
    const unsigned short* __restrict__ M1h, const unsigned short* __restrict__ M1l,
    const float* __restrict__ cm1,
    unsigned short* __restrict__ dh1h, unsigned short* __restrict__ dh1l) {
    int rowBase = blockIdx.y << 6;
    int koBase = blockIdx.x << 6;
    int t = threadIdx.x;
    int lane = t & 63, wv = t >> 6;
    int quad = lane >> 4, l15 = lane & 15;
    int qrow = (wv >> 1) << 5, qcol = (wv & 1) << 5;
    __shared__ unsigned short Ah[64 * 40], Al[64 * 40], Bh[64 * 40], Bl[64 * 40];
    f32x4 acc[2][2];
#pragma unroll
    for (int a = 0; a < 2; a++)
#pragma unroll
        for (int b = 0; b < 2; b++) acc[a][b] = (f32x4){0.f, 0.f, 0.f, 0.f};

    int ar = t >> 2, ak = (t & 3) << 3;

    for (int kt = 0; kt < 1152; kt += 32) {
        {
            const unsigned short* sH;
            const unsigned short* sL;
            int off;
            if (kt < 128) {
                off = (rowBase + ar) * 128 + kt + ak;
                sH = h2h; sL = h2l;
            } else {
                off = (rowBase + ar) * 1024 + (kt - 128) + ak;
                sH = poolh; sL = pooll;
            }
            *(uint4*)&Ah[ar * 40 + ak] = *(const uint4*)(sH + off);
            *(uint4*)&Al[ar * 40 + ak] = *(const uint4*)(sL + off);
        }
        {
            int boff = (koBase + ar) * 1152 + kt + ak;
            *(uint4*)&Bh[ar * 40 + ak] = *(const uint4*)(M1h + boff);
            *(uint4*)&Bl[ar * 40 + ak] = *(const uint4*)(M1l + boff);
        }
        __syncthreads();
        short8 bH[2], bL[2];
#pragma unroll
        for (int b = 0; b < 2; b++) {
            int boff = (qcol + (b << 4) + l15) * 40 + (quad << 3);
            bH[b] = *(const short8*)(&Bh[boff]);
            bL[b] = *(const short8*)(&Bl[boff]);
        }
#pragma unroll
        for (int a = 0; a < 2; a++) {
            int aoff = (qrow + (a << 4) + l15) * 40 + (quad << 3);
            short8 aH = *(const short8*)(&Ah[aoff]);
            short8 aL = *(const short8*)(&Al[aoff]);
#pragma unroll
            for (int b = 0; b < 2; b++) {
                acc[a][b] = __builtin_amdgcn_mfma_f32_16x16x32_bf16(aH, bH[b], acc[a][b], 0, 0, 0);
                acc[a][b] = __builtin_amdgcn_mfma_f32_16x16x32_bf16(aH, bL[b], acc[a][b], 0, 0, 0);
                acc[a][b] = __builtin_amdgcn_mfma_f32_16x16x32_bf16(aL, bH[b], acc[a][b], 0, 0, 0);
            }
        }
        __syncthreads();
    }
#pragma unroll
    for (int b = 0; b < 2; b++) {
        int col = koBase + qcol + (b << 4) + l15;
        float bias = cm1[col];
#pragma unroll
        for (int a = 0; a < 2; a++) {
#pragma unroll
            for (int rg = 0; rg < 4; rg++) {
                int row = rowBase + qrow + (a << 4) + (quad << 2) + rg;
                float v = fmaxf(acc[a][b][rg] + bias, 0.f);
                unsigned short sh, sl;
                splitf(v, sh, sl);
                dh1h[row * 1024 + col] = sh;
                dh1l[row * 1024 + col] = sl;
            }
        }
    }
}

// m2 via bf16x3 MFMA: Block: 64 rows x 128 ko, K=1024. Grid 16.
__global__ __launch_bounds__(256) void k_m2_mfma(
    const unsigned short* __restrict__ dh1h, const unsigned short* __restrict__ dh1l,
    const unsigned short* __restrict__ M2h, const unsigned short* __restrict__ M2l,
    const float* __restrict__ cm2, float* __restrict__ h_st) {
    int rowBase = blockIdx.x << 6;
    int t = threadIdx.x;
    int lane = t & 63, wv = t >> 6;
    int quad = lane >> 4, l15 = lane & 15;
    int qrow = (wv >> 1) << 5;
    int qcol = (wv & 1) << 6;
    __shared__ unsigned short Ah[64 * 40], Al[64 * 40], Bh[128 * 40], Bl[128 * 40];
    f32x4 acc[2][4];
#pragma unroll
    for (int a = 0; a < 2; a++)
#pragma unroll
        for (int b = 0; b < 4; b++) acc[a][b] = (f32x4){0.f, 0.f, 0.f, 0.f};

    int ar = t >> 2, ak = (t & 3) << 3;
    int br = t >> 1, bk = (t & 1) << 4;

    for (int kt = 0; kt < 1024; kt += 32) {
        {
            int off = (rowBase + ar) * 1024 + kt + ak;
            *(uint4*)&Ah[ar * 40 + ak] = *(const uint4*)(dh1h + off);
            *(uint4*)&Al[ar * 40 + ak] = *(const uint4*)(dh1l + off);
        }
        {
            int off = br * 1024 + kt + bk;
            *(uint4*)&Bh[br * 40 + bk] = *(const uint4*)(M2h + off);
            *(uint4*)&Bh[br * 40 + bk + 8] = *(const uint4*)(M2h + off + 8);
            *(uint4*)&Bl[br * 40 + bk] = *(const uint4*)(M2l + off);
            *(uint4*)&Bl[br * 40 + bk + 8] = *(const uint4*)(M2l + off + 8);
        }
        __syncthreads();
#pragma unroll
        for (int a = 0; a < 2; a++) {
            int aoff = (qrow + (a << 4) + l15) * 40 + (quad << 3);
            short8 aH = *(const short8*)(&Ah[aoff]);
            short8 aL = *(const short8*)(&Al[aoff]);
#pragma unroll
            for (int b = 0; b < 4; b++) {
                int boff = (qcol + (b << 4) + l15) * 40 + (quad << 3);
                short8 bH = *(const short8*)(&Bh[boff]);
                short8 bL = *(const short8*)(&Bl[boff]);
                acc[a][b] = __builtin_amdgcn_mfma_f32_16x16x32_bf16(aH, bH, acc[a][b], 0, 0, 0);
                acc[a][b] = __builtin_amdgcn_mfma_f32_16x16x32_bf16(aH, bL, acc[a][b], 0, 0, 0);
                acc[a][b] = __builtin_amdgcn_mfma_f32_16x16x32_bf16(aL, bH, acc[a][b], 0, 0, 0);
            }
        }
        __syncthreads();
    }
#pragma unroll
    for (int b = 0; b < 4; b++) {
        int col = qcol + (b << 4) + l15;
        float bias = cm2[col];
#pragma unroll
        for (int a = 0; a < 2; a++) {
#pragma unroll
            for (int rg = 0; rg < 4; rg++) {
                int row = rowBase + qrow + (a << 4) + (quad << 2) + rg;
                h_st[row * 128 + col] = fmaxf(acc[a][b][rg] + bias, 0.f);
            }
        }
    }
}

// ---------------- launch ----------------

extern "C" void kernel_launch(void* const* d_in, const int* in_sizes, int n_in,
                              void* d_out, int out_size, void* d_ws, size_t ws_size,
                              hipStream_t stream) {
    const float* last_pos     = (const float*)d_in[0];
    const float* last_pos_rel = (const float*)d_in[1];
    const float* h0   = (const float*)d_in[2];
    const float* c0   = (const float*)d_in[3];
    const float* emb_W = (const float*)d_in[5];
    const float* emb_b = (const float*)d_in[6];
    const float* lstm_Wih = (const float*)d_in[7];
    const float* lstm_Whh = (const float*)d_in[8];
    const float* lstm_bih = (const float*)d_in[9];
    const float* lstm_bhh = (const float*)d_in[10];
    const float* pos_W = (const float*)d_in[11];
    const float* pos_b = (const float*)d_in[12];
    const float* sp_W  = (const float*)d_in[13];
    const float* sp_b  = (const float*)d_in[14];
    const float* pp1_W = (const float*)d_in[15];
    const float* pp1_b = (const float*)d_in[16];
    const float* pp1_g = (const float*)d_in[17];
    const float* pp1_be= (const float*)d_in[18];
    const float* pp2_W = (const float*)d_in[19];
    const float* pp2_b = (const float*)d_in[20];
    const float* pp2_g = (const float*)d_in[21];
    const float* pp2_be= (const float*)d_in[22];
    const float* m1_W  = (const float*)d_in[23];
    const float* m1_b  = (const float*)d_in[24];
    const float* m1_g  = (const float*)d_in[25];
    const float* m1_be = (const float*)d_in[26];
    const float* m2_W  = (const float*)d_in[27];
    const float* m2_b  = (const float*)d_in[28];
    const float* m2_g  = (const float*)d_in[29];
    const float* m2_be = (const float*)d_in[30];
    float* out = (float*)d_out;

    float* p = (float*)d_ws;
    float* WgT  = p; p += 192 * 512;
    float* bg   = p; p += 512;
    float* Wh1T = p; p += 128 * 512;
    float* Mp   = p; p += 2 * 512;
    float* c1   = p; p += 512;
    unsigned short* W2bf = (unsigned short*)p; p += 512 * 1024 / 2;
    float* c2v  = p; p += 1024;
    unsigned short* M1h = (unsigned short*)p; p += 1024 * 1152 / 2;
    unsigned short* M1l = (unsigned short*)p; p += 1024 * 1152 / 2;
    float* cm1  = p; p += 1024;
    unsigned short* M2h = (unsigned short*)p; p += 128 * 1024 / 2;
    unsigned short* M2l = (unsigned short*)p; p += 128 * 1024 / 2;
    float* cm2  = p; p += 128;
    float* h_st = p; p += 1024 * 128;
    float* c_st = p; p += 1024 * 128;
    unsigned short* h2h = (unsigned short*)p; p += 1024 * 128 / 2;
    unsigned short* h2l = (unsigned short*)p; p += 1024 * 128 / 2;
    float* curr = p; p += 1024 * 2;
    float* din  = p; p += 1024 * 64;
    float* Hp   = p; p += 1024 * 512;
    unsigned short* poolh = (unsigned short*)p; p += 1024 * 1024 / 2;
    unsigned short* pooll = (unsigned short*)p; p += 1024 * 1024 / 2;
    unsigned short* dh1h = (unsigned short*)p; p += 1024 * 1024 / 2;
    unsigned short* dh1l = (unsigned short*)p; p += 1024 * 1024 / 2;
    unsigned short* x1g = (unsigned short*)p;   // 32768*512 bf16 = 33.5 MB (big-ws path only)
    size_t need = (size_t)((char*)(x1g + (size_t)32768 * 512) - (char*)d_ws);
    int big = (ws_size >= need) ? 1 : 0;

    pre_lstm<<<384, 256, 0, stream>>>(lstm_Wih, lstm_Whh, lstm_bih, lstm_bhh, WgT, bg);
    pre_wh1<<<256, 256, 0, stream>>>(pp1_W, pp1_g, Wh1T);
    pre_mp<<<2, 256, 0, stream>>>(sp_W, sp_b, pp1_W, pp1_b, pp1_g, pp1_be, Mp, c1);
    pre_w2bf<<<2048, 256, 0, stream>>>(pp2_W, pp2_b, pp2_g, pp2_be, W2bf, c2v, big);
    pre_w1split<<<4608, 256, 0, stream>>>(m1_W, m1_b, m1_g, m1_be, M1h, M1l, cm1);
    pre_w2split<<<512, 256, 0, stream>>>(m2_W, m2_b, m2_g, m2_be, M2h, M2l, cm2);
    pre_init<<<512, 256, 0, stream>>>(last_pos, last_pos_rel, h0, c0, emb_W, emb_b,
                                      h_st, c_st, curr, din);

    for (int t = 0; t < 12; t++) {
        k_lstm<<<256, 512, 0, stream>>>(WgT, bg, h_st, c_st, din, curr, h2h, h2l,
                                        pos_W, pos_b, emb_W, emb_b,
                                        Wh1T, c1, Hp, (t < 11) ? 1 : 0, out + t * 2048);
        if (t == 11) break;
        if (big) {
            k_x1<<<1024, 256, 0, stream>>>(Hp, Mp, curr, x1g);
            k_pool_g<<<dim3(8, 8, 32), 256, 0, stream>>>(x1g, W2bf, c2v, poolh, pooll);
        } else {
            k_pool_mfma<<<dim3(8, 8, 32), 256, 0, stream>>>(Hp, Mp, W2bf, c2v, curr,
                                                            poolh, pooll);
        }
        k_m1_mfma<<<dim3(16, 16), 256, 0, stream>>>(h2h, h2l, poolh, pooll,
                                                    M1h, M1l, cm1, dh1h, dh1l);
        k_m2_mfma<<<16, 256, 0, stream>>>(dh1h, dh1l, M2h, M2l, cm2, h_st);
    }
}

// Round 5
// 1621.694 us; speedup vs baseline: 4.5239x; 1.0379x over previous
//
#include <hip/hip_runtime.h>
#include <hip/hip_bf16.h>
#include <math.h>

#define DEVFN __device__ __forceinline__

constexpr float BN_INV = 0.99999500003749971f; // 1/sqrt(1+1e-5)

DEVFN float sigm(float x) { return 1.0f / (1.0f + expf(-x)); }

DEVFN unsigned short f2bf(float f) {
    __hip_bfloat16 b = __float2bfloat16(f);
    return *reinterpret_cast<unsigned short*>(&b);
}
DEVFN float bf2f(unsigned short u) {
    unsigned int x = ((unsigned int)u) << 16;
    return *reinterpret_cast<float*>(&x);
}
DEVFN void splitf(float v, unsigned short& h, unsigned short& l) {
    h = f2bf(v);
    l = f2bf(v - bf2f(h));
}
DEVFN unsigned int pack2(unsigned short a, unsigned short b) {
    return (unsigned int)a | ((unsigned int)b << 16);
}

typedef __attribute__((ext_vector_type(8))) short short8;  // 8 bf16 = 4 VGPRs
typedef __attribute__((ext_vector_type(4))) float f32x4;

// async global->LDS, 16B per lane; ldst must be wave-uniform (HW adds lane*16)
#define ASYNC_COPY16(gsrc, ldst)                                                            \
    __builtin_amdgcn_global_load_lds((const __attribute__((address_space(1))) unsigned int*)(gsrc), \
                                     (__attribute__((address_space(3))) unsigned int*)(ldst), 16, 0, 0)

// ---------------- precompute kernels (run every call; ws is re-poisoned) ----------------

__global__ void pre_lstm(const float* __restrict__ Wih, const float* __restrict__ Whh,
                         const float* __restrict__ bih, const float* __restrict__ bhh,
                         float* __restrict__ WgT, float* __restrict__ bg) {
    int idx = blockIdx.x * blockDim.x + threadIdx.x;   // 192*512
    int k = idx >> 9, t = idx & 511;
    WgT[idx] = (k < 64) ? Wih[t * 64 + k] : Whh[t * 128 + (k - 64)];
    if (idx < 512) bg[idx] = bih[idx] + bhh[idx];
}

__global__ void pre_wh1(const float* __restrict__ pp1W, const float* __restrict__ pp1g,
                        float* __restrict__ Wh1T) {
    int idx = blockIdx.x * blockDim.x + threadIdx.x;   // 128*512
    int h = idx >> 9, k = idx & 511;
    Wh1T[idx] = pp1W[k * 192 + 64 + h] * (BN_INV * pp1g[k]);
}

__global__ void pre_mp(const float* __restrict__ spW, const float* __restrict__ spb,
                       const float* __restrict__ pp1W, const float* __restrict__ pp1b,
                       const float* __restrict__ pp1g, const float* __restrict__ pp1be,
                       float* __restrict__ Mp, float* __restrict__ c1) {
    int k = blockIdx.x * blockDim.x + threadIdx.x;     // 512
    float m0 = 0.f, m1 = 0.f, c0 = 0.f;
    for (int e = 0; e < 64; e++) {
        float w = pp1W[k * 192 + e];
        m0 += spW[e * 2] * w; m1 += spW[e * 2 + 1] * w; c0 += spb[e] * w;
    }
    float s = BN_INV * pp1g[k];
    Mp[k] = m0 * s; Mp[512 + k] = m1 * s;
    c1[k] = (c0 + pp1b[k]) * s + pp1be[k];
}

// pp2 weights -> bf16, optionally XOR-swizzled (chunk c of each 64-k tile stored at c^(ko&7))
__global__ void pre_w2bf(const float* __restrict__ W, const float* __restrict__ b,
                         const float* __restrict__ g, const float* __restrict__ be,
                         unsigned short* __restrict__ Wbf, float* __restrict__ cv, int swz) {
    int idx = blockIdx.x * blockDim.x + threadIdx.x;   // 1024*512
    int ko = idx >> 9, k = idx & 511;
    float s = BN_INV * g[ko];
    int outk = swz ? ((k & ~63) | ((((k >> 3) & 7) ^ (ko & 7)) << 3) | (k & 7)) : k;
    Wbf[(ko << 9) + outk] = f2bf(W[idx] * s);
    if (idx < 1024) cv[idx] = b[idx] * s + be[idx];
}

__global__ void pre_w1split(const float* __restrict__ W, const float* __restrict__ b,
                            const float* __restrict__ g, const float* __restrict__ be,
                            unsigned short* __restrict__ Wh, unsigned short* __restrict__ Wl,
                            float* __restrict__ cv) {
    int idx = blockIdx.x * blockDim.x + threadIdx.x;   // 1024*1152
    int ko = idx / 1152;
    float s = BN_INV * g[ko];
    unsigned short h, l;
    splitf(W[idx] * s, h, l);
    Wh[idx] = h; Wl[idx] = l;
    if (idx < 1024) {
        float s2 = BN_INV * g[idx];
        cv[idx] = b[idx] * s2 + be[idx];
    }
}

__global__ void pre_w2split(const float* __restrict__ W, const float* __restrict__ b,
                            const float* __restrict__ g, const float* __restrict__ be,
                            unsigned short* __restrict__ Wh, unsigned short* __restrict__ Wl,
                            float* __restrict__ cv) {
    int idx = blockIdx.x * blockDim.x + threadIdx.x;   // 128*1024
    int ko = idx >> 10;
    float s = BN_INV * g[ko];
    unsigned short h, l;
    splitf(W[idx] * s, h, l);
    Wh[idx] = h; Wl[idx] = l;
    if (idx < 128) {
        float s2 = BN_INV * g[idx];
        cv[idx] = b[idx] * s2 + be[idx];
    }
}

__global__ void pre_init(const float* __restrict__ lp, const float* __restrict__ lpr,
                         const float* __restrict__ h0, const float* __restrict__ c0,
                         const float* __restrict__ embW, const float* __restrict__ embb,
                         float* __restrict__ h_st, float* __restrict__ c_st,
                         float* __restrict__ curr, float* __restrict__ din) {
    int idx = blockIdx.x * blockDim.x + threadIdx.x;   // 1024*128
    h_st[idx] = h0[idx];
    c_st[idx] = c0[idx];
    if (idx < 1024 * 2) curr[idx] = lp[idx];
    if (idx < 1024 * 64) {
        int n = idx >> 6, e = idx & 63;
        din[idx] = fmaf(lpr[n * 2], embW[e * 2], fmaf(lpr[n * 2 + 1], embW[e * 2 + 1], embb[e]));
    }
}

// ---------------- per-step kernels ----------------

// Fused: LSTM cell (4 peds/block) + rel_pos + curr + din2 + preds + Hp (=h2@Wh1T + c1).
__global__ __launch_bounds__(512) void k_lstm(
    const float* __restrict__ WgT, const float* __restrict__ bg,
    float* __restrict__ h_st, float* __restrict__ c_st,
    float* __restrict__ din, float* __restrict__ curr,
    unsigned short* __restrict__ h2h, unsigned short* __restrict__ h2l,
    const float* __restrict__ posW, const float* __restrict__ posb,
    const float* __restrict__ embW, const float* __restrict__ embb,
    const float* __restrict__ Wh1T, const float* __restrict__ c1,
    float* __restrict__ Hp, int doHp,
    float* __restrict__ preds) {
    int n0 = blockIdx.x << 2;
    int t = threadIdx.x;
    __shared__ float xs[4][256];
    __shared__ float gates[4][512];
    __shared__ float h2s[4][128];
    __shared__ float rp[4][2];
#pragma unroll
    for (int u = 0; u < 2; u++) {
        int lin = t + (u << 9);
        int r = lin >> 8, k = lin & 255;
        float v = 0.f;
        if (k < 64) v = din[(n0 + r) * 64 + k];
        else if (k < 192) v = h_st[(n0 + r) * 128 + (k - 64)];
        xs[r][k] = v;
    }
    __syncthreads();
    float a0 = bg[t], a1 = a0, a2 = a0, a3 = a0;
#pragma unroll 4
    for (int k = 0; k < 192; k++) {
        float w = WgT[(k << 9) + t];
        a0 = fmaf(xs[0][k], w, a0);
        a1 = fmaf(xs[1][k], w, a1);
        a2 = fmaf(xs[2][k], w, a2);
        a3 = fmaf(xs[3][k], w, a3);
    }
    gates[0][t] = a0; gates[1][t] = a1; gates[2][t] = a2; gates[3][t] = a3;
    __syncthreads();
    {
        int r = t >> 7, hx = t & 127;
        float ig = sigm(gates[r][hx]);
        float fg = sigm(gates[r][128 + hx]);
        float gg = tanhf(gates[r][256 + hx]);
        float og = sigm(gates[r][384 + hx]);
        float c2 = fmaf(fg, c_st[(n0 + r) * 128 + hx], ig * gg);
        float h2 = og * tanhf(c2);
        c_st[(n0 + r) * 128 + hx] = c2;
        unsigned short sh, sl;
        splitf(h2, sh, sl);
        h2h[(n0 + r) * 128 + hx] = sh;
        h2l[(n0 + r) * 128 + hx] = sl;
        h2s[r][hx] = h2;
    }
    __syncthreads();
    int wv = t >> 6, l = t & 63;
    if (wv < 4) {
        float p0 = fmaf(h2s[wv][l], posW[l], h2s[wv][l + 64] * posW[l + 64]);
        float p1 = fmaf(h2s[wv][l], posW[128 + l], h2s[wv][l + 64] * posW[192 + l]);
#pragma unroll
        for (int off = 32; off > 0; off >>= 1) {
            p0 += __shfl_down(p0, off, 64);
            p1 += __shfl_down(p1, off, 64);
        }
        if (l == 0) { rp[wv][0] = p0 + posb[0]; rp[wv][1] = p1 + posb[1]; }
    }
    __syncthreads();
    if (t < 256) {
        int r = t >> 6, e = t & 63;
        float r0 = rp[r][0], r1 = rp[r][1];
        din[(n0 + r) * 64 + e] = fmaf(r0, embW[e * 2], fmaf(r1, embW[e * 2 + 1], embb[e]));
        if (e == 0) {
            preds[(n0 + r) * 2] = r0; preds[(n0 + r) * 2 + 1] = r1;
            curr[(n0 + r) * 2] += r0; curr[(n0 + r) * 2 + 1] += r1;
        }
    }
    if (doHp) {
        float cc = c1[t];
        float q0 = cc, q1 = cc, q2 = cc, q3 = cc;
#pragma unroll 4
        for (int h = 0; h < 128; h++) {
            float w = Wh1T[(h << 9) + t];
            q0 = fmaf(h2s[0][h], w, q0);
            q1 = fmaf(h2s[1][h], w, q1);
            q2 = fmaf(h2s[2][h], w, q2);
            q3 = fmaf(h2s[3][h], w, q3);
        }
        Hp[((n0 + 0) << 9) + t] = q0;
        Hp[((n0 + 1) << 9) + t] = q1;
        Hp[((n0 + 2) << 9) + t] = q2;
        Hp[((n0 + 3) << 9) + t] = q3;
    }
}

// Build x1 bf16 once per step, XOR-swizzled within each 64-k tile (chunk c at c^(j&7)).
// XCD-swizzled grid (1024 linear): scene s runs on XCD s%8 so x1 lands in the L2
// that k_pool_g will read it from.  Block = one (s,i): 32 j rows x 512 k.
__global__ __launch_bounds__(256) void k_x1(
    const float* __restrict__ Hp, const float* __restrict__ Mp,
    const float* __restrict__ curr, unsigned short* __restrict__ x1g) {
    int bid = blockIdx.x;
    int c = bid & 7, q = bid >> 3;       // q 0..127
    int i = q & 31, g = q >> 5;          // g 0..3
    int s = (g << 3) + c;
    int si = (s << 5) + i;
    int t = threadIdx.x;
    __shared__ float rx[32], ry[32];
    __shared__ float m0s[512], m1s[512];
    for (int u = t; u < 512; u += 256) { m0s[u] = Mp[u]; m1s[u] = Mp[512 + u]; }
    if (t < 32) {
        int jg = (s << 5) + t;
        float dx = curr[jg * 2] - curr[si * 2];
        float dy = curr[jg * 2 + 1] - curr[si * 2 + 1];
        float den = fmaxf(sqrtf(dx * dx + dy * dy), 1e-12f);
        rx[t] = dx / den; ry[t] = dy / den;
    }
    __syncthreads();
    int j = t >> 3, c8 = t & 7;
    float rxv = rx[j], ryv = ry[j];
    const float* hp = Hp + (((s << 5) + j) << 9);
    unsigned short* op = x1g + ((size_t)((si << 5) + j) << 9);
    int swz = (c8 ^ (j & 7)) << 3;
#pragma unroll
    for (int kt = 0; kt < 512; kt += 64) {
        int k = kt + (c8 << 3);
        float4 ha = *(const float4*)(hp + k);
        float4 hb = *(const float4*)(hp + k + 4);
        uint4 o;
        o.x = pack2(f2bf(fmaxf(fmaf(rxv, m0s[k + 0], fmaf(ryv, m1s[k + 0], ha.x)), 0.f)),
                    f2bf(fmaxf(fmaf(rxv, m0s[k + 1], fmaf(ryv, m1s[k + 1], ha.y)), 0.f)));
        o.y = pack2(f2bf(fmaxf(fmaf(rxv, m0s[k + 2], fmaf(ryv, m1s[k + 2], ha.z)), 0.f)),
                    f2bf(fmaxf(fmaf(rxv, m0s[k + 3], fmaf(ryv, m1s[k + 3], ha.w)), 0.f)));
        o.z = pack2(f2bf(fmaxf(fmaf(rxv, m0s[k + 4], fmaf(ryv, m1s[k + 4], hb.x)), 0.f)),
                    f2bf(fmaxf(fmaf(rxv, m0s[k + 5], fmaf(ryv, m1s[k + 5], hb.y)), 0.f)));
        o.w = pack2(f2bf(fmaxf(fmaf(rxv, m0s[k + 6], fmaf(ryv, m1s[k + 6], hb.z)), 0.f)),
                    f2bf(fmaxf(fmaf(rxv, m0s[k + 7], fmaf(ryv, m1s[k + 7], hb.w)), 0.f)));
        *(uint4*)(op + kt + swz) = o;
    }
}

// Pure GEMM + max-pool, XCD-swizzled grid (2048 linear): XCD c owns scenes
// {c, c+8, c+16, c+24}; each scene's 64 blocks (8 rb x 8 ko) run back-to-back on
// that XCD, so the scene's 1 MB x1 slice + 1 MB W2 stay L2-resident.
__global__ __launch_bounds__(256) void k_pool_g(
    const unsigned short* __restrict__ x1g, const unsigned short* __restrict__ W2bf,
    const float* __restrict__ c2v,
    unsigned short* __restrict__ poolh, unsigned short* __restrict__ pooll) {
    int bid = blockIdx.x;
    int c = bid & 7, q = bid >> 3;       // q 0..255
    int inner = q & 63, g = q >> 6;      // g 0..3
    int s = (g << 3) + c;
    int rb = inner >> 3;
    int koBase = (inner & 7) << 7;
    int t = threadIdx.x;
    int lane = t & 63, wv = t >> 6;
    int quad = lane >> 4, l15 = lane & 15;
    int qrow = (wv >> 1) << 6, qcol = (wv & 1) << 6;
    __shared__ unsigned short As[128 * 64];
    __shared__ unsigned short Bs[128 * 64];
    f32x4 acc[4][4];
#pragma unroll
    for (int a = 0; a < 4; a++)
#pragma unroll
        for (int b = 0; b < 4; b++) acc[a][b] = (f32x4){0.f, 0.f, 0.f, 0.f};

    int rowG0 = (s << 10) + (rb << 7);
    int rlane = lane >> 3;            // 0..7 (row within 8-row group)
    int clane = (lane & 7) << 3;      // k-chunk offset (shorts)

    for (int kt = 0; kt < 512; kt += 64) {
#pragma unroll
        for (int u = 0; u < 4; u++) {
            int r = (wv << 5) + (u << 3);
            ASYNC_COPY16(x1g + (size_t)(rowG0 + r + rlane) * 512 + kt + clane, &As[r << 6]);
            ASYNC_COPY16(W2bf + (size_t)(koBase + r + rlane) * 512 + kt + clane, &Bs[r << 6]);
        }
        __syncthreads();
#pragma unroll
        for (int kt2 = 0; kt2 < 2; kt2++) {
            short8 aF[4], bF[4];
#pragma unroll
            for (int a = 0; a < 4; a++) {
                int r = qrow + (a << 4) + l15;
                int pos = ((kt2 << 2) + quad) ^ (r & 7);
                aF[a] = *(const short8*)(&As[(r << 6) + (pos << 3)]);
            }
#pragma unroll
            for (int b = 0; b < 4; b++) {
                int r = qcol + (b << 4) + l15;
                int pos = ((kt2 << 2) + quad) ^ (r & 7);
                bF[b] = *(const short8*)(&Bs[(r << 6) + (pos << 3)]);
            }
#pragma unroll
            for (int a = 0; a < 4; a++)
#pragma unroll
                for (int b = 0; b < 4; b++)
                    acc[a][b] = __builtin_amdgcn_mfma_f32_16x16x32_bf16(aF[a], bF[b], acc[a][b], 0, 0, 0);
        }
        __syncthreads();
    }

    float mx0[4], mx1[4];
#pragma unroll
    for (int b = 0; b < 4; b++) {
        float m = acc[0][b].x;
#pragma unroll
        for (int a = 0; a < 2; a++) {
            m = fmaxf(m, acc[a][b].x); m = fmaxf(m, acc[a][b].y);
            m = fmaxf(m, acc[a][b].z); m = fmaxf(m, acc[a][b].w);
        }
        m = fmaxf(m, __shfl_xor(m, 16));
        m = fmaxf(m, __shfl_xor(m, 32));
        mx0[b] = m;
        float n = acc[2][b].x;
#pragma unroll
        for (int a = 2; a < 4; a++) {
            n = fmaxf(n, acc[a][b].x); n = fmaxf(n, acc[a][b].y);
            n = fmaxf(n, acc[a][b].z); n = fmaxf(n, acc[a][b].w);
        }
        n = fmaxf(n, __shfl_xor(n, 16));
        n = fmaxf(n, __shfl_xor(n, 32));
        mx1[b] = n;
    }
    float v0 = (quad == 0) ? mx0[0] : (quad == 1) ? mx0[1] : (quad == 2) ? mx0[2] : mx0[3];
    float v1 = (quad == 0) ? mx1[0] : (quad == 1) ? mx1[1] : (quad == 2) ? mx1[2] : mx1[3];
    int col = koBase + qcol + (quad << 4) + l15;
    int i0 = (rb << 2) + ((wv >> 1) << 1);
    int si0 = (s << 5) + i0;
    float bias = c2v[col];
    float w0 = fmaxf(v0 + bias, 0.f);
    float w1 = fmaxf(v1 + bias, 0.f);
    unsigned short h0, l0, h1, l1;
    splitf(w0, h0, l0); splitf(w1, h1, l1);
    poolh[si0 * 1024 + col] = h0; pooll[si0 * 1024 + col] = l0;
    poolh[(si0 + 1) * 1024 + col] = h1; pooll[(si0 + 1) * 1024 + col] = l1;
}

// Fallback (small ws): fused build + GEMM + pool. W2bf must be UNswizzled for this path.
__global__ __launch_bounds__(256) void k_pool_mfma(
    const float* __restrict__ Hp, const float* __restrict__ Mp,
    const unsigned short* __restrict__ W2bf,
    const float* __restrict__ c2v, const float* __restrict__ curr,
    unsigned short* __restrict__ poolh, unsigned short* __restrict__ pooll) {
    int s = blockIdx.z;
    int rb = blockIdx.y;
    int koBase = blockIdx.x << 7;
    int t = threadIdx.x;
    int lane = t & 63, wv = t >> 6;
    int quad = lane >> 4, l15 = lane & 15;
    int qrow = (wv >> 1) << 6;
    int qcol = (wv & 1) << 6;

    __shared__ unsigned short As[128 * 40];
    __shared__ unsigned short Bs[128 * 40];
    __shared__ float rx[128], ry[128];

    if (t < 128) {
        int iL = t >> 5, j = t & 31;
        int ig = (s << 5) + (rb << 2) + iL;
        int jg = (s << 5) + j;
        float dx = curr[jg * 2] - curr[ig * 2];
        float dy = curr[jg * 2 + 1] - curr[ig * 2 + 1];
        float den = fmaxf(sqrtf(dx * dx + dy * dy), 1e-12f);
        rx[t] = dx / den; ry[t] = dy / den;
    }
    __syncthreads();

    f32x4 acc[4][4];
#pragma unroll
    for (int a = 0; a < 4; a++)
#pragma unroll
        for (int b = 0; b < 4; b++) acc[a][b] = (f32x4){0.f, 0.f, 0.f, 0.f};

    int r0 = t >> 3, c4 = (t & 7) << 2;
    int bn = t >> 1, bk = (t & 1) << 4;

    for (int kt = 0; kt < 512; kt += 32) {
#pragma unroll
        for (int p = 0; p < 4; p++) {
            int rr = r0 + (p << 5);
            int j = rr & 31;
            int kg = kt + c4;
            float4 hv = *(const float4*)(Hp + (((s << 5) + j) << 9) + kg);
            float4 m0 = *(const float4*)(Mp + kg);
            float4 m1 = *(const float4*)(Mp + 512 + kg);
            float rxv = rx[rr], ryv = ry[rr];
            float v0 = fmaxf(fmaf(rxv, m0.x, fmaf(ryv, m1.x, hv.x)), 0.f);
            float v1 = fmaxf(fmaf(rxv, m0.y, fmaf(ryv, m1.y, hv.y)), 0.f);
            float v2 = fmaxf(fmaf(rxv, m0.z, fmaf(ryv, m1.z, hv.z)), 0.f);
            float v3 = fmaxf(fmaf(rxv, m0.w, fmaf(ryv, m1.w, hv.w)), 0.f);
            unsigned int u0 = pack2(f2bf(v0), f2bf(v1));
            unsigned int u1 = pack2(f2bf(v2), f2bf(v3));
            *(uint2*)(&As[rr * 40 + c4]) = make_uint2(u0, u1);
        }
        {
            const unsigned short* src = W2bf + (((koBase + bn) << 9) + kt + bk);
            uint4 w0 = *(const uint4*)src;
            uint4 w1 = *(const uint4*)(src + 8);
            *(uint4*)(&Bs[bn * 40 + bk]) = w0;
            *(uint4*)(&Bs[bn * 40 + bk + 8]) = w1;
        }
        __syncthreads();
        short8 bF[4];
#pragma unroll
        for (int b = 0; b < 4; b++)
            bF[b] = *(const short8*)(&Bs[(qcol + (b << 4) + l15) * 40 + (quad << 3)]);
#pragma unroll
        for (int a = 0; a < 4; a++) {
            short8 aF = *(const short8*)(&As[(qrow + (a << 4) + l15) * 40 + (quad << 3)]);
#pragma unroll
            for (int b = 0; b < 4; b++)
                acc[a][b] = __builtin_amdgcn_mfma_f32_16x16x32_bf16(aF, bF[b], acc[a][b], 0, 0, 0);
        }
        __syncthreads();
    }

    float mx0[4], mx1[4];
#pragma unroll
    for (int b = 0; b < 4; b++) {
        float m = acc[0][b].x;
#pragma unroll
        for (int a = 0; a < 2; a++) {
            m = fmaxf(m, acc[a][b].x); m = fmaxf(m, acc[a][b].y);
            m = fmaxf(m, acc[a][b].z); m = fmaxf(m, acc[a][b].w);
        }
        m = fmaxf(m, __shfl_xor(m, 16));
        m = fmaxf(m, __shfl_xor(m, 32));
        mx0[b] = m;
        float n = acc[2][b].x;
#pragma unroll
        for (int a = 2; a < 4; a++) {
            n = fmaxf(n, acc[a][b].x); n = fmaxf(n, acc[a][b].y);
            n = fmaxf(n, acc[a][b].z); n = fmaxf(n, acc[a][b].w);
        }
        n = fmaxf(n, __shfl_xor(n, 16));
        n = fmaxf(n, __shfl_xor(n, 32));
        mx1[b] = n;
    }
    float v0 = (quad == 0) ? mx0[0] : (quad == 1) ? mx0[1] : (quad == 2) ? mx0[2] : mx0[3];
    float v1 = (quad == 0) ? mx1[0] : (quad == 1) ? mx1[1] : (quad == 2) ? mx1[2] : mx1[3];
    int col = koBase + qcol + (quad << 4) + l15;
    int i0 = (rb << 2) + ((wv >> 1) << 1);
    int si0 = (s << 5) + i0;
    float bias = c2v[col];
    float w0 = fmaxf(v0 + bias, 0.f);
    float w1 = fmaxf(v1 + bias, 0.f);
    unsigned short h0, l0, h1, l1;
    splitf(w0, h0, l0); splitf(w1, h1, l1);
    poolh[si0 * 1024 + col] = h0; pooll[si0 * 1024 + col] = l0;
    poolh[(si0 + 1) * 1024 + col] = h1; pooll[(si0 + 1) * 1024 + col] = l1;
}

// m1 via bf16x3 MFMA. Block: 64 rows x 64 ko, K=1152, B-frags hoisted.
__global__ __launch_bounds__(256) void k_m1_mfma(
    const unsigned short* __restrict__ h2h, const unsigned short* __restrict__ h2l,
    const unsigned short* __restrict__ poolh, const unsigned short* __restrict__ pooll,
    const unsigned short* __restrict__ M1h, const unsigned short* __restrict__ M1l,
    const float* __restrict__ cm1,
    unsigned short* __restrict__ dh1h, unsigned short* __restrict__ dh1l) {
    int rowBase = blockIdx.y << 6;
    int koBase = blockIdx.x << 6;
    int t = threadIdx.x;
    int lane = t & 63, wv = t >> 6;
    int quad = lane >> 4, l15 = lane & 15;
    int qrow = (wv >> 1) << 5, qcol = (wv & 1) << 5;
    __shared__ unsigned short Ah[64 * 40], Al[64 * 40], Bh[64 * 40], Bl[64 * 40];
    f32x4 acc[2][2];
#pragma unroll
    for (int a = 0; a < 2; a++)
#pragma unroll
        for (int b = 0; b < 2; b++) acc[a][b] = (f32x4){0.f, 0.f, 0.f, 0.f};

    int ar = t >> 2, ak = (t & 3) << 3;

    for (int kt = 0; kt < 1152; kt += 32) {
        {
            const unsigned short* sH;
            const unsigned short* sL;
            int off;
            if (kt < 128) {
                off = (rowBase + ar) * 128 + kt + ak;
                sH = h2h; sL = h2l;
            } else {
                off = (rowBase + ar) * 1024 + (kt - 128) + ak;
                sH = poolh; sL = pooll;
            }
            *(uint4*)&Ah[ar * 40 + ak] = *(const uint4*)(sH + off);
            *(uint4*)&Al[ar * 40 + ak] = *(const uint4*)(sL + off);
        }
        {
            int boff = (koBase + ar) * 1152 + kt + ak;
            *(uint4*)&Bh[ar * 40 + ak] = *(const uint4*)(M1h + boff);
            *(uint4*)&Bl[ar * 40 + ak] = *(const uint4*)(M1l + boff);
        }
        __syncthreads();
        short8 bH[2], bL[2];
#pragma unroll
        for (int b = 0; b < 2; b++) {
            int boff = (qcol + (b << 4) + l15) * 40 + (quad << 3);
            bH[b] = *(const short8*)(&Bh[boff]);
            bL[b] = *(const short8*)(&Bl[boff]);
        }
#pragma unroll
        for (int a = 0; a < 2; a++) {
            int aoff = (qrow + (a << 4) + l15) * 40 + (quad << 3);
            short8 aH = *(const short8*)(&Ah[aoff]);
            short8 aL = *(const short8*)(&Al[aoff]);
#pragma unroll
            for (int b = 0; b < 2; b++) {
                acc[a][b] = __builtin_amdgcn_mfma_f32_16x16x32_bf16(aH, bH[b], acc[a][b], 0, 0, 0);
                acc[a][b] = __builtin_amdgcn_mfma_f32_16x16x32_bf16(aH, bL[b], acc[a][b], 0, 0, 0);
                acc[a][b] = __builtin_amdgcn_mfma_f32_16x16x32_bf16(aL, bH[b], acc[a][b], 0, 0, 0);
            }
        }
        __syncthreads();
    }
#pragma unroll
    for (int b = 0; b < 2; b++) {
        int col = koBase + qcol + (b << 4) + l15;
        float bias = cm1[col];
#pragma unroll
        for (int a = 0; a < 2; a++) {
#pragma unroll
            for (int rg = 0; rg < 4; rg++) {
                int row = rowBase + qrow + (a << 4) + (quad << 2) + rg;
                float v = fmaxf(acc[a][b][rg] + bias, 0.f);
                unsigned short sh, sl;
                splitf(v, sh, sl);
                dh1h[row * 1024 + col] = sh;
                dh1l[row * 1024 + col] = sl;
            }
        }
    }
}

// m2 via bf16x3 MFMA: Block: 64 rows x 128 ko, K=1024. Grid 16.
__global__ __launch_bounds__(256) void k_m2_mfma(
    const unsigned short* __restrict__ dh1h, const unsigned short* __restrict__ dh1l,
    const unsigned short* __restrict__ M2h, const unsigned short* __restrict__ M2l,
    const float* __restrict__ cm2, float* __restrict__ h_st) {
    int rowBase = blockIdx.x << 6;
    int t = threadIdx.x;
    int lane = t & 63, wv = t >> 6;
    int quad = lane >> 4, l15 = lane & 15;
    int qrow = (wv >> 1) << 5;
    int qcol = (wv & 1) << 6;
    __shared__ unsigned short Ah[64 * 40], Al[64 * 40], Bh[128 * 40], Bl[128 * 40];
    f32x4 acc[2][4];
#pragma unroll
    for (int a = 0; a < 2; a++)
#pragma unroll
        for (int b = 0; b < 4; b++) acc[a][b] = (f32x4){0.f, 0.f, 0.f, 0.f};

    int ar = t >> 2, ak = (t & 3) << 3;
    int br = t >> 1, bk = (t & 1) << 4;

    for (int kt = 0; kt < 1024; kt += 32) {
        {
            int off = (rowBase + ar) * 1024 + kt + ak;
            *(uint4*)&Ah[ar * 40 + ak] = *(const uint4*)(dh1h + off);
            *(uint4*)&Al[ar * 40 + ak] = *(const uint4*)(dh1l + off);
        }
        {
            int off = br * 1024 + kt + bk;
            *(uint4*)&Bh[br * 40 + bk] = *(const uint4*)(M2h + off);
            *(uint4*)&Bh[br * 40 + bk + 8] = *(const uint4*)(M2h + off + 8);
            *(uint4*)&Bl[br * 40 + bk] = *(const uint4*)(M2l + off);
            *(uint4*)&Bl[br * 40 + bk + 8] = *(const uint4*)(M2l + off + 8);
        }
        __syncthreads();
#pragma unroll
        for (int a = 0; a < 2; a++) {
            int aoff = (qrow + (a << 4) + l15) * 40 + (quad << 3);
            short8 aH = *(const short8*)(&Ah[aoff]);
            short8 aL = *(const short8*)(&Al[aoff]);
#pragma unroll
            for (int b = 0; b < 4; b++) {
                int boff = (qcol + (b << 4) + l15) * 40 + (quad << 3);
                short8 bH = *(const short8*)(&Bh[boff]);
                short8 bL = *(const short8*)(&Bl[boff]);
                acc[a][b] = __builtin_amdgcn_mfma_f32_16x16x32_bf16(aH, bH, acc[a][b], 0, 0, 0);
                acc[a][b] = __builtin_amdgcn_mfma_f32_16x16x32_bf16(aH, bL, acc[a][b], 0, 0, 0);
                acc[a][b] = __builtin_amdgcn_mfma_f32_16x16x32_bf16(aL, bH, acc[a][b], 0, 0, 0);
            }
        }
        __syncthreads();
    }
#pragma unroll
    for (int b = 0; b < 4; b++) {
        int col = qcol + (b << 4) + l15;
        float bias = cm2[col];
#pragma unroll
        for (int a = 0; a < 2; a++) {
#pragma unroll
            for (int rg = 0; rg < 4; rg++) {
                int row = rowBase + qrow + (a << 4) + (quad << 2) + rg;
                h_st[row * 128 + col] = fmaxf(acc[a][b][rg] + bias, 0.f);
            }
        }
    }
}

// ---------------- launch ----------------

extern "C" void kernel_launch(void* const* d_in, const int* in_sizes, int n_in,
                              void* d_out, int out_size, void* d_ws, size_t ws_size,
                              hipStream_t stream) {
    const float* last_pos     = (const float*)d_in[0];
    const float* last_pos_rel = (const float*)d_in[1];
    const float* h0   = (const float*)d_in[2];
    const float* c0   = (const float*)d_in[3];
    const float* emb_W = (const float*)d_in[5];
    const float* emb_b = (const float*)d_in[6];
    const float* lstm_Wih = (const float*)d_in[7];
    const float* lstm_Whh = (const float*)d_in[8];
    const float* lstm_bih = (const float*)d_in[9];
    const float* lstm_bhh = (const float*)d_in[10];
    const float* pos_W = (const float*)d_in[11];
    const float* pos_b = (const float*)d_in[12];
    const float* sp_W  = (const float*)d_in[13];
    const float* sp_b  = (const float*)d_in[14];
    const float* pp1_W = (const float*)d_in[15];
    const float* pp1_b = (const float*)d_in[16];
    const float* pp1_g = (const float*)d_in[17];
    const float* pp1_be= (const float*)d_in[18];
    const float* pp2_W = (const float*)d_in[19];
    const float* pp2_b = (const float*)d_in[20];
    const float* pp2_g = (const float*)d_in[21];
    const float* pp2_be= (const float*)d_in[22];
    const float* m1_W  = (const float*)d_in[23];
    const float* m1_b  = (const float*)d_in[24];
    const float* m1_g  = (const float*)d_in[25];
    const float* m1_be = (const float*)d_in[26];
    const float* m2_W  = (const float*)d_in[27];
    const float* m2_b  = (const float*)d_in[28];
    const float* m2_g  = (const float*)d_in[29];
    const float* m2_be = (const float*)d_in[30];
    float* out = (float*)d_out;

    float* p = (float*)d_ws;
    float* WgT  = p; p += 192 * 512;
    float* bg   = p; p += 512;
    float* Wh1T = p; p += 128 * 512;
    float* Mp   = p; p += 2 * 512;
    float* c1   = p; p += 512;
    unsigned short* W2bf = (unsigned short*)p; p += 512 * 1024 / 2;
    float* c2v  = p; p += 1024;
    unsigned short* M1h = (unsigned short*)p; p += 1024 * 1152 / 2;
    unsigned short* M1l = (unsigned short*)p; p += 1024 * 1152 / 2;
    float* cm1  = p; p += 1024;
    unsigned short* M2h = (unsigned short*)p; p += 128 * 1024 / 2;
    unsigned short* M2l = (unsigned short*)p; p += 128 * 1024 / 2;
    float* cm2  = p; p += 128;
    float* h_st = p; p += 1024 * 128;
    float* c_st = p; p += 1024 * 128;
    unsigned short* h2h = (unsigned short*)p; p += 1024 * 128 / 2;
    unsigned short* h2l = (unsigned short*)p; p += 1024 * 128 / 2;
    float* curr = p; p += 1024 * 2;
    float* din  = p; p += 1024 * 64;
    float* Hp   = p; p += 1024 * 512;
    unsigned short* poolh = (unsigned short*)p; p += 1024 * 1024 / 2;
    unsigned short* pooll = (unsigned short*)p; p += 1024 * 1024 / 2;
    unsigned short* dh1h = (unsigned short*)p; p += 1024 * 1024 / 2;
    unsigned short* dh1l = (unsigned short*)p; p += 1024 * 1024 / 2;
    unsigned short* x1g = (unsigned short*)p;   // 32768*512 bf16 = 33.5 MB (big-ws path only)
    size_t need = (size_t)((char*)(x1g + (size_t)32768 * 512) - (char*)d_ws);
    int big = (ws_size >= need) ? 1 : 0;

    pre_lstm<<<384, 256, 0, stream>>>(lstm_Wih, lstm_Whh, lstm_bih, lstm_bhh, WgT, bg);
    pre_wh1<<<256, 256, 0, stream>>>(pp1_W, pp1_g, Wh1T);
    pre_mp<<<2, 256, 0, stream>>>(sp_W, sp_b, pp1_W, pp1_b, pp1_g, pp1_be, Mp, c1);
    pre_w2bf<<<2048, 256, 0, stream>>>(pp2_W, pp2_b, pp2_g, pp2_be, W2bf, c2v, big);
    pre_w1split<<<4608, 256, 0, stream>>>(m1_W, m1_b, m1_g, m1_be, M1h, M1l, cm1);
    pre_w2split<<<512, 256, 0, stream>>>(m2_W, m2_b, m2_g, m2_be, M2h, M2l, cm2);
    pre_init<<<512, 256, 0, stream>>>(last_pos, last_pos_rel, h0, c0, emb_W, emb_b,
                                      h_st, c_st, curr, din);

    for (int t = 0; t < 12; t++) {
        k_lstm<<<256, 512, 0, stream>>>(WgT, bg, h_st, c_st, din, curr, h2h, h2l,
                                        pos_W, pos_b, emb_W, emb_b,
                                        Wh1T, c1, Hp, (t < 11) ? 1 : 0, out + t * 2048);
        if (t == 11) break;
        if (big) {
            k_x1<<<1024, 256, 0, stream>>>(Hp, Mp, curr, x1g);
            k_pool_g<<<2048, 256, 0, stream>>>(x1g, W2bf, c2v, poolh, pooll);
        } else {
            k_pool_mfma<<<dim3(8, 8, 32), 256, 0, stream>>>(Hp, Mp, W2bf, c2v, curr,
                                                            poolh, pooll);
        }
        k_m1_mfma<<<dim3(16, 16), 256, 0, stream>>>(h2h, h2l, poolh, pooll,
                                                    M1h, M1l, cm1, dh1h, dh1l);
        k_m2_mfma<<<16, 256, 0, stream>>>(dh1h, dh1l, M2h, M2l, cm2, h_st);
    }
}

// Round 6
// 1516.721 us; speedup vs baseline: 4.8370x; 1.0692x over previous
//
#include <hip/hip_runtime.h>
#include <hip/hip_bf16.h>
#include <math.h>

#define DEVFN __device__ __forceinline__

constexpr float BN_INV = 0.99999500003749971f; // 1/sqrt(1+1e-5)

DEVFN float sigm(float x) { return 1.0f / (1.0f + expf(-x)); }

DEVFN unsigned short f2bf(float f) {
    __hip_bfloat16 b = __float2bfloat16(f);
    return *reinterpret_cast<unsigned short*>(&b);
}
DEVFN float bf2f(unsigned short u) {
    unsigned int x = ((unsigned int)u) << 16;
    return *reinterpret_cast<float*>(&x);
}
DEVFN void splitf(float v, unsigned short& h, unsigned short& l) {
    h = f2bf(v);
    l = f2bf(v - bf2f(h));
}
DEVFN unsigned int pack2(unsigned short a, unsigned short b) {
    return (unsigned int)a | ((unsigned int)b << 16);
}

typedef __attribute__((ext_vector_type(8))) short short8;  // 8 bf16 = 4 VGPRs
typedef __attribute__((ext_vector_type(4))) float f32x4;

// async global->LDS, 16B per lane; ldst must be wave-uniform (HW adds lane*16)
#define ASYNC_COPY16(gsrc, ldst)                                                            \
    __builtin_amdgcn_global_load_lds((const __attribute__((address_space(1))) unsigned int*)(gsrc), \
                                     (__attribute__((address_space(3))) unsigned int*)(ldst), 16, 0, 0)

// ---------------- precompute kernels (run every call; ws is re-poisoned) ----------------

__global__ void pre_lstm(const float* __restrict__ Wih, const float* __restrict__ Whh,
                         const float* __restrict__ bih, const float* __restrict__ bhh,
                         float* __restrict__ WgT, float* __restrict__ bg) {
    int idx = blockIdx.x * blockDim.x + threadIdx.x;   // 192*512
    int k = idx >> 9, t = idx & 511;
    WgT[idx] = (k < 64) ? Wih[t * 64 + k] : Whh[t * 128 + (k - 64)];
    if (idx < 512) bg[idx] = bih[idx] + bhh[idx];
}

__global__ void pre_wh1(const float* __restrict__ pp1W, const float* __restrict__ pp1g,
                        float* __restrict__ Wh1T) {
    int idx = blockIdx.x * blockDim.x + threadIdx.x;   // 128*512
    int h = idx >> 9, k = idx & 511;
    Wh1T[idx] = pp1W[k * 192 + 64 + h] * (BN_INV * pp1g[k]);
}

__global__ void pre_mp(const float* __restrict__ spW, const float* __restrict__ spb,
                       const float* __restrict__ pp1W, const float* __restrict__ pp1b,
                       const float* __restrict__ pp1g, const float* __restrict__ pp1be,
                       float* __restrict__ Mp, float* __restrict__ c1) {
    int k = blockIdx.x * blockDim.x + threadIdx.x;     // 512
    float m0 = 0.f, m1 = 0.f, c0 = 0.f;
    for (int e = 0; e < 64; e++) {
        float w = pp1W[k * 192 + e];
        m0 += spW[e * 2] * w; m1 += spW[e * 2 + 1] * w; c0 += spb[e] * w;
    }
    float s = BN_INV * pp1g[k];
    Mp[k] = m0 * s; Mp[512 + k] = m1 * s;
    c1[k] = (c0 + pp1b[k]) * s + pp1be[k];
}

// pp2 weights -> bf16, optionally XOR-swizzled (chunk c of each 64-k tile stored at c^(ko&7))
__global__ void pre_w2bf(const float* __restrict__ W, const float* __restrict__ b,
                         const float* __restrict__ g, const float* __restrict__ be,
                         unsigned short* __restrict__ Wbf, float* __restrict__ cv, int swz) {
    int idx = blockIdx.x * blockDim.x + threadIdx.x;   // 1024*512
    int ko = idx >> 9, k = idx & 511;
    float s = BN_INV * g[ko];
    int outk = swz ? ((k & ~63) | ((((k >> 3) & 7) ^ (ko & 7)) << 3) | (k & 7)) : k;
    Wbf[(ko << 9) + outk] = f2bf(W[idx] * s);
    if (idx < 1024) cv[idx] = b[idx] * s + be[idx];
}

__global__ void pre_w1split(const float* __restrict__ W, const float* __restrict__ b,
                            const float* __restrict__ g, const float* __restrict__ be,
                            unsigned short* __restrict__ Wh, unsigned short* __restrict__ Wl,
                            float* __restrict__ cv) {
    int idx = blockIdx.x * blockDim.x + threadIdx.x;   // 1024*1152
    int ko = idx / 1152;
    float s = BN_INV * g[ko];
    unsigned short h, l;
    splitf(W[idx] * s, h, l);
    Wh[idx] = h; Wl[idx] = l;
    if (idx < 1024) {
        float s2 = BN_INV * g[idx];
        cv[idx] = b[idx] * s2 + be[idx];
    }
}

__global__ void pre_w2split(const float* __restrict__ W, const float* __restrict__ b,
                            const float* __restrict__ g, const float* __restrict__ be,
                            unsigned short* __restrict__ Wh, unsigned short* __restrict__ Wl,
                            float* __restrict__ cv) {
    int idx = blockIdx.x * blockDim.x + threadIdx.x;   // 128*1024
    int ko = idx >> 10;
    float s = BN_INV * g[ko];
    unsigned short h, l;
    splitf(W[idx] * s, h, l);
    Wh[idx] = h; Wl[idx] = l;
    if (idx < 128) {
        float s2 = BN_INV * g[idx];
        cv[idx] = b[idx] * s2 + be[idx];
    }
}

__global__ void pre_init(const float* __restrict__ lp, const float* __restrict__ lpr,
                         const float* __restrict__ h0, const float* __restrict__ c0,
                         const float* __restrict__ embW, const float* __restrict__ embb,
                         float* __restrict__ h_st, float* __restrict__ c_st,
                         float* __restrict__ curr, float* __restrict__ din) {
    int idx = blockIdx.x * blockDim.x + threadIdx.x;   // 1024*128
    h_st[idx] = h0[idx];
    c_st[idx] = c0[idx];
    if (idx < 1024 * 2) curr[idx] = lp[idx];
    if (idx < 1024 * 64) {
        int n = idx >> 6, e = idx & 63;
        din[idx] = fmaf(lpr[n * 2], embW[e * 2], fmaf(lpr[n * 2 + 1], embW[e * 2 + 1], embb[e]));
    }
}

// ---------------- per-step kernels ----------------

// Fused: LSTM cell (4 peds/block) + rel_pos + curr + din2 + preds + Hp (=h2@Wh1T + c1).
__global__ __launch_bounds__(512) void k_lstm(
    const float* __restrict__ WgT, const float* __restrict__ bg,
    float* __restrict__ h_st, float* __restrict__ c_st,
    float* __restrict__ din, float* __restrict__ curr,
    unsigned short* __restrict__ h2h, unsigned short* __restrict__ h2l,
    const float* __restrict__ posW, const float* __restrict__ posb,
    const float* __restrict__ embW, const float* __restrict__ embb,
    const float* __restrict__ Wh1T, const float* __restrict__ c1,
    float* __restrict__ Hp, int doHp,
    float* __restrict__ preds) {
    int n0 = blockIdx.x << 2;
    int t = threadIdx.x;
    __shared__ float xs[4][256];
    __shared__ float gates[4][512];
    __shared__ float h2s[4][128];
    __shared__ float rp[4][2];
#pragma unroll
    for (int u = 0; u < 2; u++) {
        int lin = t + (u << 9);
        int r = lin >> 8, k = lin & 255;
        float v = 0.f;
        if (k < 64) v = din[(n0 + r) * 64 + k];
        else if (k < 192) v = h_st[(n0 + r) * 128 + (k - 64)];
        xs[r][k] = v;
    }
    __syncthreads();
    float a0 = bg[t], a1 = a0, a2 = a0, a3 = a0;
#pragma unroll 4
    for (int k = 0; k < 192; k++) {
        float w = WgT[(k << 9) + t];
        a0 = fmaf(xs[0][k], w, a0);
        a1 = fmaf(xs[1][k], w, a1);
        a2 = fmaf(xs[2][k], w, a2);
        a3 = fmaf(xs[3][k], w, a3);
    }
    gates[0][t] = a0; gates[1][t] = a1; gates[2][t] = a2; gates[3][t] = a3;
    __syncthreads();
    {
        int r = t >> 7, hx = t & 127;
        float ig = sigm(gates[r][hx]);
        float fg = sigm(gates[r][128 + hx]);
        float gg = tanhf(gates[r][256 + hx]);
        float og = sigm(gates[r][384 + hx]);
        float c2 = fmaf(fg, c_st[(n0 + r) * 128 + hx], ig * gg);
        float h2 = og * tanhf(c2);
        c_st[(n0 + r) * 128 + hx] = c2;
        unsigned short sh, sl;
        splitf(h2, sh, sl);
        h2h[(n0 + r) * 128 + hx] = sh;
        h2l[(n0 + r) * 128 + hx] = sl;
        h2s[r][hx] = h2;
    }
    __syncthreads();
    int wv = t >> 6, l = t & 63;
    if (wv < 4) {
        float p0 = fmaf(h2s[wv][l], posW[l], h2s[wv][l + 64] * posW[l + 64]);
        float p1 = fmaf(h2s[wv][l], posW[128 + l], h2s[wv][l + 64] * posW[192 + l]);
#pragma unroll
        for (int off = 32; off > 0; off >>= 1) {
            p0 += __shfl_down(p0, off, 64);
            p1 += __shfl_down(p1, off, 64);
        }
        if (l == 0) { rp[wv][0] = p0 + posb[0]; rp[wv][1] = p1 + posb[1]; }
    }
    __syncthreads();
    if (t < 256) {
        int r = t >> 6, e = t & 63;
        float r0 = rp[r][0], r1 = rp[r][1];
        din[(n0 + r) * 64 + e] = fmaf(r0, embW[e * 2], fmaf(r1, embW[e * 2 + 1], embb[e]));
        if (e == 0) {
            preds[(n0 + r) * 2] = r0; preds[(n0 + r) * 2 + 1] = r1;
            curr[(n0 + r) * 2] += r0; curr[(n0 + r) * 2 + 1] += r1;
        }
    }
    if (doHp) {
        float cc = c1[t];
        float q0 = cc, q1 = cc, q2 = cc, q3 = cc;
#pragma unroll 4
        for (int h = 0; h < 128; h++) {
            float w = Wh1T[(h << 9) + t];
            q0 = fmaf(h2s[0][h], w, q0);
            q1 = fmaf(h2s[1][h], w, q1);
            q2 = fmaf(h2s[2][h], w, q2);
            q3 = fmaf(h2s[3][h], w, q3);
        }
        Hp[((n0 + 0) << 9) + t] = q0;
        Hp[((n0 + 1) << 9) + t] = q1;
        Hp[((n0 + 2) << 9) + t] = q2;
        Hp[((n0 + 3) << 9) + t] = q3;
    }
}

// Build x1 bf16 once per step, XOR-swizzled within each 64-k tile (chunk c at c^(j&7)).
// XCD-swizzled grid (1024 linear): scene s runs on XCD s%8 so x1 lands in the L2
// that k_pool_g will read it from.  Block = one (s,i): 32 j rows x 512 k.
__global__ __launch_bounds__(256) void k_x1(
    const float* __restrict__ Hp, const float* __restrict__ Mp,
    const float* __restrict__ curr, unsigned short* __restrict__ x1g) {
    int bid = blockIdx.x;
    int c = bid & 7, q = bid >> 3;       // q 0..127
    int i = q & 31, g = q >> 5;          // g 0..3
    int s = (g << 3) + c;
    int si = (s << 5) + i;
    int t = threadIdx.x;
    __shared__ float rx[32], ry[32];
    __shared__ float m0s[512], m1s[512];
    for (int u = t; u < 512; u += 256) { m0s[u] = Mp[u]; m1s[u] = Mp[512 + u]; }
    if (t < 32) {
        int jg = (s << 5) + t;
        float dx = curr[jg * 2] - curr[si * 2];
        float dy = curr[jg * 2 + 1] - curr[si * 2 + 1];
        float den = fmaxf(sqrtf(dx * dx + dy * dy), 1e-12f);
        rx[t] = dx / den; ry[t] = dy / den;
    }
    __syncthreads();
    int j = t >> 3, c8 = t & 7;
    float rxv = rx[j], ryv = ry[j];
    const float* hp = Hp + (((s << 5) + j) << 9);
    unsigned short* op = x1g + ((size_t)((si << 5) + j) << 9);
    int swz = (c8 ^ (j & 7)) << 3;
#pragma unroll
    for (int kt = 0; kt < 512; kt += 64) {
        int k = kt + (c8 << 3);
        float4 ha = *(const float4*)(hp + k);
        float4 hb = *(const float4*)(hp + k + 4);
        uint4 o;
        o.x = pack2(f2bf(fmaxf(fmaf(rxv, m0s[k + 0], fmaf(ryv, m1s[k + 0], ha.x)), 0.f)),
                    f2bf(fmaxf(fmaf(rxv, m0s[k + 1], fmaf(ryv, m1s[k + 1], ha.y)), 0.f)));
        o.y = pack2(f2bf(fmaxf(fmaf(rxv, m0s[k + 2], fmaf(ryv, m1s[k + 2], ha.z)), 0.f)),
                    f2bf(fmaxf(fmaf(rxv, m0s[k + 3], fmaf(ryv, m1s[k + 3], ha.w)), 0.f)));
        o.z = pack2(f2bf(fmaxf(fmaf(rxv, m0s[k + 4], fmaf(ryv, m1s[k + 4], hb.x)), 0.f)),
                    f2bf(fmaxf(fmaf(rxv, m0s[k + 5], fmaf(ryv, m1s[k + 5], hb.y)), 0.f)));
        o.w = pack2(f2bf(fmaxf(fmaf(rxv, m0s[k + 6], fmaf(ryv, m1s[k + 6], hb.z)), 0.f)),
                    f2bf(fmaxf(fmaf(rxv, m0s[k + 7], fmaf(ryv, m1s[k + 7], hb.w)), 0.f)));
        *(uint4*)(op + kt + swz) = o;
    }
}

// Pure GEMM + max-pool. 256x256 tile, 1024 threads (16 waves, each a 64x64 quadrant),
// BK=64, K=512. XCD-swizzled linear grid (512): XCD c owns scenes {c,c+8,c+16,c+24}.
// LDS fragment addresses are kt-invariant (r&7 == l15&7) -> hoisted.
__global__ __launch_bounds__(1024, 4) void k_pool_g(
    const unsigned short* __restrict__ x1g, const unsigned short* __restrict__ W2bf,
    const float* __restrict__ c2v,
    unsigned short* __restrict__ poolh, unsigned short* __restrict__ pooll) {
    int bid = blockIdx.x;
    int c = bid & 7, q = bid >> 3;       // q 0..63
    int inner = q & 15, g = q >> 4;      // g 0..3
    int s = (g << 3) + c;
    int rb = inner >> 2;                 // 256-row group (8 i's)
    int koB = (inner & 3) << 8;          // 0,256,512,768
    int t = threadIdx.x;
    int lane = t & 63, wv = t >> 6;      // 16 waves
    int quad = lane >> 4, l15 = lane & 15;
    int wr = wv >> 2, wc = wv & 3;
    int qrow = wr << 6, qcol = wc << 6;
    __shared__ unsigned short As[256 * 64];
    __shared__ unsigned short Bs[256 * 64];
    f32x4 acc[4][4];
#pragma unroll
    for (int a = 0; a < 4; a++)
#pragma unroll
        for (int b = 0; b < 4; b++) acc[a][b] = (f32x4){0.f, 0.f, 0.f, 0.f};

    int rlane = lane >> 3;               // 0..7
    int clane = (lane & 7) << 3;         // k-chunk (shorts)
    const unsigned short* gA = x1g + (size_t)((s << 10) + (rb << 8) + (wv << 4) + rlane) * 512 + clane;
    const unsigned short* gB = W2bf + (size_t)(koB + (wv << 4) + rlane) * 512 + clane;
    unsigned short* lA = As + (wv << 10);         // rows wv*16..wv*16+15
    unsigned short* lB = Bs + (wv << 10);
    // hoisted fragment bases (kt-invariant): pos = ((kt2<<2)+quad) ^ (l15&7)
    const unsigned short* pa0 = As + ((qrow + l15) << 6) + ((quad ^ (l15 & 7)) << 3);
    const unsigned short* pb0 = Bs + ((qcol + l15) << 6) + ((quad ^ (l15 & 7)) << 3);
    const unsigned short* pa1 = As + ((qrow + l15) << 6) + (((4 + quad) ^ (l15 & 7)) << 3);
    const unsigned short* pb1 = Bs + ((qcol + l15) << 6) + (((4 + quad) ^ (l15 & 7)) << 3);

    for (int kt = 0; kt < 512; kt += 64) {
        ASYNC_COPY16(gA + kt, lA);
        ASYNC_COPY16(gA + kt + 8 * 512, lA + (8 << 6));
        ASYNC_COPY16(gB + kt, lB);
        ASYNC_COPY16(gB + kt + 8 * 512, lB + (8 << 6));
        __syncthreads();
        {
            short8 aF[4], bF[4];
#pragma unroll
            for (int a = 0; a < 4; a++) aF[a] = *(const short8*)(pa0 + (a << 10));
#pragma unroll
            for (int b = 0; b < 4; b++) bF[b] = *(const short8*)(pb0 + (b << 10));
#pragma unroll
            for (int a = 0; a < 4; a++)
#pragma unroll
                for (int b = 0; b < 4; b++)
                    acc[a][b] = __builtin_amdgcn_mfma_f32_16x16x32_bf16(aF[a], bF[b], acc[a][b], 0, 0, 0);
#pragma unroll
            for (int a = 0; a < 4; a++) aF[a] = *(const short8*)(pa1 + (a << 10));
#pragma unroll
            for (int b = 0; b < 4; b++) bF[b] = *(const short8*)(pb1 + (b << 10));
#pragma unroll
            for (int a = 0; a < 4; a++)
#pragma unroll
                for (int b = 0; b < 4; b++)
                    acc[a][b] = __builtin_amdgcn_mfma_f32_16x16x32_bf16(aF[a], bF[b], acc[a][b], 0, 0, 0);
        }
        __syncthreads();
    }

    // max over j: quadrant rows = 2 i's (32 j each); a=0,1 -> i0, a=2,3 -> i0+1
    float mx0[4], mx1[4];
#pragma unroll
    for (int b = 0; b < 4; b++) {
        float m = acc[0][b].x;
#pragma unroll
        for (int a = 0; a < 2; a++) {
            m = fmaxf(m, acc[a][b].x); m = fmaxf(m, acc[a][b].y);
            m = fmaxf(m, acc[a][b].z); m = fmaxf(m, acc[a][b].w);
        }
        m = fmaxf(m, __shfl_xor(m, 16));
        m = fmaxf(m, __shfl_xor(m, 32));
        mx0[b] = m;
        float n = acc[2][b].x;
#pragma unroll
        for (int a = 2; a < 4; a++) {
            n = fmaxf(n, acc[a][b].x); n = fmaxf(n, acc[a][b].y);
            n = fmaxf(n, acc[a][b].z); n = fmaxf(n, acc[a][b].w);
        }
        n = fmaxf(n, __shfl_xor(n, 16));
        n = fmaxf(n, __shfl_xor(n, 32));
        mx1[b] = n;
    }
    float v0 = (quad == 0) ? mx0[0] : (quad == 1) ? mx0[1] : (quad == 2) ? mx0[2] : mx0[3];
    float v1 = (quad == 0) ? mx1[0] : (quad == 1) ? mx1[1] : (quad == 2) ? mx1[2] : mx1[3];
    int col = koB + qcol + (quad << 4) + l15;
    int i0 = (rb << 3) + (wr << 1);
    int si0 = (s << 5) + i0;
    float bias = c2v[col];
    float w0 = fmaxf(v0 + bias, 0.f);
    float w1 = fmaxf(v1 + bias, 0.f);
    unsigned short h0, l0, h1, l1;
    splitf(w0, h0, l0); splitf(w1, h1, l1);
    poolh[si0 * 1024 + col] = h0; pooll[si0 * 1024 + col] = l0;
    poolh[(si0 + 1) * 1024 + col] = h1; pooll[(si0 + 1) * 1024 + col] = l1;
}

// Fallback (small ws): fused build + GEMM + pool. W2bf must be UNswizzled for this path.
__global__ __launch_bounds__(256) void k_pool_mfma(
    const float* __restrict__ Hp, const float* __restrict__ Mp,
    const unsigned short* __restrict__ W2bf,
    const float* __restrict__ c2v, const float* __restrict__ curr,
    unsigned short* __restrict__ poolh, unsigned short* __restrict__ pooll) {
    int s = blockIdx.z;
    int rb = blockIdx.y;
    int koBase = blockIdx.x << 7;
    int t = threadIdx.x;
    int lane = t & 63, wv = t >> 6;
    int quad = lane >> 4, l15 = lane & 15;
    int qrow = (wv >> 1) << 6;
    int qcol = (wv & 1) << 6;

    __shared__ unsigned short As[128 * 40];
    __shared__ unsigned short Bs[128 * 40];
    __shared__ float rx[128], ry[128];

    if (t < 128) {
        int iL = t >> 5, j = t & 31;
        int ig = (s << 5) + (rb << 2) + iL;
        int jg = (s << 5) + j;
        float dx = curr[jg * 2] - curr[ig * 2];
        float dy = curr[jg * 2 + 1] - curr[ig * 2 + 1];
        float den = fmaxf(sqrtf(dx * dx + dy * dy), 1e-12f);
        rx[t] = dx / den; ry[t] = dy / den;
    }
    __syncthreads();

    f32x4 acc[4][4];
#pragma unroll
    for (int a = 0; a < 4; a++)
#pragma unroll
        for (int b = 0; b < 4; b++) acc[a][b] = (f32x4){0.f, 0.f, 0.f, 0.f};

    int r0 = t >> 3, c4 = (t & 7) << 2;
    int bn = t >> 1, bk = (t & 1) << 4;

    for (int kt = 0; kt < 512; kt += 32) {
#pragma unroll
        for (int p = 0; p < 4; p++) {
            int rr = r0 + (p << 5);
            int j = rr & 31;
            int kg = kt + c4;
            float4 hv = *(const float4*)(Hp + (((s << 5) + j) << 9) + kg);
            float4 m0 = *(const float4*)(Mp + kg);
            float4 m1 = *(const float4*)(Mp + 512 + kg);
            float rxv = rx[rr], ryv = ry[rr];
            float v0 = fmaxf(fmaf(rxv, m0.x, fmaf(ryv, m1.x, hv.x)), 0.f);
            float v1 = fmaxf(fmaf(rxv, m0.y, fmaf(ryv, m1.y, hv.y)), 0.f);
            float v2 = fmaxf(fmaf(rxv, m0.z, fmaf(ryv, m1.z, hv.z)), 0.f);
            float v3 = fmaxf(fmaf(rxv, m0.w, fmaf(ryv, m1.w, hv.w)), 0.f);
            unsigned int u0 = pack2(f2bf(v0), f2bf(v1));
            unsigned int u1 = pack2(f2bf(v2), f2bf(v3));
            *(uint2*)(&As[rr * 40 + c4]) = make_uint2(u0, u1);
        }
        {
            const unsigned short* src = W2bf + (((koBase + bn) << 9) + kt + bk);
            uint4 w0 = *(const uint4*)src;
            uint4 w1 = *(const uint4*)(src + 8);
            *(uint4*)(&Bs[bn * 40 + bk]) = w0;
            *(uint4*)(&Bs[bn * 40 + bk + 8]) = w1;
        }
        __syncthreads();
        short8 bF[4];
#pragma unroll
        for (int b = 0; b < 4; b++)
            bF[b] = *(const short8*)(&Bs[(qcol + (b << 4) + l15) * 40 + (quad << 3)]);
#pragma unroll
        for (int a = 0; a < 4; a++) {
            short8 aF = *(const short8*)(&As[(qrow + (a << 4) + l15) * 40 + (quad << 3)]);
#pragma unroll
            for (int b = 0; b < 4; b++)
                acc[a][b] = __builtin_amdgcn_mfma_f32_16x16x32_bf16(aF, bF[b], acc[a][b], 0, 0, 0);
        }
        __syncthreads();
    }

    float mx0[4], mx1[4];
#pragma unroll
    for (int b = 0; b < 4; b++) {
        float m = acc[0][b].x;
#pragma unroll
        for (int a = 0; a < 2; a++) {
            m = fmaxf(m, acc[a][b].x); m = fmaxf(m, acc[a][b].y);
            m = fmaxf(m, acc[a][b].z); m = fmaxf(m, acc[a][b].w);
        }
        m = fmaxf(m, __shfl_xor(m, 16));
        m = fmaxf(m, __shfl_xor(m, 32));
        mx0[b] = m;
        float n = acc[2][b].x;
#pragma unroll
        for (int a = 2; a < 4; a++) {
            n = fmaxf(n, acc[a][b].x); n = fmaxf(n, acc[a][b].y);
            n = fmaxf(n, acc[a][b].z); n = fmaxf(n, acc[a][b].w);
        }
        n = fmaxf(n, __shfl_xor(n, 16));
        n = fmaxf(n, __shfl_xor(n, 32));
        mx1[b] = n;
    }
    float v0 = (quad == 0) ? mx0[0] : (quad == 1) ? mx0[1] : (quad == 2) ? mx0[2] : mx0[3];
    float v1 = (quad == 0) ? mx1[0] : (quad == 1) ? mx1[1] : (quad == 2) ? mx1[2] : mx1[3];
    int col = koBase + qcol + (quad << 4) + l15;
    int i0 = (rb << 2) + ((wv >> 1) << 1);
    int si0 = (s << 5) + i0;
    float bias = c2v[col];
    float w0 = fmaxf(v0 + bias, 0.f);
    float w1 = fmaxf(v1 + bias, 0.f);
    unsigned short h0, l0, h1, l1;
    splitf(w0, h0, l0); splitf(w1, h1, l1);
    poolh[si0 * 1024 + col] = h0; pooll[si0 * 1024 + col] = l0;
    poolh[(si0 + 1) * 1024 + col] = h1; pooll[(si0 + 1) * 1024 + col] = l1;
}

// m1 via bf16x3 MFMA. Block: 64 rows x 64 ko, K=1152, B-frags hoisted.
__global__ __launch_bounds__(256) void k_m1_mfma(
    const unsigned short* __restrict__ h2h, const unsigned short* __restrict__ h2l,
    const unsigned short* __restrict__ poolh, const unsigned short* __restrict__ pooll,
    const unsigned short* __restrict__ M1h, const unsigned short* __restrict__ M1l,
    const float* __restrict__ cm1,
    unsigned short* __restrict__ dh1h, unsigned short* __restrict__ dh1l) {
    int rowBase = blockIdx.y << 6;
    int koBase = blockIdx.x << 6;
    int t = threadIdx.x;
    int lane = t & 63, wv = t >> 6;
    int quad = lane >> 4, l15 = lane & 15;
    int qrow = (wv >> 1) << 5, qcol = (wv & 1) << 5;
    __shared__ unsigned short Ah[64 * 40], Al[64 * 40], Bh[64 * 40], Bl[64 * 40];
    f32x4 acc[2][2];
#pragma unroll
    for (int a = 0; a < 2; a++)
#pragma unroll
        for (int b = 0; b < 2; b++) acc[a][b] = (f32x4){0.f, 0.f, 0.f, 0.f};

    int ar = t >> 2, ak = (t & 3) << 3;

    for (int kt = 0; kt < 1152; kt += 32) {
        {
            const unsigned short* sH;
            const unsigned short* sL;
            int off;
            if (kt < 128) {
                off = (rowBase + ar) * 128 + kt + ak;
                sH = h2h; sL = h2l;
            } else {
                off = (rowBase + ar) * 1024 + (kt - 128) + ak;
                sH = poolh; sL = pooll;
            }
            *(uint4*)&Ah[ar * 40 + ak] = *(const uint4*)(sH + off);
            *(uint4*)&Al[ar * 40 + ak] = *(const uint4*)(sL + off);
        }
        {
            int boff = (koBase + ar) * 1152 + kt + ak;
            *(uint4*)&Bh[ar * 40 + ak] = *(const uint4*)(M1h + boff);
            *(uint4*)&Bl[ar * 40 + ak] = *(const uint4*)(M1l + boff);
        }
        __syncthreads();
        short8 bH[2], bL[2];
#pragma unroll
        for (int b = 0; b < 2; b++) {
            int boff = (qcol + (b << 4) + l15) * 40 + (quad << 3);
            bH[b] = *(const short8*)(&Bh[boff]);
            bL[b] = *(const short8*)(&Bl[boff]);
        }
#pragma unroll
        for (int a = 0; a < 2; a++) {
            int aoff = (qrow + (a << 4) + l15) * 40 + (quad << 3);
            short8 aH = *(const short8*)(&Ah[aoff]);
            short8 aL = *(const short8*)(&Al[aoff]);
#pragma unroll
            for (int b = 0; b < 2; b++) {
                acc[a][b] = __builtin_amdgcn_mfma_f32_16x16x32_bf16(aH, bH[b], acc[a][b], 0, 0, 0);
                acc[a][b] = __builtin_amdgcn_mfma_f32_16x16x32_bf16(aH, bL[b], acc[a][b], 0, 0, 0);
                acc[a][b] = __builtin_amdgcn_mfma_f32_16x16x32_bf16(aL, bH[b], acc[a][b], 0, 0, 0);
            }
        }
        __syncthreads();
    }
#pragma unroll
    for (int b = 0; b < 2; b++) {
        int col = koBase + qcol + (b << 4) + l15;
        float bias = cm1[col];
#pragma unroll
        for (int a = 0; a < 2; a++) {
#pragma unroll
            for (int rg = 0; rg < 4; rg++) {
                int row = rowBase + qrow + (a << 4) + (quad << 2) + rg;
                float v = fmaxf(acc[a][b][rg] + bias, 0.f);
                unsigned short sh, sl;
                splitf(v, sh, sl);
                dh1h[row * 1024 + col] = sh;
                dh1l[row * 1024 + col] = sl;
            }
        }
    }
}

// m2 via bf16x3 MFMA: Block: 64 rows x 128 ko, K=1024. Grid 16.
__global__ __launch_bounds__(256) void k_m2_mfma(
    const unsigned short* __restrict__ dh1h, const unsigned short* __restrict__ dh1l,
    const unsigned short* __restrict__ M2h, const unsigned short* __restrict__ M2l,
    const float* __restrict__ cm2, float* __restrict__ h_st) {
    int rowBase = blockIdx.x << 6;
    int t = threadIdx.x;
    int lane = t & 63, wv = t >> 6;
    int quad = lane >> 4, l15 = lane & 15;
    int qrow = (wv >> 1) << 5;
    int qcol = (wv & 1) << 6;
    __shared__ unsigned short Ah[64 * 40], Al[64 * 40], Bh[128 * 40], Bl[128 * 40];
    f32x4 acc[2][4];
#pragma unroll
    for (int a = 0; a < 2; a++)
#pragma unroll
        for (int b = 0; b < 4; b++) acc[a][b] = (f32x4){0.f, 0.f, 0.f, 0.f};

    int ar = t >> 2, ak = (t & 3) << 3;
    int br = t >> 1, bk = (t & 1) << 4;

    for (int kt = 0; kt < 1024; kt += 32) {
        {
            int off = (rowBase + ar) * 1024 + kt + ak;
            *(uint4*)&Ah[ar * 40 + ak] = *(const uint4*)(dh1h + off);
            *(uint4*)&Al[ar * 40 + ak] = *(const uint4*)(dh1l + off);
        }
        {
            int off = br * 1024 + kt + bk;
            *(uint4*)&Bh[br * 40 + bk] = *(const uint4*)(M2h + off);
            *(uint4*)&Bh[br * 40 + bk + 8] = *(const uint4*)(M2h + off + 8);
            *(uint4*)&Bl[br * 40 + bk] = *(const uint4*)(M2l + off);
            *(uint4*)&Bl[br * 40 + bk + 8] = *(const uint4*)(M2l + off + 8);
        }
        __syncthreads();
#pragma unroll
        for (int a = 0; a < 2; a++) {
            int aoff = (qrow + (a << 4) + l15) * 40 + (quad << 3);
            short8 aH = *(const short8*)(&Ah[aoff]);
            short8 aL = *(const short8*)(&Al[aoff]);
#pragma unroll
            for (int b = 0; b < 4; b++) {
                int boff = (qcol + (b << 4) + l15) * 40 + (quad << 3);
                short8 bH = *(const short8*)(&Bh[boff]);
                short8 bL = *(const short8*)(&Bl[boff]);
                acc[a][b] = __builtin_amdgcn_mfma_f32_16x16x32_bf16(aH, bH, acc[a][b], 0, 0, 0);
                acc[a][b] = __builtin_amdgcn_mfma_f32_16x16x32_bf16(aH, bL, acc[a][b], 0, 0, 0);
                acc[a][b] = __builtin_amdgcn_mfma_f32_16x16x32_bf16(aL, bH, acc[a][b], 0, 0, 0);
            }
        }
        __syncthreads();
    }
#pragma unroll
    for (int b = 0; b < 4; b++) {
        int col = qcol + (b << 4) + l15;
        float bias = cm2[col];
#pragma unroll
        for (int a = 0; a < 2; a++) {
#pragma unroll
            for (int rg = 0; rg < 4; rg++) {
                int row = rowBase + qrow + (a << 4) + (quad << 2) + rg;
                h_st[row * 128 + col] = fmaxf(acc[a][b][rg] + bias, 0.f);
            }
        }
    }
}

// ---------------- launch ----------------

extern "C" void kernel_launch(void* const* d_in, const int* in_sizes, int n_in,
                              void* d_out, int out_size, void* d_ws, size_t ws_size,
                              hipStream_t stream) {
    const float* last_pos     = (const float*)d_in[0];
    const float* last_pos_rel = (const float*)d_in[1];
    const float* h0   = (const float*)d_in[2];
    const float* c0   = (const float*)d_in[3];
    const float* emb_W = (const float*)d_in[5];
    const float* emb_b = (const float*)d_in[6];
    const float* lstm_Wih = (const float*)d_in[7];
    const float* lstm_Whh = (const float*)d_in[8];
    const float* lstm_bih = (const float*)d_in[9];
    const float* lstm_bhh = (const float*)d_in[10];
    const float* pos_W = (const float*)d_in[11];
    const float* pos_b = (const float*)d_in[12];
    const float* sp_W  = (const float*)d_in[13];
    const float* sp_b  = (const float*)d_in[14];
    const float* pp1_W = (const float*)d_in[15];
    const float* pp1_b = (const float*)d_in[16];
    const float* pp1_g = (const float*)d_in[17];
    const float* pp1_be= (const float*)d_in[18];
    const float* pp2_W = (const float*)d_in[19];
    const float* pp2_b = (const float*)d_in[20];
    const float* pp2_g = (const float*)d_in[21];
    const float* pp2_be= (const float*)d_in[22];
    const float* m1_W  = (const float*)d_in[23];
    const float* m1_b  = (const float*)d_in[24];
    const float* m1_g  = (const float*)d_in[25];
    const float* m1_be = (const float*)d_in[26];
    const float* m2_W  = (const float*)d_in[27];
    const float* m2_b  = (const float*)d_in[28];
    const float* m2_g  = (const float*)d_in[29];
    const float* m2_be = (const float*)d_in[30];
    float* out = (float*)d_out;

    float* p = (float*)d_ws;
    float* WgT  = p; p += 192 * 512;
    float* bg   = p; p += 512;
    float* Wh1T = p; p += 128 * 512;
    float* Mp   = p; p += 2 * 512;
    float* c1   = p; p += 512;
    unsigned short* W2bf = (unsigned short*)p; p += 512 * 1024 / 2;
    float* c2v  = p; p += 1024;
    unsigned short* M1h = (unsigned short*)p; p += 1024 * 1152 / 2;
    unsigned short* M1l = (unsigned short*)p; p += 1024 * 1152 / 2;
    float* cm1  = p; p += 1024;
    unsigned short* M2h = (unsigned short*)p; p += 128 * 1024 / 2;
    unsigned short* M2l = (unsigned short*)p; p += 128 * 1024 / 2;
    float* cm2  = p; p += 128;
    float* h_st = p; p += 1024 * 128;
    float* c_st = p; p += 1024 * 128;
    unsigned short* h2h = (unsigned short*)p; p += 1024 * 128 / 2;
    unsigned short* h2l = (unsigned short*)p; p += 1024 * 128 / 2;
    float* curr = p; p += 1024 * 2;
    float* din  = p; p += 1024 * 64;
    float* Hp   = p; p += 1024 * 512;
    unsigned short* poolh = (unsigned short*)p; p += 1024 * 1024 / 2;
    unsigned short* pooll = (unsigned short*)p; p += 1024 * 1024 / 2;
    unsigned short* dh1h = (unsigned short*)p; p += 1024 * 1024 / 2;
    unsigned short* dh1l = (unsigned short*)p; p += 1024 * 1024 / 2;
    unsigned short* x1g = (unsigned short*)p;   // 32768*512 bf16 = 33.5 MB (big-ws path only)
    size_t need = (size_t)((char*)(x1g + (size_t)32768 * 512) - (char*)d_ws);
    int big = (ws_size >= need) ? 1 : 0;

    pre_lstm<<<384, 256, 0, stream>>>(lstm_Wih, lstm_Whh, lstm_bih, lstm_bhh, WgT, bg);
    pre_wh1<<<256, 256, 0, stream>>>(pp1_W, pp1_g, Wh1T);
    pre_mp<<<2, 256, 0, stream>>>(sp_W, sp_b, pp1_W, pp1_b, pp1_g, pp1_be, Mp, c1);
    pre_w2bf<<<2048, 256, 0, stream>>>(pp2_W, pp2_b, pp2_g, pp2_be, W2bf, c2v, big);
    pre_w1split<<<4608, 256, 0, stream>>>(m1_W, m1_b, m1_g, m1_be, M1h, M1l, cm1);
    pre_w2split<<<512, 256, 0, stream>>>(m2_W, m2_b, m2_g, m2_be, M2h, M2l, cm2);
    pre_init<<<512, 256, 0, stream>>>(last_pos, last_pos_rel, h0, c0, emb_W, emb_b,
                                      h_st, c_st, curr, din);

    for (int t = 0; t < 12; t++) {
        k_lstm<<<256, 512, 0, stream>>>(WgT, bg, h_st, c_st, din, curr, h2h, h2l,
                                        pos_W, pos_b, emb_W, emb_b,
                                        Wh1T, c1, Hp, (t < 11) ? 1 : 0, out + t * 2048);
        if (t == 11) break;
        if (big) {
            k_x1<<<1024, 256, 0, stream>>>(Hp, Mp, curr, x1g);
            k_pool_g<<<512, 1024, 0, stream>>>(x1g, W2bf, c2v, poolh, pooll);
        } else {
            k_pool_mfma<<<dim3(8, 8, 32), 256, 0, stream>>>(Hp, Mp, W2bf, c2v, curr,
                                                            poolh, pooll);
        }
        k_m1_mfma<<<dim3(16, 16), 256, 0, stream>>>(h2h, h2l, poolh, pooll,
                                                    M1h, M1l, cm1, dh1h, dh1l);
        k_m2_mfma<<<16, 256, 0, stream>>>(dh1h, dh1l, M2h, M2l, cm2, h_st);
    }
}

// Round 7
// 1386.727 us; speedup vs baseline: 5.2904x; 1.0937x over previous
//
#include <hip/hip_runtime.h>
#include <hip/hip_bf16.h>
#include <math.h>

#define DEVFN __device__ __forceinline__

constexpr float BN_INV = 0.99999500003749971f; // 1/sqrt(1+1e-5)

DEVFN float sigm(float x) { return 1.0f / (1.0f + expf(-x)); }

DEVFN unsigned short f2bf(float f) {
    __hip_bfloat16 b = __float2bfloat16(f);
    return *reinterpret_cast<unsigned short*>(&b);
}
DEVFN float bf2f(unsigned short u) {
    unsigned int x = ((unsigned int)u) << 16;
    return *reinterpret_cast<float*>(&x);
}
DEVFN void splitf(float v, unsigned short& h, unsigned short& l) {
    h = f2bf(v);
    l = f2bf(v - bf2f(h));
}
DEVFN unsigned int pack2(unsigned short a, unsigned short b) {
    return (unsigned int)a | ((unsigned int)b << 16);
}

typedef __attribute__((ext_vector_type(8))) short short8;  // 8 bf16 = 4 VGPRs
typedef __attribute__((ext_vector_type(4))) float f32x4;

// async global->LDS, 16B per lane; ldst must be wave-uniform (HW adds lane*16)
#define ASYNC_COPY16(gsrc, ldst)                                                            \
    __builtin_amdgcn_global_load_lds((const __attribute__((address_space(1))) unsigned int*)(gsrc), \
                                     (__attribute__((address_space(3))) unsigned int*)(ldst), 16, 0, 0)

// ---------------- precompute kernels (run every call; ws is re-poisoned) ----------------

// Merged small precompute: [0,384) lstm-weight transpose, [384,640) wh1,
// [640,642) Mp/c1, [642,1154) state init.
__global__ void pre_misc(
    const float* __restrict__ Wih, const float* __restrict__ Whh,
    const float* __restrict__ bih, const float* __restrict__ bhh,
    float* __restrict__ WgT, float* __restrict__ bg,
    const float* __restrict__ pp1W, const float* __restrict__ pp1g,
    float* __restrict__ Wh1T,
    const float* __restrict__ spW, const float* __restrict__ spb,
    const float* __restrict__ pp1b, const float* __restrict__ pp1be,
    float* __restrict__ Mp, float* __restrict__ c1,
    const float* __restrict__ lp, const float* __restrict__ lpr,
    const float* __restrict__ h0, const float* __restrict__ c0,
    const float* __restrict__ embW, const float* __restrict__ embb,
    float* __restrict__ h_st, float* __restrict__ c_st,
    float* __restrict__ curr, float* __restrict__ din) {
    int bid = blockIdx.x, t = threadIdx.x;
    if (bid < 384) {
        int idx = bid * 256 + t;           // 192*512
        int k = idx >> 9, tt = idx & 511;
        WgT[idx] = (k < 64) ? Wih[tt * 64 + k] : Whh[tt * 128 + (k - 64)];
        if (idx < 512) bg[idx] = bih[idx] + bhh[idx];
    } else if (bid < 640) {
        int idx = (bid - 384) * 256 + t;   // 128*512
        int h = idx >> 9, k = idx & 511;
        Wh1T[idx] = pp1W[k * 192 + 64 + h] * (BN_INV * pp1g[k]);
    } else if (bid < 642) {
        int k = (bid - 640) * 256 + t;     // 512
        float m0 = 0.f, m1 = 0.f, c0v = 0.f;
        for (int e = 0; e < 64; e++) {
            float w = pp1W[k * 192 + e];
            m0 += spW[e * 2] * w; m1 += spW[e * 2 + 1] * w; c0v += spb[e] * w;
        }
        float s = BN_INV * pp1g[k];
        Mp[k] = m0 * s; Mp[512 + k] = m1 * s;
        c1[k] = (c0v + pp1b[k]) * s + pp1be[k];
    } else {
        int idx = (bid - 642) * 256 + t;   // 1024*128
        h_st[idx] = h0[idx];
        c_st[idx] = c0[idx];
        if (idx < 1024 * 2) curr[idx] = lp[idx];
        if (idx < 1024 * 64) {
            int n = idx >> 6, e = idx & 63;
            din[idx] = fmaf(lpr[n * 2], embW[e * 2], fmaf(lpr[n * 2 + 1], embW[e * 2 + 1], embb[e]));
        }
    }
}

// pp2 weights -> bf16, optionally XOR-swizzled (chunk c of each 64-k tile stored at c^(ko&7))
__global__ void pre_w2bf(const float* __restrict__ W, const float* __restrict__ b,
                         const float* __restrict__ g, const float* __restrict__ be,
                         unsigned short* __restrict__ Wbf, float* __restrict__ cv, int swz) {
    int idx = blockIdx.x * blockDim.x + threadIdx.x;   // 1024*512
    int ko = idx >> 9, k = idx & 511;
    float s = BN_INV * g[ko];
    int outk = swz ? ((k & ~63) | ((((k >> 3) & 7) ^ (ko & 7)) << 3) | (k & 7)) : k;
    Wbf[(ko << 9) + outk] = f2bf(W[idx] * s);
    if (idx < 1024) cv[idx] = b[idx] * s + be[idx];
}

__global__ void pre_w1split(const float* __restrict__ W, const float* __restrict__ b,
                            const float* __restrict__ g, const float* __restrict__ be,
                            unsigned short* __restrict__ Wh, unsigned short* __restrict__ Wl,
                            float* __restrict__ cv) {
    int idx = blockIdx.x * blockDim.x + threadIdx.x;   // 1024*1152
    int ko = idx / 1152;
    float s = BN_INV * g[ko];
    unsigned short h, l;
    splitf(W[idx] * s, h, l);
    Wh[idx] = h; Wl[idx] = l;
    if (idx < 1024) {
        float s2 = BN_INV * g[idx];
        cv[idx] = b[idx] * s2 + be[idx];
    }
}

__global__ void pre_w2split(const float* __restrict__ W, const float* __restrict__ b,
                            const float* __restrict__ g, const float* __restrict__ be,
                            unsigned short* __restrict__ Wh, unsigned short* __restrict__ Wl,
                            float* __restrict__ cv) {
    int idx = blockIdx.x * blockDim.x + threadIdx.x;   // 128*1024
    int ko = idx >> 10;
    float s = BN_INV * g[ko];
    unsigned short h, l;
    splitf(W[idx] * s, h, l);
    Wh[idx] = h; Wl[idx] = l;
    if (idx < 128) {
        float s2 = BN_INV * g[idx];
        cv[idx] = b[idx] * s2 + be[idx];
    }
}

// ---------------- per-step kernels ----------------

// Fused: LSTM cell (4 peds/block) + rel_pos + curr + din2 + preds + Hp (=h2@Wh1T + c1).
__global__ __launch_bounds__(512) void k_lstm(
    const float* __restrict__ WgT, const float* __restrict__ bg,
    float* __restrict__ h_st, float* __restrict__ c_st,
    float* __restrict__ din, float* __restrict__ curr,
    unsigned short* __restrict__ h2h, unsigned short* __restrict__ h2l,
    const float* __restrict__ posW, const float* __restrict__ posb,
    const float* __restrict__ embW, const float* __restrict__ embb,
    const float* __restrict__ Wh1T, const float* __restrict__ c1,
    float* __restrict__ Hp, int doHp,
    float* __restrict__ preds) {
    int n0 = blockIdx.x << 2;
    int t = threadIdx.x;
    __shared__ float xs[4][256];
    __shared__ float gates[4][512];
    __shared__ float h2s[4][128];
    __shared__ float rp[4][2];
#pragma unroll
    for (int u = 0; u < 2; u++) {
        int lin = t + (u << 9);
        int r = lin >> 8, k = lin & 255;
        float v = 0.f;
        if (k < 64) v = din[(n0 + r) * 64 + k];
        else if (k < 192) v = h_st[(n0 + r) * 128 + (k - 64)];
        xs[r][k] = v;
    }
    __syncthreads();
    float a0 = bg[t], a1 = a0, a2 = a0, a3 = a0;
#pragma unroll 4
    for (int k = 0; k < 192; k++) {
        float w = WgT[(k << 9) + t];
        a0 = fmaf(xs[0][k], w, a0);
        a1 = fmaf(xs[1][k], w, a1);
        a2 = fmaf(xs[2][k], w, a2);
        a3 = fmaf(xs[3][k], w, a3);
    }
    gates[0][t] = a0; gates[1][t] = a1; gates[2][t] = a2; gates[3][t] = a3;
    __syncthreads();
    {
        int r = t >> 7, hx = t & 127;
        float ig = sigm(gates[r][hx]);
        float fg = sigm(gates[r][128 + hx]);
        float gg = tanhf(gates[r][256 + hx]);
        float og = sigm(gates[r][384 + hx]);
        float c2 = fmaf(fg, c_st[(n0 + r) * 128 + hx], ig * gg);
        float h2 = og * tanhf(c2);
        c_st[(n0 + r) * 128 + hx] = c2;
        unsigned short sh, sl;
        splitf(h2, sh, sl);
        h2h[(n0 + r) * 128 + hx] = sh;
        h2l[(n0 + r) * 128 + hx] = sl;
        h2s[r][hx] = h2;
    }
    __syncthreads();
    int wv = t >> 6, l = t & 63;
    if (wv < 4) {
        float p0 = fmaf(h2s[wv][l], posW[l], h2s[wv][l + 64] * posW[l + 64]);
        float p1 = fmaf(h2s[wv][l], posW[128 + l], h2s[wv][l + 64] * posW[192 + l]);
#pragma unroll
        for (int off = 32; off > 0; off >>= 1) {
            p0 += __shfl_down(p0, off, 64);
            p1 += __shfl_down(p1, off, 64);
        }
        if (l == 0) { rp[wv][0] = p0 + posb[0]; rp[wv][1] = p1 + posb[1]; }
    }
    __syncthreads();
    if (t < 256) {
        int r = t >> 6, e = t & 63;
        float r0 = rp[r][0], r1 = rp[r][1];
        din[(n0 + r) * 64 + e] = fmaf(r0, embW[e * 2], fmaf(r1, embW[e * 2 + 1], embb[e]));
        if (e == 0) {
            preds[(n0 + r) * 2] = r0; preds[(n0 + r) * 2 + 1] = r1;
            curr[(n0 + r) * 2] += r0; curr[(n0 + r) * 2 + 1] += r1;
        }
    }
    if (doHp) {
        float cc = c1[t];
        float q0 = cc, q1 = cc, q2 = cc, q3 = cc;
#pragma unroll 4
        for (int h = 0; h < 128; h++) {
            float w = Wh1T[(h << 9) + t];
            q0 = fmaf(h2s[0][h], w, q0);
            q1 = fmaf(h2s[1][h], w, q1);
            q2 = fmaf(h2s[2][h], w, q2);
            q3 = fmaf(h2s[3][h], w, q3);
        }
        Hp[((n0 + 0) << 9) + t] = q0;
        Hp[((n0 + 1) << 9) + t] = q1;
        Hp[((n0 + 2) << 9) + t] = q2;
        Hp[((n0 + 3) << 9) + t] = q3;
    }
}

// Build x1 bf16 once per step, XOR-swizzled within each 64-k tile (chunk c at c^(j&7)).
// XCD-swizzled grid: scene s on XCD s%8 so x1 lands in the consumer's L2.
__global__ __launch_bounds__(256) void k_x1(
    const float* __restrict__ Hp, const float* __restrict__ Mp,
    const float* __restrict__ curr, unsigned short* __restrict__ x1g) {
    int bid = blockIdx.x;
    int c = bid & 7, q = bid >> 3;       // q 0..127
    int i = q & 31, g = q >> 5;          // g 0..3
    int s = (g << 3) + c;
    int si = (s << 5) + i;
    int t = threadIdx.x;
    __shared__ float rx[32], ry[32];
    __shared__ float m0s[512], m1s[512];
    for (int u = t; u < 512; u += 256) { m0s[u] = Mp[u]; m1s[u] = Mp[512 + u]; }
    if (t < 32) {
        int jg = (s << 5) + t;
        float dx = curr[jg * 2] - curr[si * 2];
        float dy = curr[jg * 2 + 1] - curr[si * 2 + 1];
        float den = fmaxf(sqrtf(dx * dx + dy * dy), 1e-12f);
        rx[t] = dx / den; ry[t] = dy / den;
    }
    __syncthreads();
    int j = t >> 3, c8 = t & 7;
    float rxv = rx[j], ryv = ry[j];
    const float* hp = Hp + (((s << 5) + j) << 9);
    unsigned short* op = x1g + ((size_t)((si << 5) + j) << 9);
    int swz = (c8 ^ (j & 7)) << 3;
#pragma unroll
    for (int kt = 0; kt < 512; kt += 64) {
        int k = kt + (c8 << 3);
        float4 ha = *(const float4*)(hp + k);
        float4 hb = *(const float4*)(hp + k + 4);
        uint4 o;
        o.x = pack2(f2bf(fmaxf(fmaf(rxv, m0s[k + 0], fmaf(ryv, m1s[k + 0], ha.x)), 0.f)),
                    f2bf(fmaxf(fmaf(rxv, m0s[k + 1], fmaf(ryv, m1s[k + 1], ha.y)), 0.f)));
        o.y = pack2(f2bf(fmaxf(fmaf(rxv, m0s[k + 2], fmaf(ryv, m1s[k + 2], ha.z)), 0.f)),
                    f2bf(fmaxf(fmaf(rxv, m0s[k + 3], fmaf(ryv, m1s[k + 3], ha.w)), 0.f)));
        o.z = pack2(f2bf(fmaxf(fmaf(rxv, m0s[k + 4], fmaf(ryv, m1s[k + 4], hb.x)), 0.f)),
                    f2bf(fmaxf(fmaf(rxv, m0s[k + 5], fmaf(ryv, m1s[k + 5], hb.y)), 0.f)));
        o.w = pack2(f2bf(fmaxf(fmaf(rxv, m0s[k + 6], fmaf(ryv, m1s[k + 6], hb.z)), 0.f)),
                    f2bf(fmaxf(fmaf(rxv, m0s[k + 7], fmaf(ryv, m1s[k + 7], hb.w)), 0.f)));
        *(uint4*)(op + kt + swz) = o;
    }
}

// Pure GEMM + max-pool. 256x256 tile, 1024 threads (16 waves), BK=64, K=512,
// DOUBLE-BUFFERED async staging: tile i+1 issued before compute of tile i, so the
// barrier's vmcnt drain overlaps ~600 cyc of MFMA. XCD-swizzled linear grid (512).
__global__ __launch_bounds__(1024, 4) void k_pool_g(
    const unsigned short* __restrict__ x1g, const unsigned short* __restrict__ W2bf,
    const float* __restrict__ c2v,
    unsigned short* __restrict__ poolh, unsigned short* __restrict__ pooll) {
    int bid = blockIdx.x;
    int c = bid & 7, q = bid >> 3;       // q 0..63
    int inner = q & 15, g = q >> 4;      // g 0..3
    int s = (g << 3) + c;
    int rb = inner >> 2;                 // 256-row group (8 i's)
    int koB = (inner & 3) << 8;          // 0,256,512,768
    int t = threadIdx.x;
    int lane = t & 63, wv = t >> 6;      // 16 waves
    int quad = lane >> 4, l15 = lane & 15;
    int wr = wv >> 2, wc = wv & 3;
    int qrow = wr << 6, qcol = wc << 6;
    __shared__ unsigned short As[2][256 * 64];
    __shared__ unsigned short Bs[2][256 * 64];
    f32x4 acc[4][4];
#pragma unroll
    for (int a = 0; a < 4; a++)
#pragma unroll
        for (int b = 0; b < 4; b++) acc[a][b] = (f32x4){0.f, 0.f, 0.f, 0.f};

    int rlane = lane >> 3;               // 0..7
    int clane = (lane & 7) << 3;         // k-chunk (shorts)
    const unsigned short* gA = x1g + (size_t)((s << 10) + (rb << 8) + (wv << 4) + rlane) * 512 + clane;
    const unsigned short* gB = W2bf + (size_t)(koB + (wv << 4) + rlane) * 512 + clane;
    // hoisted fragment bases (kt-invariant): pos = ((kt2<<2)+quad) ^ (l15&7)
    const unsigned short* pa0 = &As[0][((qrow + l15) << 6) + ((quad ^ (l15 & 7)) << 3)];
    const unsigned short* pb0 = &Bs[0][((qcol + l15) << 6) + ((quad ^ (l15 & 7)) << 3)];
    const unsigned short* pa1 = &As[0][((qrow + l15) << 6) + (((4 + quad) ^ (l15 & 7)) << 3)];
    const unsigned short* pb1 = &Bs[0][((qcol + l15) << 6) + (((4 + quad) ^ (l15 & 7)) << 3)];

    // stage tile (kt) into buffer buf
#define POOL_STAGE(kt, buf)                                           \
    do {                                                              \
        unsigned short* lA = &As[buf][wv << 10];                      \
        unsigned short* lB = &Bs[buf][wv << 10];                      \
        ASYNC_COPY16(gA + (kt), lA);                                  \
        ASYNC_COPY16(gA + (kt) + 8 * 512, lA + (8 << 6));             \
        ASYNC_COPY16(gB + (kt), lB);                                  \
        ASYNC_COPY16(gB + (kt) + 8 * 512, lB + (8 << 6));             \
    } while (0)

    POOL_STAGE(0, 0);
    __syncthreads();
    for (int i = 0; i < 8; i++) {
        if (i < 7) POOL_STAGE((i + 1) << 6, (i + 1) & 1);
        int off = (i & 1) << 14;       // buffer stride 256*64 shorts
        short8 aF[4], bF[4];
#pragma unroll
        for (int a = 0; a < 4; a++) aF[a] = *(const short8*)(pa0 + off + (a << 10));
#pragma unroll
        for (int b = 0; b < 4; b++) bF[b] = *(const short8*)(pb0 + off + (b << 10));
#pragma unroll
        for (int a = 0; a < 4; a++)
#pragma unroll
            for (int b = 0; b < 4; b++)
                acc[a][b] = __builtin_amdgcn_mfma_f32_16x16x32_bf16(aF[a], bF[b], acc[a][b], 0, 0, 0);
#pragma unroll
        for (int a = 0; a < 4; a++) aF[a] = *(const short8*)(pa1 + off + (a << 10));
#pragma unroll
        for (int b = 0; b < 4; b++) bF[b] = *(const short8*)(pb1 + off + (b << 10));
#pragma unroll
        for (int a = 0; a < 4; a++)
#pragma unroll
            for (int b = 0; b < 4; b++)
                acc[a][b] = __builtin_amdgcn_mfma_f32_16x16x32_bf16(aF[a], bF[b], acc[a][b], 0, 0, 0);
        __syncthreads();
    }
#undef POOL_STAGE

    // max over j: quadrant rows = 2 i's (32 j each); a=0,1 -> i0, a=2,3 -> i0+1
    float mx0[4], mx1[4];
#pragma unroll
    for (int b = 0; b < 4; b++) {
        float m = acc[0][b].x;
#pragma unroll
        for (int a = 0; a < 2; a++) {
            m = fmaxf(m, acc[a][b].x); m = fmaxf(m, acc[a][b].y);
            m = fmaxf(m, acc[a][b].z); m = fmaxf(m, acc[a][b].w);
        }
        m = fmaxf(m, __shfl_xor(m, 16));
        m = fmaxf(m, __shfl_xor(m, 32));
        mx0[b] = m;
        float n = acc[2][b].x;
#pragma unroll
        for (int a = 2; a < 4; a++) {
            n = fmaxf(n, acc[a][b].x); n = fmaxf(n, acc[a][b].y);
            n = fmaxf(n, acc[a][b].z); n = fmaxf(n, acc[a][b].w);
        }
        n = fmaxf(n, __shfl_xor(n, 16));
        n = fmaxf(n, __shfl_xor(n, 32));
        mx1[b] = n;
    }
    float v0 = (quad == 0) ? mx0[0] : (quad == 1) ? mx0[1] : (quad == 2) ? mx0[2] : mx0[3];
    float v1 = (quad == 0) ? mx1[0] : (quad == 1) ? mx1[1] : (quad == 2) ? mx1[2] : mx1[3];
    int col = koB + qcol + (quad << 4) + l15;
    int i0 = (rb << 3) + (wr << 1);
    int si0 = (s << 5) + i0;
    float bias = c2v[col];
    float w0 = fmaxf(v0 + bias, 0.f);
    float w1 = fmaxf(v1 + bias, 0.f);
    unsigned short h0, l0, h1, l1;
    splitf(w0, h0, l0); splitf(w1, h1, l1);
    poolh[si0 * 1024 + col] = h0; pooll[si0 * 1024 + col] = l0;
    poolh[(si0 + 1) * 1024 + col] = h1; pooll[(si0 + 1) * 1024 + col] = l1;
}

// Fallback (small ws): fused build + GEMM + pool. W2bf must be UNswizzled for this path.
__global__ __launch_bounds__(256) void k_pool_mfma(
    const float* __restrict__ Hp, const float* __restrict__ Mp,
    const unsigned short* __restrict__ W2bf,
    const float* __restrict__ c2v, const float* __restrict__ curr,
    unsigned short* __restrict__ poolh, unsigned short* __restrict__ pooll) {
    int s = blockIdx.z;
    int rb = blockIdx.y;
    int koBase = blockIdx.x << 7;
    int t = threadIdx.x;
    int lane = t & 63, wv = t >> 6;
    int quad = lane >> 4, l15 = lane & 15;
    int qrow = (wv >> 1) << 6;
    int qcol = (wv & 1) << 6;

    __shared__ unsigned short As[128 * 40];
    __shared__ unsigned short Bs[128 * 40];
    __shared__ float rx[128], ry[128];

    if (t < 128) {
        int iL = t >> 5, j = t & 31;
        int ig = (s << 5) + (rb << 2) + iL;
        int jg = (s << 5) + j;
        float dx = curr[jg * 2] - curr[ig * 2];
        float dy = curr[jg * 2 + 1] - curr[ig * 2 + 1];
        float den = fmaxf(sqrtf(dx * dx + dy * dy), 1e-12f);
        rx[t] = dx / den; ry[t] = dy / den;
    }
    __syncthreads();

    f32x4 acc[4][4];
#pragma unroll
    for (int a = 0; a < 4; a++)
#pragma unroll
        for (int b = 0; b < 4; b++) acc[a][b] = (f32x4){0.f, 0.f, 0.f, 0.f};

    int r0 = t >> 3, c4 = (t & 7) << 2;
    int bn = t >> 1, bk = (t & 1) << 4;

    for (int kt = 0; kt < 512; kt += 32) {
#pragma unroll
        for (int p = 0; p < 4; p++) {
            int rr = r0 + (p << 5);
            int j = rr & 31;
            int kg = kt + c4;
            float4 hv = *(const float4*)(Hp + (((s << 5) + j) << 9) + kg);
            float4 m0 = *(const float4*)(Mp + kg);
            float4 m1 = *(const float4*)(Mp + 512 + kg);
            float rxv = rx[rr], ryv = ry[rr];
            float v0 = fmaxf(fmaf(rxv, m0.x, fmaf(ryv, m1.x, hv.x)), 0.f);
            float v1 = fmaxf(fmaf(rxv, m0.y, fmaf(ryv, m1.y, hv.y)), 0.f);
            float v2 = fmaxf(fmaf(rxv, m0.z, fmaf(ryv, m1.z, hv.z)), 0.f);
            float v3 = fmaxf(fmaf(rxv, m0.w, fmaf(ryv, m1.w, hv.w)), 0.f);
            unsigned int u0 = pack2(f2bf(v0), f2bf(v1));
            unsigned int u1 = pack2(f2bf(v2), f2bf(v3));
            *(uint2*)(&As[rr * 40 + c4]) = make_uint2(u0, u1);
        }
        {
            const unsigned short* src = W2bf + (((koBase + bn) << 9) + kt + bk);
            uint4 w0 = *(const uint4*)src;
            uint4 w1 = *(const uint4*)(src + 8);
            *(uint4*)(&Bs[bn * 40 + bk]) = w0;
            *(uint4*)(&Bs[bn * 40 + bk + 8]) = w1;
        }
        __syncthreads();
        short8 bF[4];
#pragma unroll
        for (int b = 0; b < 4; b++)
            bF[b] = *(const short8*)(&Bs[(qcol + (b << 4) + l15) * 40 + (quad << 3)]);
#pragma unroll
        for (int a = 0; a < 4; a++) {
            short8 aF = *(const short8*)(&As[(qrow + (a << 4) + l15) * 40 + (quad << 3)]);
#pragma unroll
            for (int b = 0; b < 4; b++)
                acc[a][b] = __builtin_amdgcn_mfma_f32_16x16x32_bf16(aF, bF[b], acc[a][b], 0, 0, 0);
        }
        __syncthreads();
    }

    float mx0[4], mx1[4];
#pragma unroll
    for (int b = 0; b < 4; b++) {
        float m = acc[0][b].x;
#pragma unroll
        for (int a = 0; a < 2; a++) {
            m = fmaxf(m, acc[a][b].x); m = fmaxf(m, acc[a][b].y);
            m = fmaxf(m, acc[a][b].z); m = fmaxf(m, acc[a][b].w);
        }
        m = fmaxf(m, __shfl_xor(m, 16));
        m = fmaxf(m, __shfl_xor(m, 32));
        mx0[b] = m;
        float n = acc[2][b].x;
#pragma unroll
        for (int a = 2; a < 4; a++) {
            n = fmaxf(n, acc[a][b].x); n = fmaxf(n, acc[a][b].y);
            n = fmaxf(n, acc[a][b].z); n = fmaxf(n, acc[a][b].w);
        }
        n = fmaxf(n, __shfl_xor(n, 16));
        n = fmaxf(n, __shfl_xor(n, 32));
        mx1[b] = n;
    }
    float v0 = (quad == 0) ? mx0[0] : (quad == 1) ? mx0[1] : (quad == 2) ? mx0[2] : mx0[3];
    float v1 = (quad == 0) ? mx1[0] : (quad == 1) ? mx1[1] : (quad == 2) ? mx1[2] : mx1[3];
    int col = koBase + qcol + (quad << 4) + l15;
    int i0 = (rb << 2) + ((wv >> 1) << 1);
    int si0 = (s << 5) + i0;
    float bias = c2v[col];
    float w0 = fmaxf(v0 + bias, 0.f);
    float w1 = fmaxf(v1 + bias, 0.f);
    unsigned short h0, l0, h1, l1;
    splitf(w0, h0, l0); splitf(w1, h1, l1);
    poolh[si0 * 1024 + col] = h0; pooll[si0 * 1024 + col] = l0;
    poolh[(si0 + 1) * 1024 + col] = h1; pooll[(si0 + 1) * 1024 + col] = l1;
}

// m1 via bf16x3 MFMA. Block: 64 rows x 64 ko, BK=64 (18 stages), K=1152.
__global__ __launch_bounds__(256) void k_m1_mfma(
    const unsigned short* __restrict__ h2h, const unsigned short* __restrict__ h2l,
    const unsigned short* __restrict__ poolh, const unsigned short* __restrict__ pooll,
    const unsigned short* __restrict__ M1h, const unsigned short* __restrict__ M1l,
    const float* __restrict__ cm1,
    unsigned short* __restrict__ dh1h, unsigned short* __restrict__ dh1l) {
    int rowBase = blockIdx.y << 6;
    int koBase = blockIdx.x << 6;
    int t = threadIdx.x;
    int lane = t & 63, wv = t >> 6;
    int quad = lane >> 4, l15 = lane & 15;
    int qrow = (wv >> 1) << 5, qcol = (wv & 1) << 5;
    __shared__ unsigned short Ah[64 * 72], Al[64 * 72], Bh[64 * 72], Bl[64 * 72];
    f32x4 acc[2][2];
#pragma unroll
    for (int a = 0; a < 2; a++)
#pragma unroll
        for (int b = 0; b < 2; b++) acc[a][b] = (f32x4){0.f, 0.f, 0.f, 0.f};

    int ar = t >> 2, ak = (t & 3) << 4;   // 64 rows x 64 k, 16 shorts/thread

    for (int kt = 0; kt < 1152; kt += 64) {
        {
            const unsigned short* sH;
            const unsigned short* sL;
            int off;
            if (kt < 128) {
                off = (rowBase + ar) * 128 + kt + ak;
                sH = h2h; sL = h2l;
            } else {
                off = (rowBase + ar) * 1024 + (kt - 128) + ak;
                sH = poolh; sL = pooll;
            }
            *(uint4*)&Ah[ar * 72 + ak] = *(const uint4*)(sH + off);
            *(uint4*)&Ah[ar * 72 + ak + 8] = *(const uint4*)(sH + off + 8);
            *(uint4*)&Al[ar * 72 + ak] = *(const uint4*)(sL + off);
            *(uint4*)&Al[ar * 72 + ak + 8] = *(const uint4*)(sL + off + 8);
        }
        {
            int boff = (koBase + ar) * 1152 + kt + ak;
            *(uint4*)&Bh[ar * 72 + ak] = *(const uint4*)(M1h + boff);
            *(uint4*)&Bh[ar * 72 + ak + 8] = *(const uint4*)(M1h + boff + 8);
            *(uint4*)&Bl[ar * 72 + ak] = *(const uint4*)(M1l + boff);
            *(uint4*)&Bl[ar * 72 + ak + 8] = *(const uint4*)(M1l + boff + 8);
        }
        __syncthreads();
#pragma unroll
        for (int kk2 = 0; kk2 < 2; kk2++) {
            int kc = ((kk2 << 2) | quad) << 3;
            short8 bH[2], bL[2];
#pragma unroll
            for (int b = 0; b < 2; b++) {
                int boff = (qcol + (b << 4) + l15) * 72 + kc;
                bH[b] = *(const short8*)(&Bh[boff]);
                bL[b] = *(const short8*)(&Bl[boff]);
            }
#pragma unroll
            for (int a = 0; a < 2; a++) {
                int aoff = (qrow + (a << 4) + l15) * 72 + kc;
                short8 aH = *(const short8*)(&Ah[aoff]);
                short8 aL = *(const short8*)(&Al[aoff]);
#pragma unroll
                for (int b = 0; b < 2; b++) {
                    acc[a][b] = __builtin_amdgcn_mfma_f32_16x16x32_bf16(aH, bH[b], acc[a][b], 0, 0, 0);
                    acc[a][b] = __builtin_amdgcn_mfma_f32_16x16x32_bf16(aH, bL[b], acc[a][b], 0, 0, 0);
                    acc[a][b] = __builtin_amdgcn_mfma_f32_16x16x32_bf16(aL, bH[b], acc[a][b], 0, 0, 0);
                }
            }
        }
        __syncthreads();
    }
#pragma unroll
    for (int b = 0; b < 2; b++) {
        int col = koBase + qcol + (b << 4) + l15;
        float bias = cm1[col];
#pragma unroll
        for (int a = 0; a < 2; a++) {
#pragma unroll
            for (int rg = 0; rg < 4; rg++) {
                int row = rowBase + qrow + (a << 4) + (quad << 2) + rg;
                float v = fmaxf(acc[a][b][rg] + bias, 0.f);
                unsigned short sh, sl;
                splitf(v, sh, sl);
                dh1h[row * 1024 + col] = sh;
                dh1l[row * 1024 + col] = sl;
            }
        }
    }
}

// m2 via bf16x3 MFMA: Block: 32 rows x 128 ko, K=1024. Grid 32.
__global__ __launch_bounds__(256) void k_m2_mfma(
    const unsigned short* __restrict__ dh1h, const unsigned short* __restrict__ dh1l,
    const unsigned short* __restrict__ M2h, const unsigned short* __restrict__ M2l,
    const float* __restrict__ cm2, float* __restrict__ h_st) {
    int rowBase = blockIdx.x << 5;
    int t = threadIdx.x;
    int lane = t & 63, wv = t >> 6;
    int quad = lane >> 4, l15 = lane & 15;
    int qrow = (wv >> 1) << 4;   // 0 or 16
    int qcol = (wv & 1) << 6;    // 0 or 64
    __shared__ unsigned short Ah[32 * 40], Al[32 * 40], Bh[128 * 40], Bl[128 * 40];
    f32x4 acc[4];
#pragma unroll
    for (int b = 0; b < 4; b++) acc[b] = (f32x4){0.f, 0.f, 0.f, 0.f};

    int ar = t >> 3, ak = (t & 7) << 2;   // A: 32 rows x 32 k, 4 shorts/thread
    int br = t >> 1, bk = (t & 1) << 4;   // B: 128 ko x 32 k, 16 shorts/thread

    for (int kt = 0; kt < 1024; kt += 32) {
        {
            int off = (rowBase + ar) * 1024 + kt + ak;
            *(uint2*)&Ah[ar * 40 + ak] = *(const uint2*)(dh1h + off);
            *(uint2*)&Al[ar * 40 + ak] = *(const uint2*)(dh1l + off);
        }
        {
            int off = br * 1024 + kt + bk;
            *(uint4*)&Bh[br * 40 + bk] = *(const uint4*)(M2h + off);
            *(uint4*)&Bh[br * 40 + bk + 8] = *(const uint4*)(M2h + off + 8);
            *(uint4*)&Bl[br * 40 + bk] = *(const uint4*)(M2l + off);
            *(uint4*)&Bl[br * 40 + bk + 8] = *(const uint4*)(M2l + off + 8);
        }
        __syncthreads();
        {
            int aoff = (qrow + l15) * 40 + (quad << 3);
            short8 aH = *(const short8*)(&Ah[aoff]);
            short8 aL = *(const short8*)(&Al[aoff]);
#pragma unroll
            for (int b = 0; b < 4; b++) {
                int boff = (qcol + (b << 4) + l15) * 40 + (quad << 3);
                short8 bH = *(const short8*)(&Bh[boff]);
                short8 bL = *(const short8*)(&Bl[boff]);
                acc[b] = __builtin_amdgcn_mfma_f32_16x16x32_bf16(aH, bH, acc[b], 0, 0, 0);
                acc[b] = __builtin_amdgcn_mfma_f32_16x16x32_bf16(aH, bL, acc[b], 0, 0, 0);
                acc[b] = __builtin_amdgcn_mfma_f32_16x16x32_bf16(aL, bH, acc[b], 0, 0, 0);
            }
        }
        __syncthreads();
    }
#pragma unroll
    for (int b = 0; b < 4; b++) {
        int col = qcol + (b << 4) + l15;
        float bias = cm2[col];
#pragma unroll
        for (int rg = 0; rg < 4; rg++) {
            int row = rowBase + qrow + (quad << 2) + rg;
            h_st[row * 128 + col] = fmaxf(acc[b][rg] + bias, 0.f);
        }
    }
}

// ---------------- launch ----------------

extern "C" void kernel_launch(void* const* d_in, const int* in_sizes, int n_in,
                              void* d_out, int out_size, void* d_ws, size_t ws_size,
                              hipStream_t stream) {
    const float* last_pos     = (const float*)d_in[0];
    const float* last_pos_rel = (const float*)d_in[1];
    const float* h0   = (const float*)d_in[2];
    const float* c0   = (const float*)d_in[3];
    const float* emb_W = (const float*)d_in[5];
    const float* emb_b = (const float*)d_in[6];
    const float* lstm_Wih = (const float*)d_in[7];
    const float* lstm_Whh = (const float*)d_in[8];
    const float* lstm_bih = (const float*)d_in[9];
    const float* lstm_bhh = (const float*)d_in[10];
    const float* pos_W = (const float*)d_in[11];
    const float* pos_b = (const float*)d_in[12];
    const float* sp_W  = (const float*)d_in[13];
    const float* sp_b  = (const float*)d_in[14];
    const float* pp1_W = (const float*)d_in[15];
    const float* pp1_b = (const float*)d_in[16];
    const float* pp1_g = (const float*)d_in[17];
    const float* pp1_be= (const float*)d_in[18];
    const float* pp2_W = (const float*)d_in[19];
    const float* pp2_b = (const float*)d_in[20];
    const float* pp2_g = (const float*)d_in[21];
    const float* pp2_be= (const float*)d_in[22];
    const float* m1_W  = (const float*)d_in[23];
    const float* m1_b  = (const float*)d_in[24];
    const float* m1_g  = (const float*)d_in[25];
    const float* m1_be = (const float*)d_in[26];
    const float* m2_W  = (const float*)d_in[27];
    const float* m2_b  = (const float*)d_in[28];
    const float* m2_g  = (const float*)d_in[29];
    const float* m2_be = (const float*)d_in[30];
    float* out = (float*)d_out;

    float* p = (float*)d_ws;
    float* WgT  = p; p += 192 * 512;
    float* bg   = p; p += 512;
    float* Wh1T = p; p += 128 * 512;
    float* Mp   = p; p += 2 * 512;
    float* c1   = p; p += 512;
    unsigned short* W2bf = (unsigned short*)p; p += 512 * 1024 / 2;
    float* c2v  = p; p += 1024;
    unsigned short* M1h = (unsigned short*)p; p += 1024 * 1152 / 2;
    unsigned short* M1l = (unsigned short*)p; p += 1024 * 1152 / 2;
    float* cm1  = p; p += 1024;
    unsigned short* M2h = (unsigned short*)p; p += 128 * 1024 / 2;
    unsigned short* M2l = (unsigned short*)p; p += 128 * 1024 / 2;
    float* cm2  = p; p += 128;
    float* h_st = p; p += 1024 * 128;
    float* c_st = p; p += 1024 * 128;
    unsigned short* h2h = (unsigned short*)p; p += 1024 * 128 / 2;
    unsigned short* h2l = (unsigned short*)p; p += 1024 * 128 / 2;
    float* curr = p; p += 1024 * 2;
    float* din  = p; p += 1024 * 64;
    float* Hp   = p; p += 1024 * 512;
    unsigned short* poolh = (unsigned short*)p; p += 1024 * 1024 / 2;
    unsigned short* pooll = (unsigned short*)p; p += 1024 * 1024 / 2;
    unsigned short* dh1h = (unsigned short*)p; p += 1024 * 1024 / 2;
    unsigned short* dh1l = (unsigned short*)p; p += 1024 * 1024 / 2;
    unsigned short* x1g = (unsigned short*)p;   // 32768*512 bf16 = 33.5 MB (big-ws path only)
    size_t need = (size_t)((char*)(x1g + (size_t)32768 * 512) - (char*)d_ws);
    int big = (ws_size >= need) ? 1 : 0;

    pre_misc<<<1154, 256, 0, stream>>>(lstm_Wih, lstm_Whh, lstm_bih, lstm_bhh, WgT, bg,
                                       pp1_W, pp1_g, Wh1T,
                                       sp_W, sp_b, pp1_b, pp1_be, Mp, c1,
                                       last_pos, last_pos_rel, h0, c0, emb_W, emb_b,
                                       h_st, c_st, curr, din);
    pre_w2bf<<<2048, 256, 0, stream>>>(pp2_W, pp2_b, pp2_g, pp2_be, W2bf, c2v, big);
    pre_w1split<<<4608, 256, 0, stream>>>(m1_W, m1_b, m1_g, m1_be, M1h, M1l, cm1);
    pre_w2split<<<512, 256, 0, stream>>>(m2_W, m2_b, m2_g, m2_be, M2h, M2l, cm2);

    for (int t = 0; t < 12; t++) {
        k_lstm<<<256, 512, 0, stream>>>(WgT, bg, h_st, c_st, din, curr, h2h, h2l,
                                        pos_W, pos_b, emb_W, emb_b,
                                        Wh1T, c1, Hp, (t < 11) ? 1 : 0, out + t * 2048);
        if (t == 11) break;
        if (big) {
            k_x1<<<1024, 256, 0, stream>>>(Hp, Mp, curr, x1g);
            k_pool_g<<<512, 1024, 0, stream>>>(x1g, W2bf, c2v, poolh, pooll);
        } else {
            k_pool_mfma<<<dim3(8, 8, 32), 256, 0, stream>>>(Hp, Mp, W2bf, c2v, curr,
                                                            poolh, pooll);
        }
        k_m1_mfma<<<dim3(16, 16), 256, 0, stream>>>(h2h, h2l, poolh, pooll,
                                                    M1h, M1l, cm1, dh1h, dh1l);
        k_m2_mfma<<<32, 256, 0, stream>>>(dh1h, dh1l, M2h, M2l, cm2, h_st);
    }
}